// Round 1
// baseline (2507.359 us; speedup 1.0000x reference)
//
#include <hip/hip_runtime.h>
#include <cstddef>

#define NPTS 4096
#define KNBR 80
#define CH   128
#define NF   (NPTS*CH)      // 524288
#define FFD  512

__device__ __forceinline__ float dot4f(float4 a, float4 b){
    return a.x*b.x + a.y*b.y + a.z*b.z + a.w*b.w;
}

// ---------------- pos stats (mean, 1/(std_ddof1+1e-8)) ----------------
__global__ void pos_stats_kernel(const float* __restrict__ pos, float* __restrict__ stats){
    __shared__ float red[256];
    int t = threadIdx.x;
    float s = 0.f;
    for (int i = t; i < NPTS; i += 256) s += pos[(size_t)i*3];
    red[t] = s; __syncthreads();
    for (int o = 128; o; o >>= 1){ if (t < o) red[t] += red[t+o]; __syncthreads(); }
    float mean = red[0] / (float)NPTS;
    __syncthreads();
    float ss = 0.f;
    for (int i = t; i < NPTS; i += 256){ float d = pos[(size_t)i*3] - mean; ss += d*d; }
    red[t] = ss; __syncthreads();
    for (int o = 128; o; o >>= 1){ if (t < o) red[t] += red[t+o]; __syncthreads(); }
    if (t == 0){
        float sd = sqrtf(red[0] / (float)(NPTS-1));
        stats[512] = mean;
        stats[513] = 1.f/(sd + 1e-8f);
    }
}

// ---------------- positional encoding ----------------
__global__ void pe_kernel(const float* __restrict__ pos, const float* __restrict__ stats,
                          float* __restrict__ pe){
    int t = blockIdx.x*256 + threadIdx.x;      // 0 .. 4096*64-1
    int i = t >> 6, m = t & 63;
    float px = (pos[(size_t)i*3] - stats[512]) * stats[513];
    float dv = expf((float)(2*m) * -0.07195578415606394f);   // -ln(10000)/128
    float ang = px * dv;
    float sv, cv;
    sincosf(ang, &sv, &cv);
    pe[(size_t)i*CH + 2*m]     = sv;
    pe[(size_t)i*CH + 2*m + 1] = cv;
}

// ---------------- build A matrix (N x 64 x 128) for cconv ----------------
__global__ __launch_bounds__(128) void build_A_kernel(
        const float* __restrict__ xin, const float* __restrict__ yin,
        const float* __restrict__ pos, const int* __restrict__ nbr,
        float* __restrict__ Abuf, int base, int rows){
    __shared__ float Asm[64*CH];
    const float* feat = blockIdx.y ? yin : xin;
    int i = base + blockIdx.x;
    int t = threadIdx.x;
    for (int kx = t; kx < 64*CH; kx += 128) Asm[kx] = 0.f;
    __syncthreads();
    float p0 = pos[(size_t)i*3], p1 = pos[(size_t)i*3+1], p2 = pos[(size_t)i*3+2];
    const float RAD = 0.1125f;   // == float32(0.225)/2
    for (int j = 0; j < KNBR; ++j){
        int nb = nbr[(size_t)i*KNBR + j];
        if (nb == i) continue;   // mask == (idx != self)
        float rx = (pos[(size_t)nb*3+0]-p0)/RAD;
        float ry = (pos[(size_t)nb*3+1]-p1)/RAD;
        float rz = (pos[(size_t)nb*3+2]-p2)/RAD;
        float r2 = rx*rx + ry*ry + rz*rz;
        float w1 = 1.f - r2;
        float win = fminf(fmaxf(w1*w1*w1, 0.f), 1.f);
        float nrm = sqrtf(fmaxf(r2, 1e-12f));
        float linf = fmaxf(fmaxf(fabsf(rx), fabsf(ry)), fabsf(rz));
        linf = fmaxf(linf, 1e-9f);
        float sc = nrm/linf;
        float gx = fminf(fmaxf((rx*sc+1.f)*0.5f*3.f, 0.f), 3.f);
        float gy = fminf(fmaxf((ry*sc+1.f)*0.5f*3.f, 0.f), 3.f);
        float gz = fminf(fmaxf((rz*sc+1.f)*0.5f*3.f, 0.f), 3.f);
        float fx = fminf(floorf(gx), 2.f), fy = fminf(floorf(gy), 2.f), fz = fminf(floorf(gz), 2.f);
        float tx = gx-fx, ty = gy-fy, tz = gz-fz;
        int ix = (int)fx, iy = (int)fy, iz = (int)fz;
        int cb = ((ix<<4) + (iy<<2) + iz)*CH + t;
        float v = feat[(size_t)nb*CH + t];
        float x0 = (1.f-tx)*win, x1 = tx*win;
        float w00 = x0*(1.f-ty), w01 = x0*ty, w10 = x1*(1.f-ty), w11 = x1*ty;
        float z0 = 1.f-tz, z1 = tz;
        Asm[cb       ] += w00*z0*v;
        Asm[cb +  128] += w00*z1*v;
        Asm[cb +  512] += w01*z0*v;
        Asm[cb +  640] += w01*z1*v;
        Asm[cb + 2048] += w10*z0*v;
        Asm[cb + 2176] += w10*z1*v;
        Asm[cb + 2560] += w11*z0*v;
        Asm[cb + 2688] += w11*z1*v;
    }
    __syncthreads();
    size_t off = ((size_t)blockIdx.y*rows + blockIdx.x) * (size_t)(64*CH);
    for (int kx = t; kx < 64*CH; kx += 128) Abuf[off + kx] = Asm[kx];
}

// ---------------- generic tiled GEMM: out = A @ W(^T) + bias, opt relu ----------------
// WT=true : W is (Dout, Cin) row-major (out = A @ W^T)
// WT=false: W is (Cin, Dout) row-major (out = A @ W)
// z-batched: A += z*aZ, out += z*oZ, W/bias switch to alt pointer for z==1 if non-null.
template<bool WT>
__global__ __launch_bounds__(256) void gemm_kernel(
        const float* __restrict__ A, const float* __restrict__ W0, const float* __restrict__ W1p,
        const float* __restrict__ b0, const float* __restrict__ b1p,
        float* __restrict__ out, int M, int Cin, int Dout,
        long aZ, long oZ, int relu){
    __shared__ __align__(16) float As[64][36];
    __shared__ __align__(16) float Ws[64][36];
    const float* W    = (blockIdx.z && W1p) ? W1p : W0;
    const float* bias = (blockIdx.z && b1p) ? b1p : b0;
    A   += (long)blockIdx.z * aZ;
    out += (long)blockIdx.z * oZ;
    int r0 = blockIdx.x*64, c0 = blockIdx.y*64;
    int tid = threadIdx.x;
    int rg = tid >> 4, cg = tid & 15;
    float acc[4][4] = {};
    for (int kk = 0; kk < Cin; kk += 32){
        #pragma unroll
        for (int rep = 0; rep < 2; ++rep){
            int idx = tid + rep*256;
            int r = idx >> 3, k4 = (idx & 7)*4;
            *(float4*)&As[r][k4] = *(const float4*)&A[(size_t)(r0+r)*Cin + kk + k4];
        }
        if (WT){
            #pragma unroll
            for (int rep = 0; rep < 2; ++rep){
                int idx = tid + rep*256;
                int c = idx >> 3, k4 = (idx & 7)*4;
                *(float4*)&Ws[c][k4] = *(const float4*)&W[(size_t)(c0+c)*Cin + kk + k4];
            }
        } else {
            #pragma unroll
            for (int rep = 0; rep < 8; ++rep){
                int idx = tid + rep*256;
                int cc = idx & 63, kx = idx >> 6;
                Ws[cc][kx] = W[(size_t)(kk+kx)*Dout + c0 + cc];
            }
        }
        __syncthreads();
        #pragma unroll
        for (int k4 = 0; k4 < 32; k4 += 4){
            float4 a[4], w[4];
            #pragma unroll
            for (int i = 0; i < 4; ++i) a[i] = *(const float4*)&As[rg*4+i][k4];
            #pragma unroll
            for (int j = 0; j < 4; ++j) w[j] = *(const float4*)&Ws[cg*4+j][k4];
            #pragma unroll
            for (int i = 0; i < 4; ++i)
                #pragma unroll
                for (int j = 0; j < 4; ++j)
                    acc[i][j] += dot4f(a[i], w[j]);
        }
        __syncthreads();
    }
    #pragma unroll
    for (int i = 0; i < 4; ++i){
        int r = r0 + rg*4 + i;
        #pragma unroll
        for (int j = 0; j < 4; ++j){
            int c = c0 + cg*4 + j;
            float v = acc[i][j] + (bias ? bias[c] : 0.f);
            if (relu) v = fmaxf(v, 0.f);
            out[(size_t)r*Dout + c] = v;
        }
    }
}

// ---------------- BatchNorm stats (mean over N per channel) ----------------
__global__ void bn_stats_kernel(const float* __restrict__ hconv, float* __restrict__ stats){
    __shared__ float rs[256];
    __shared__ float rq[256];
    int ch = blockIdx.x, f = blockIdx.y, t = threadIdx.x;
    const float* src = hconv + (size_t)f*NF;
    float s = 0.f, q2 = 0.f;
    for (int r = t; r < NPTS; r += 256){
        float vv = src[(size_t)r*CH + ch];
        s += vv; q2 += vv*vv;
    }
    rs[t] = s; rq[t] = q2; __syncthreads();
    for (int o = 128; o; o >>= 1){
        if (t < o){ rs[t] += rs[t+o]; rq[t] += rq[t+o]; }
        __syncthreads();
    }
    if (t == 0){
        float m = rs[0]/(float)NPTS;
        float var = rq[0]/(float)NPTS - m*m;
        stats[f*128 + ch] = m;
        stats[256 + f*128 + ch] = rsqrtf(var + 1e-5f);
    }
}

__global__ void bn_apply_kernel(const float* __restrict__ hconv, const float* __restrict__ stats,
        const float* __restrict__ gx, const float* __restrict__ bxp,
        const float* __restrict__ gy, const float* __restrict__ byp,
        float* __restrict__ xf){
    int f = blockIdx.y;
    size_t idx = (size_t)blockIdx.x*256 + threadIdx.x;
    int ch = idx & 127;
    const float* g = f ? gy : gx;
    const float* b = f ? byp : bxp;
    float m = stats[f*128 + ch], inv = stats[256 + f*128 + ch];
    float vv = hconv[(size_t)f*NF + idx];
    xf[(size_t)f*NF + idx] = fmaxf((vv - m)*inv*g[ch] + b[ch], 0.f);
}

__global__ void addpe_kernel(const float* __restrict__ xf, const float* __restrict__ pe,
                             float* __restrict__ h){
    int f = blockIdx.y;
    size_t idx = (size_t)blockIdx.x*256 + threadIdx.x;
    h[(size_t)f*NF + idx] = xf[(size_t)f*NF + idx] + pe[idx];
}

// ---------------- flash attention (fp32, online softmax) ----------------
// grid (N/64, NHEADS, 2feat), block 256.  thread -> (qrow = tid>>2, sub = tid&3)
__global__ __launch_bounds__(256) void attn_kernel(const float* __restrict__ qg,
        const float* __restrict__ kg, const float* __restrict__ vg, float* __restrict__ og){
    __shared__ __align__(16) float Kt[64][36];
    __shared__ __align__(16) float Vt[64][36];
    __shared__ float Pt[64][65];
    int q0 = blockIdx.x*64, hoff = blockIdx.y*32;
    size_t zo = (size_t)blockIdx.z * NF;
    const float* Q = qg + zo; const float* K = kg + zo; const float* V = vg + zo;
    float* O = og + zo;
    int tid = threadIdx.x, qrow = tid >> 2, sub = tid & 3;
    float qv[32];
    #pragma unroll
    for (int c = 0; c < 32; ++c)
        qv[c] = Q[(size_t)(q0+qrow)*CH + hoff + c] * 0.17677669529663687f;  // 1/sqrt(32)
    float acc[8] = {0,0,0,0,0,0,0,0};
    float mprev = -3.0e38f, l = 0.f;
    for (int kt = 0; kt < 64; ++kt){
        int k0 = kt*64;
        __syncthreads();
        #pragma unroll
        for (int rep = 0; rep < 2; ++rep){
            int idx = tid + rep*256;
            int r = idx >> 3, c4 = (idx & 7)*4;
            *(float4*)&Kt[r][c4] = *(const float4*)&K[(size_t)(k0+r)*CH + hoff + c4];
            *(float4*)&Vt[r][c4] = *(const float4*)&V[(size_t)(k0+r)*CH + hoff + c4];
        }
        __syncthreads();
        float sv[16];
        float mloc = -3.0e38f;
        #pragma unroll
        for (int u = 0; u < 16; ++u){
            int ky = sub*16 + u;
            float s = 0.f;
            #pragma unroll
            for (int c4 = 0; c4 < 32; c4 += 4){
                float4 kv = *(const float4*)&Kt[ky][c4];
                s += qv[c4]*kv.x + qv[c4+1]*kv.y + qv[c4+2]*kv.z + qv[c4+3]*kv.w;
            }
            sv[u] = s;
            mloc = fmaxf(mloc, s);
        }
        mloc = fmaxf(mloc, __shfl_xor(mloc, 1));
        mloc = fmaxf(mloc, __shfl_xor(mloc, 2));
        float mnew = fmaxf(mprev, mloc);
        float alpha = __expf(mprev - mnew);
        float sump = 0.f;
        #pragma unroll
        for (int u = 0; u < 16; ++u){
            float p = __expf(sv[u] - mnew);
            Pt[qrow][sub*16 + u] = p;
            sump += p;
        }
        sump += __shfl_xor(sump, 1);
        sump += __shfl_xor(sump, 2);
        l = l*alpha + sump;
        #pragma unroll
        for (int j = 0; j < 8; ++j) acc[j] *= alpha;
        mprev = mnew;
        __syncthreads();
        for (int k2 = 0; k2 < 64; ++k2){
            float p = Pt[qrow][k2];
            float4 va = *(const float4*)&Vt[k2][sub*8];
            float4 vb = *(const float4*)&Vt[k2][sub*8 + 4];
            acc[0] += p*va.x; acc[1] += p*va.y; acc[2] += p*va.z; acc[3] += p*va.w;
            acc[4] += p*vb.x; acc[5] += p*vb.y; acc[6] += p*vb.z; acc[7] += p*vb.w;
        }
    }
    float invl = 1.f / l;
    #pragma unroll
    for (int j = 0; j < 8; ++j)
        O[(size_t)(q0+qrow)*CH + hoff + sub*8 + j] = acc[j]*invl;
}

// ---------------- LayerNorm(a + b) ----------------
__global__ __launch_bounds__(128) void ln_res_kernel(const float* __restrict__ a,
        const float* __restrict__ b, const float* __restrict__ g,
        const float* __restrict__ be, float* __restrict__ out){
    __shared__ float red[128];
    int t = threadIdx.x;
    size_t off = (size_t)blockIdx.y*NF + (size_t)blockIdx.x*CH;
    float v = a[off + t] + b[off + t];
    red[t] = v; __syncthreads();
    for (int o = 64; o; o >>= 1){ if (t < o) red[t] += red[t+o]; __syncthreads(); }
    float m = red[0] / 128.f;
    __syncthreads();
    float d = v - m;
    red[t] = d*d; __syncthreads();
    for (int o = 64; o; o >>= 1){ if (t < o) red[t] += red[t+o]; __syncthreads(); }
    float var = red[0] / 128.f;
    out[off + t] = (v - m)*rsqrtf(var + 1e-5f)*g[t] + be[t];
}

// ---------------- final gate ----------------
__global__ void combine_kernel(const float* __restrict__ xfo, const float* __restrict__ yfo,
        const float* __restrict__ x, const float* __restrict__ y, float* __restrict__ out){
    size_t idx = (size_t)blockIdx.x*256 + threadIdx.x;
    float s = xfo[idx] + yfo[idx];
    float w = 1.f/(1.f + __expf(-s));
    out[idx] = 2.f*x[idx]*w + 2.f*y[idx]*(1.f - w);
}

extern "C" void kernel_launch(void* const* d_in, const int* in_sizes, int n_in,
                              void* d_out, int out_size, void* d_ws, size_t ws_size,
                              hipStream_t stream){
    (void)in_sizes; (void)n_in; (void)out_size;
    const float* x    = (const float*)d_in[0];
    const float* y    = (const float*)d_in[1];
    const float* pos  = (const float*)d_in[2];
    const int*   nbr  = (const int*)  d_in[3];
    // d_in[4] = nbr_mask (bool) -- unused: mask == (idx != row)
    const float* Wx   = (const float*)d_in[5];
    const float* bx   = (const float*)d_in[6];
    const float* bnxg = (const float*)d_in[7];
    const float* bnxb = (const float*)d_in[8];
    const float* Wy   = (const float*)d_in[9];
    const float* by   = (const float*)d_in[10];
    const float* bnyg = (const float*)d_in[11];
    const float* bnyb = (const float*)d_in[12];
    const float* Wq   = (const float*)d_in[13];
    const float* bq   = (const float*)d_in[14];
    const float* Wk   = (const float*)d_in[15];
    const float* bk   = (const float*)d_in[16];
    const float* Wv   = (const float*)d_in[17];
    const float* bv   = (const float*)d_in[18];
    const float* Wo   = (const float*)d_in[19];
    const float* bo   = (const float*)d_in[20];
    const float* ln1g = (const float*)d_in[21];
    const float* ln1b = (const float*)d_in[22];
    const float* W1   = (const float*)d_in[23];
    const float* b1   = (const float*)d_in[24];
    const float* W2   = (const float*)d_in[25];
    const float* b2   = (const float*)d_in[26];
    const float* ln2g = (const float*)d_in[27];
    const float* ln2b = (const float*)d_in[28];

    float* ws     = (float*)d_ws;
    float* pe     = ws;
    float* hconv  = ws + (size_t)NF*1;    // 2 feats; later aliased as o
    float* xf     = ws + (size_t)NF*3;    // 2 feats; later aliased as xfo/yfo
    float* h      = ws + (size_t)NF*5;    // 2 feats; later aliased as o2
    float* q      = ws + (size_t)NF*7;    // 2 feats; later aliased as feat1
    float* k      = ws + (size_t)NF*9;    // 2 feats; later aliased as ff2
    float* v      = ws + (size_t)NF*11;   // 2 feats
    float* stats  = ws + (size_t)NF*13;   // 514 floats used, 2048 reserved
    float* ff1    = stats + 2048;         // 2 feats x 4096 x 512
    float* Abuf   = ff1 + (size_t)NF*8;
    float* o      = hconv;
    float* o2     = h;
    float* feat1  = q;
    float* ff2    = k;
    float* xfo    = xf;

    size_t fixedBytes = (size_t)(Abuf - ws) * sizeof(float);
    int chunk = 64;
    const int cand[6] = {4096, 2048, 1024, 512, 256, 128};
    for (int ci = 0; ci < 6; ++ci){
        size_t need = fixedBytes + (size_t)2*cand[ci]*8192*sizeof(float);
        if (need <= ws_size){ chunk = cand[ci]; break; }
    }

    pos_stats_kernel<<<1, 256, 0, stream>>>(pos, stats);
    pe_kernel<<<NPTS*64/256, 256, 0, stream>>>(pos, stats, pe);

    for (int base = 0; base < NPTS; base += chunk){
        build_A_kernel<<<dim3(chunk, 2), 128, 0, stream>>>(x, y, pos, nbr, Abuf, base, chunk);
        gemm_kernel<false><<<dim3(chunk/64, 2, 2), 256, 0, stream>>>(
            Abuf, Wx, Wy, bx, by, hconv + (size_t)base*CH,
            chunk, 8192, 128, (long)chunk*8192, (long)NF, 0);
    }

    bn_stats_kernel<<<dim3(128, 2), 256, 0, stream>>>(hconv, stats);
    bn_apply_kernel<<<dim3(NF/256, 2), 256, 0, stream>>>(hconv, stats, bnxg, bnxb, bnyg, bnyb, xf);
    addpe_kernel<<<dim3(NF/256, 2), 256, 0, stream>>>(xf, pe, h);

    gemm_kernel<true><<<dim3(64, 2, 2), 256, 0, stream>>>(h, Wq, nullptr, bq, nullptr, q,
        NPTS, 128, 128, (long)NF, (long)NF, 0);
    gemm_kernel<true><<<dim3(64, 2, 2), 256, 0, stream>>>(h, Wk, nullptr, bk, nullptr, k,
        NPTS, 128, 128, (long)NF, (long)NF, 0);
    gemm_kernel<true><<<dim3(64, 2, 2), 256, 0, stream>>>(h, Wv, nullptr, bv, nullptr, v,
        NPTS, 128, 128, (long)NF, (long)NF, 0);

    attn_kernel<<<dim3(64, 4, 2), 256, 0, stream>>>(q, k, v, o);

    gemm_kernel<true><<<dim3(64, 2, 2), 256, 0, stream>>>(o, Wo, nullptr, bo, nullptr, o2,
        NPTS, 128, 128, (long)NF, (long)NF, 0);
    ln_res_kernel<<<dim3(NPTS, 2), 128, 0, stream>>>(xf, o2, ln1g, ln1b, feat1);

    gemm_kernel<true><<<dim3(64, 8, 2), 256, 0, stream>>>(feat1, W1, nullptr, b1, nullptr, ff1,
        NPTS, 128, 512, (long)NF, (long)NPTS*FFD, 1);
    gemm_kernel<true><<<dim3(64, 2, 2), 256, 0, stream>>>(ff1, W2, nullptr, b2, nullptr, ff2,
        NPTS, 512, 128, (long)NPTS*FFD, (long)NF, 0);
    ln_res_kernel<<<dim3(NPTS, 2), 128, 0, stream>>>(feat1, ff2, ln2g, ln2b, xfo);

    combine_kernel<<<NF/256, 256, 0, stream>>>(xfo, xfo + NF, x, y, (float*)d_out);
}

// Round 2
// 1200.979 us; speedup vs baseline: 2.0878x; 2.0878x over previous
//
#include <hip/hip_runtime.h>
#include <cstddef>

#define NPTS 4096
#define KNBR 80
#define CH   128
#define NF   (NPTS*CH)      // 524288
#define FFD  512
#define KSPLIT 8

typedef unsigned short ushort_t;
typedef short bf16x8 __attribute__((ext_vector_type(8)));
typedef float f32x4 __attribute__((ext_vector_type(4)));

__device__ __forceinline__ float dot4f(float4 a, float4 b){
    return a.x*b.x + a.y*b.y + a.z*b.z + a.w*b.w;
}

__device__ __forceinline__ unsigned short f2bf(float f){
    unsigned int u = __float_as_uint(f);
    unsigned int r = (u + 0x7FFFu + ((u >> 16) & 1u)) >> 16;
    return (unsigned short)r;
}

__device__ __forceinline__ void load_lds16(const ushort_t* g, ushort_t* l){
    __builtin_amdgcn_global_load_lds(
        (const __attribute__((address_space(1))) unsigned int*)g,
        (__attribute__((address_space(3))) unsigned int*)l, 16, 0, 0);
}

// ---------------- pos stats ----------------
__global__ void pos_stats_kernel(const float* __restrict__ pos, float* __restrict__ stats){
    __shared__ float red[256];
    int t = threadIdx.x;
    float s = 0.f;
    for (int i = t; i < NPTS; i += 256) s += pos[(size_t)i*3];
    red[t] = s; __syncthreads();
    for (int o = 128; o; o >>= 1){ if (t < o) red[t] += red[t+o]; __syncthreads(); }
    float mean = red[0] / (float)NPTS;
    __syncthreads();
    float ss = 0.f;
    for (int i = t; i < NPTS; i += 256){ float d = pos[(size_t)i*3] - mean; ss += d*d; }
    red[t] = ss; __syncthreads();
    for (int o = 128; o; o >>= 1){ if (t < o) red[t] += red[t+o]; __syncthreads(); }
    if (t == 0){
        float sd = sqrtf(red[0] / (float)(NPTS-1));
        stats[512] = mean;
        stats[513] = 1.f/(sd + 1e-8f);
    }
}

// ---------------- positional encoding ----------------
__global__ void pe_kernel(const float* __restrict__ pos, const float* __restrict__ stats,
                          float* __restrict__ pe){
    int t = blockIdx.x*256 + threadIdx.x;
    int i = t >> 6, m = t & 63;
    float px = (pos[(size_t)i*3] - stats[512]) * stats[513];
    float dv = expf((float)(2*m) * -0.07195578415606394f);
    float ang = px * dv;
    float sv, cv;
    sincosf(ang, &sv, &cv);
    pe[(size_t)i*CH + 2*m]     = sv;
    pe[(size_t)i*CH + 2*m + 1] = cv;
}

// ---------------- W transpose+cast: Wt[f][n][k] = W_f[k][n] (bf16) ----------------
__global__ __launch_bounds__(256) void wt_kernel(const float* __restrict__ Wx,
        const float* __restrict__ Wy, ushort_t* __restrict__ Wt){
    __shared__ float tile[32][33];
    const float* W = blockIdx.z ? Wy : Wx;
    int kb = blockIdx.x, nb = blockIdx.y;
    int tr = threadIdx.x & 31, tc = threadIdx.x >> 5;   // tc 0..7
    #pragma unroll
    for (int rr = 0; rr < 32; rr += 8)
        tile[tc+rr][tr] = W[(size_t)(kb*32 + tc + rr)*128 + nb*32 + tr];
    __syncthreads();
    size_t fo = (size_t)blockIdx.z * 8192 * 128;
    #pragma unroll
    for (int rr = 0; rr < 32; rr += 8)
        Wt[fo + (size_t)(nb*32 + tc + rr)*8192 + kb*32 + tr] = f2bf(tile[tr][tc+rr]);
}

// ---------------- cconv stage 1: per-point C@F -> A (bf16) ----------------
// block = 1 point, 256 threads. Geometry once per neighbor, compacted.
__global__ __launch_bounds__(256, 2) void cf_kernel(
        const float* __restrict__ xin, const float* __restrict__ yin,
        const float* __restrict__ pos, const int* __restrict__ nbr,
        ushort_t* __restrict__ Abuf, int base, int chunk){
    __shared__ __align__(16) float F[KNBR][128];
    __shared__ __align__(16) float Ct[KNBR][64];
    __shared__ int nbl[KNBR];
    __shared__ int cnt;
    int i = base + blockIdx.x;
    int t = threadIdx.x;
    if (t == 0) cnt = 0;
    for (int z = t; z < KNBR*64; z += 256) (&Ct[0][0])[z] = 0.f;
    __syncthreads();
    if (t < KNBR){
        int nb = nbr[(size_t)i*KNBR + t];
        if (nb != i){
            float p0 = pos[(size_t)i*3], p1 = pos[(size_t)i*3+1], p2 = pos[(size_t)i*3+2];
            const float RAD = 0.1125f;
            float rx = (pos[(size_t)nb*3+0]-p0)/RAD;
            float ry = (pos[(size_t)nb*3+1]-p1)/RAD;
            float rz = (pos[(size_t)nb*3+2]-p2)/RAD;
            float r2 = rx*rx + ry*ry + rz*rz;
            float w1 = 1.f - r2;
            float win = fminf(fmaxf(w1*w1*w1, 0.f), 1.f);
            float nrm = sqrtf(fmaxf(r2, 1e-12f));
            float linf = fmaxf(fmaxf(fabsf(rx), fabsf(ry)), fabsf(rz));
            linf = fmaxf(linf, 1e-9f);
            float sc = nrm/linf;
            float gx = fminf(fmaxf((rx*sc+1.f)*0.5f*3.f, 0.f), 3.f);
            float gy = fminf(fmaxf((ry*sc+1.f)*0.5f*3.f, 0.f), 3.f);
            float gz = fminf(fmaxf((rz*sc+1.f)*0.5f*3.f, 0.f), 3.f);
            float fx = fminf(floorf(gx), 2.f), fy = fminf(floorf(gy), 2.f), fz = fminf(floorf(gz), 2.f);
            float tx = gx-fx, ty = gy-fy, tz = gz-fz;
            int ix = (int)fx, iy = (int)fy, iz = (int)fz;
            int cb = (ix<<4) + (iy<<2) + iz;
            float x0 = (1.f-tx)*win, x1 = tx*win;
            float w00 = x0*(1.f-ty), w01 = x0*ty, w10 = x1*(1.f-ty), w11 = x1*ty;
            float z0 = 1.f-tz, z1 = tz;
            int slot = atomicAdd(&cnt, 1);
            nbl[slot] = nb;
            Ct[slot][cb     ] = w00*z0;
            Ct[slot][cb + 1 ] = w00*z1;
            Ct[slot][cb + 4 ] = w01*z0;
            Ct[slot][cb + 5 ] = w01*z1;
            Ct[slot][cb + 16] = w10*z0;
            Ct[slot][cb + 17] = w10*z1;
            Ct[slot][cb + 20] = w11*z0;
            Ct[slot][cb + 21] = w11*z1;
        }
    }
    __syncthreads();
    int n = cnt;
    int g4 = t >> 4, c8 = t & 15;
    int cl = t & 127;
    for (int f = 0; f < 2; ++f){
        const float* feat = f ? yin : xin;
        __syncthreads();   // previous compute done before F overwrite
        for (int j = (t >> 7); j < n; j += 2)
            F[j][cl] = feat[(size_t)nbl[j]*128 + cl];
        __syncthreads();
        float acc[4][8] = {};
        for (int j = 0; j < n; ++j){
            float4 cw = *(const float4*)&Ct[j][g4*4];
            float4 f0 = *(const float4*)&F[j][c8*8];
            float4 f1 = *(const float4*)&F[j][c8*8 + 4];
            float cwv[4] = {cw.x, cw.y, cw.z, cw.w};
            float fv[8]  = {f0.x, f0.y, f0.z, f0.w, f1.x, f1.y, f1.z, f1.w};
            #pragma unroll
            for (int r = 0; r < 4; ++r)
                #pragma unroll
                for (int c = 0; c < 8; ++c)
                    acc[r][c] += cwv[r]*fv[c];
        }
        ushort_t* dst = Abuf + ((size_t)f*chunk + blockIdx.x)*8192;
        #pragma unroll
        for (int r = 0; r < 4; ++r){
            uint4 pk;
            pk.x = (unsigned)f2bf(acc[r][0]) | ((unsigned)f2bf(acc[r][1]) << 16);
            pk.y = (unsigned)f2bf(acc[r][2]) | ((unsigned)f2bf(acc[r][3]) << 16);
            pk.z = (unsigned)f2bf(acc[r][4]) | ((unsigned)f2bf(acc[r][5]) << 16);
            pk.w = (unsigned)f2bf(acc[r][6]) | ((unsigned)f2bf(acc[r][7]) << 16);
            *(uint4*)(dst + (size_t)(g4*4 + r)*128 + c8*8) = pk;
        }
    }
}

// ---------------- cconv stage 2: MFMA GEMM  P = A(bf16) @ Wt^T, split-K ----------------
// grid (chunk/128, 1, 2*KSPLIT), 256 threads (4 waves, 2x2 of 64x64)
__global__ __launch_bounds__(256) void mfma_gemm_kernel(
        const ushort_t* __restrict__ Abuf, const ushort_t* __restrict__ Wt,
        float* __restrict__ Pbuf, int chunk){
    __shared__ ushort_t Asm[128*64];
    __shared__ ushort_t Bsm[128*64];
    int tid = threadIdx.x, lane = tid & 63, w = tid >> 6;
    int feat = blockIdx.z >> 3, s = blockIdx.z & 7;
    const ushort_t* Ab = Abuf + (size_t)feat*chunk*8192 + (size_t)blockIdx.x*128*8192;
    const ushort_t* Bb = Wt + (size_t)feat*128*8192;
    int wm = w >> 1, wn = w & 1;
    int lr = lane >> 3, pb = lane & 7, lb = pb ^ lr;   // XOR swizzle source block
    int quad = lane >> 4, l15 = lane & 15;
    int arow0 = w*32;
    f32x4 acc[4][4] = {};
    const int kk0 = s*(8192/KSPLIT), kk1 = kk0 + 8192/KSPLIT;
    for (int kk = kk0; kk < kk1; kk += 64){
        __syncthreads();
        #pragma unroll
        for (int q = 0; q < 4; ++q){
            int r = arow0 + q*8 + lr;
            load_lds16(Ab + (size_t)r*8192 + kk + lb*8, Asm + (arow0 + q*8)*64);
            load_lds16(Bb + (size_t)r*8192 + kk + lb*8, Bsm + (arow0 + q*8)*64);
        }
        __syncthreads();
        #pragma unroll
        for (int h = 0; h < 2; ++h){
            bf16x8 aF[4], bF[4];
            #pragma unroll
            for (int mt = 0; mt < 4; ++mt){
                int ml = wm*64 + mt*16 + l15;
                int p = (h*4 + quad) ^ (ml & 7);
                aF[mt] = *(const bf16x8*)(Asm + ml*64 + p*8);
            }
            #pragma unroll
            for (int nt = 0; nt < 4; ++nt){
                int nl = wn*64 + nt*16 + l15;
                int p = (h*4 + quad) ^ (nl & 7);
                bF[nt] = *(const bf16x8*)(Bsm + nl*64 + p*8);
            }
            #pragma unroll
            for (int mt = 0; mt < 4; ++mt)
                #pragma unroll
                for (int nt = 0; nt < 4; ++nt)
                    acc[mt][nt] = __builtin_amdgcn_mfma_f32_16x16x32_bf16(
                        aF[mt], bF[nt], acc[mt][nt], 0, 0, 0);
        }
    }
    float* P = Pbuf + (size_t)blockIdx.z*chunk*128 + (size_t)blockIdx.x*128*128;
    #pragma unroll
    for (int mt = 0; mt < 4; ++mt)
        #pragma unroll
        for (int nt = 0; nt < 4; ++nt)
            #pragma unroll
            for (int reg = 0; reg < 4; ++reg){
                int r = wm*64 + mt*16 + quad*4 + reg;
                int c = wn*64 + nt*16 + l15;
                P[(size_t)r*128 + c] = acc[mt][nt][reg];
            }
}

__global__ void reduceP_kernel(const float* __restrict__ P, float* __restrict__ hconv,
                               int chunk, int base){
    int f = blockIdx.y;
    size_t idx = (size_t)blockIdx.x*256 + threadIdx.x;   // < chunk*128
    float s = 0.f;
    #pragma unroll
    for (int sp = 0; sp < KSPLIT; ++sp)
        s += P[((size_t)(f*KSPLIT + sp))*chunk*128 + idx];
    hconv[(size_t)f*NF + (size_t)base*128 + idx] = s;
}

// ---------------- generic fp32 tiled GEMM (qkv / o / ff) ----------------
template<bool WT>
__global__ __launch_bounds__(256) void gemm_kernel(
        const float* __restrict__ A, const float* __restrict__ W0, const float* __restrict__ W1p,
        const float* __restrict__ b0, const float* __restrict__ b1p,
        float* __restrict__ out, int M, int Cin, int Dout,
        long aZ, long oZ, int relu){
    __shared__ __align__(16) float As[64][36];
    __shared__ __align__(16) float Ws[64][36];
    const float* W    = (blockIdx.z && W1p) ? W1p : W0;
    const float* bias = (blockIdx.z && b1p) ? b1p : b0;
    A   += (long)blockIdx.z * aZ;
    out += (long)blockIdx.z * oZ;
    int r0 = blockIdx.x*64, c0 = blockIdx.y*64;
    int tid = threadIdx.x;
    int rg = tid >> 4, cg = tid & 15;
    float acc[4][4] = {};
    for (int kk = 0; kk < Cin; kk += 32){
        #pragma unroll
        for (int rep = 0; rep < 2; ++rep){
            int idx = tid + rep*256;
            int r = idx >> 3, k4 = (idx & 7)*4;
            *(float4*)&As[r][k4] = *(const float4*)&A[(size_t)(r0+r)*Cin + kk + k4];
        }
        if (WT){
            #pragma unroll
            for (int rep = 0; rep < 2; ++rep){
                int idx = tid + rep*256;
                int c = idx >> 3, k4 = (idx & 7)*4;
                *(float4*)&Ws[c][k4] = *(const float4*)&W[(size_t)(c0+c)*Cin + kk + k4];
            }
        } else {
            #pragma unroll
            for (int rep = 0; rep < 8; ++rep){
                int idx = tid + rep*256;
                int cc = idx & 63, kx = idx >> 6;
                Ws[cc][kx] = W[(size_t)(kk+kx)*Dout + c0 + cc];
            }
        }
        __syncthreads();
        #pragma unroll
        for (int k4 = 0; k4 < 32; k4 += 4){
            float4 a[4], wv[4];
            #pragma unroll
            for (int i = 0; i < 4; ++i) a[i] = *(const float4*)&As[rg*4+i][k4];
            #pragma unroll
            for (int j = 0; j < 4; ++j) wv[j] = *(const float4*)&Ws[cg*4+j][k4];
            #pragma unroll
            for (int i = 0; i < 4; ++i)
                #pragma unroll
                for (int j = 0; j < 4; ++j)
                    acc[i][j] += dot4f(a[i], wv[j]);
        }
        __syncthreads();
    }
    #pragma unroll
    for (int i = 0; i < 4; ++i){
        int r = r0 + rg*4 + i;
        #pragma unroll
        for (int j = 0; j < 4; ++j){
            int c = c0 + cg*4 + j;
            float v = acc[i][j] + (bias ? bias[c] : 0.f);
            if (relu) v = fmaxf(v, 0.f);
            out[(size_t)r*Dout + c] = v;
        }
    }
}

// ---------------- BatchNorm ----------------
__global__ void bn_stats_kernel(const float* __restrict__ hconv, float* __restrict__ stats){
    __shared__ float rs[256];
    __shared__ float rq[256];
    int ch = blockIdx.x, f = blockIdx.y, t = threadIdx.x;
    const float* src = hconv + (size_t)f*NF;
    float s = 0.f, q2 = 0.f;
    for (int r = t; r < NPTS; r += 256){
        float vv = src[(size_t)r*CH + ch];
        s += vv; q2 += vv*vv;
    }
    rs[t] = s; rq[t] = q2; __syncthreads();
    for (int o = 128; o; o >>= 1){
        if (t < o){ rs[t] += rs[t+o]; rq[t] += rq[t+o]; }
        __syncthreads();
    }
    if (t == 0){
        float m = rs[0]/(float)NPTS;
        float var = rq[0]/(float)NPTS - m*m;
        stats[f*128 + ch] = m;
        stats[256 + f*128 + ch] = rsqrtf(var + 1e-5f);
    }
}

__global__ void bn_apply_kernel(const float* __restrict__ hconv, const float* __restrict__ stats,
        const float* __restrict__ gx, const float* __restrict__ bxp,
        const float* __restrict__ gy, const float* __restrict__ byp,
        float* __restrict__ xf){
    int f = blockIdx.y;
    size_t idx = (size_t)blockIdx.x*256 + threadIdx.x;
    int ch = idx & 127;
    const float* g = f ? gy : gx;
    const float* b = f ? byp : bxp;
    float m = stats[f*128 + ch], inv = stats[256 + f*128 + ch];
    float vv = hconv[(size_t)f*NF + idx];
    xf[(size_t)f*NF + idx] = fmaxf((vv - m)*inv*g[ch] + b[ch], 0.f);
}

__global__ void addpe_kernel(const float* __restrict__ xf, const float* __restrict__ pe,
                             float* __restrict__ h){
    int f = blockIdx.y;
    size_t idx = (size_t)blockIdx.x*256 + threadIdx.x;
    h[(size_t)f*NF + idx] = xf[(size_t)f*NF + idx] + pe[idx];
}

// ---------------- flash attention (fp32) ----------------
__global__ __launch_bounds__(256) void attn_kernel(const float* __restrict__ qg,
        const float* __restrict__ kg, const float* __restrict__ vg, float* __restrict__ og){
    __shared__ __align__(16) float Kt[64][36];
    __shared__ __align__(16) float Vt[64][36];
    __shared__ float Pt[64][65];
    int q0 = blockIdx.x*64, hoff = blockIdx.y*32;
    size_t zo = (size_t)blockIdx.z * NF;
    const float* Q = qg + zo; const float* K = kg + zo; const float* V = vg + zo;
    float* O = og + zo;
    int tid = threadIdx.x, qrow = tid >> 2, sub = tid & 3;
    float qv[32];
    #pragma unroll
    for (int c = 0; c < 32; ++c)
        qv[c] = Q[(size_t)(q0+qrow)*CH + hoff + c] * 0.17677669529663687f;
    float acc[8] = {0,0,0,0,0,0,0,0};
    float mprev = -3.0e38f, l = 0.f;
    for (int kt = 0; kt < 64; ++kt){
        int k0 = kt*64;
        __syncthreads();
        #pragma unroll
        for (int rep = 0; rep < 2; ++rep){
            int idx = tid + rep*256;
            int r = idx >> 3, c4 = (idx & 7)*4;
            *(float4*)&Kt[r][c4] = *(const float4*)&K[(size_t)(k0+r)*CH + hoff + c4];
            *(float4*)&Vt[r][c4] = *(const float4*)&V[(size_t)(k0+r)*CH + hoff + c4];
        }
        __syncthreads();
        float sv[16];
        float mloc = -3.0e38f;
        #pragma unroll
        for (int u = 0; u < 16; ++u){
            int ky = sub*16 + u;
            float s = 0.f;
            #pragma unroll
            for (int c4 = 0; c4 < 32; c4 += 4){
                float4 kv = *(const float4*)&Kt[ky][c4];
                s += qv[c4]*kv.x + qv[c4+1]*kv.y + qv[c4+2]*kv.z + qv[c4+3]*kv.w;
            }
            sv[u] = s;
            mloc = fmaxf(mloc, s);
        }
        mloc = fmaxf(mloc, __shfl_xor(mloc, 1));
        mloc = fmaxf(mloc, __shfl_xor(mloc, 2));
        float mnew = fmaxf(mprev, mloc);
        float alpha = __expf(mprev - mnew);
        float sump = 0.f;
        #pragma unroll
        for (int u = 0; u < 16; ++u){
            float p = __expf(sv[u] - mnew);
            Pt[qrow][sub*16 + u] = p;
            sump += p;
        }
        sump += __shfl_xor(sump, 1);
        sump += __shfl_xor(sump, 2);
        l = l*alpha + sump;
        #pragma unroll
        for (int j = 0; j < 8; ++j) acc[j] *= alpha;
        mprev = mnew;
        __syncthreads();
        for (int k2 = 0; k2 < 64; ++k2){
            float p = Pt[qrow][k2];
            float4 va = *(const float4*)&Vt[k2][sub*8];
            float4 vb = *(const float4*)&Vt[k2][sub*8 + 4];
            acc[0] += p*va.x; acc[1] += p*va.y; acc[2] += p*va.z; acc[3] += p*va.w;
            acc[4] += p*vb.x; acc[5] += p*vb.y; acc[6] += p*vb.z; acc[7] += p*vb.w;
        }
    }
    float invl = 1.f / l;
    #pragma unroll
    for (int j = 0; j < 8; ++j)
        O[(size_t)(q0+qrow)*CH + hoff + sub*8 + j] = acc[j]*invl;
}

// ---------------- LayerNorm(a + b) ----------------
__global__ __launch_bounds__(128) void ln_res_kernel(const float* __restrict__ a,
        const float* __restrict__ b, const float* __restrict__ g,
        const float* __restrict__ be, float* __restrict__ out){
    __shared__ float red[128];
    int t = threadIdx.x;
    size_t off = (size_t)blockIdx.y*NF + (size_t)blockIdx.x*CH;
    float v = a[off + t] + b[off + t];
    red[t] = v; __syncthreads();
    for (int o = 64; o; o >>= 1){ if (t < o) red[t] += red[t+o]; __syncthreads(); }
    float m = red[0] / 128.f;
    __syncthreads();
    float d = v - m;
    red[t] = d*d; __syncthreads();
    for (int o = 64; o; o >>= 1){ if (t < o) red[t] += red[t+o]; __syncthreads(); }
    float var = red[0] / 128.f;
    out[off + t] = (v - m)*rsqrtf(var + 1e-5f)*g[t] + be[t];
}

__global__ void combine_kernel(const float* __restrict__ xfo, const float* __restrict__ yfo,
        const float* __restrict__ x, const float* __restrict__ y, float* __restrict__ out){
    size_t idx = (size_t)blockIdx.x*256 + threadIdx.x;
    float s = xfo[idx] + yfo[idx];
    float w = 1.f/(1.f + __expf(-s));
    out[idx] = 2.f*x[idx]*w + 2.f*y[idx]*(1.f - w);
}

extern "C" void kernel_launch(void* const* d_in, const int* in_sizes, int n_in,
                              void* d_out, int out_size, void* d_ws, size_t ws_size,
                              hipStream_t stream){
    (void)in_sizes; (void)n_in; (void)out_size;
    const float* x    = (const float*)d_in[0];
    const float* y    = (const float*)d_in[1];
    const float* pos  = (const float*)d_in[2];
    const int*   nbr  = (const int*)  d_in[3];
    const float* Wx   = (const float*)d_in[5];
    const float* bnxg = (const float*)d_in[7];
    const float* bnxb = (const float*)d_in[8];
    const float* Wy   = (const float*)d_in[9];
    const float* bnyg = (const float*)d_in[11];
    const float* bnyb = (const float*)d_in[12];
    const float* Wq   = (const float*)d_in[13];
    const float* bq   = (const float*)d_in[14];
    const float* Wk   = (const float*)d_in[15];
    const float* bk   = (const float*)d_in[16];
    const float* Wv   = (const float*)d_in[17];
    const float* bv   = (const float*)d_in[18];
    const float* Wo   = (const float*)d_in[19];
    const float* bo   = (const float*)d_in[20];
    const float* ln1g = (const float*)d_in[21];
    const float* ln1b = (const float*)d_in[22];
    const float* W1   = (const float*)d_in[23];
    const float* b1   = (const float*)d_in[24];
    const float* W2   = (const float*)d_in[25];
    const float* b2   = (const float*)d_in[26];
    const float* ln2g = (const float*)d_in[27];
    const float* ln2b = (const float*)d_in[28];

    float* ws     = (float*)d_ws;
    float* pe     = ws;
    float* hconv  = ws + (size_t)NF*1;
    float* xf     = ws + (size_t)NF*3;
    float* h      = ws + (size_t)NF*5;
    float* q      = ws + (size_t)NF*7;
    float* k      = ws + (size_t)NF*9;
    float* v      = ws + (size_t)NF*11;
    float* stats  = ws + (size_t)NF*13;
    float* ff1    = stats + 2048;                 // 4*NF
    float* Pbuf   = ff1 + (size_t)4*NF;
    float* o      = hconv;
    float* o2     = h;
    float* feat1  = q;
    float* ff2    = k;
    float* xfo    = xf;

    const size_t fixedFloats = (size_t)17*NF + 2048;
    int chunk = 128;
    const int cand[6] = {4096, 2048, 1024, 512, 256, 128};
    for (int ci = 0; ci < 6; ++ci){
        size_t need = (fixedFloats + (size_t)1048576 + (size_t)10240*cand[ci]) * 4;
        if (need <= ws_size){ chunk = cand[ci]; break; }
    }
    ushort_t* Wt   = (ushort_t*)(Pbuf + (size_t)2048*chunk);
    ushort_t* Abuf = Wt + (size_t)2*8192*128;

    pos_stats_kernel<<<1, 256, 0, stream>>>(pos, stats);
    pe_kernel<<<NPTS*64/256, 256, 0, stream>>>(pos, stats, pe);
    wt_kernel<<<dim3(256, 4, 2), 256, 0, stream>>>(Wx, Wy, Wt);

    for (int base = 0; base < NPTS; base += chunk){
        cf_kernel<<<chunk, 256, 0, stream>>>(x, y, pos, nbr, Abuf, base, chunk);
        mfma_gemm_kernel<<<dim3(chunk/128, 1, 2*KSPLIT), 256, 0, stream>>>(Abuf, Wt, Pbuf, chunk);
        reduceP_kernel<<<dim3(chunk*128/256, 2), 256, 0, stream>>>(Pbuf, hconv, chunk, base);
    }

    bn_stats_kernel<<<dim3(128, 2), 256, 0, stream>>>(hconv, stats);
    bn_apply_kernel<<<dim3(NF/256, 2), 256, 0, stream>>>(hconv, stats, bnxg, bnxb, bnyg, bnyb, xf);
    addpe_kernel<<<dim3(NF/256, 2), 256, 0, stream>>>(xf, pe, h);

    gemm_kernel<true><<<dim3(64, 2, 2), 256, 0, stream>>>(h, Wq, nullptr, bq, nullptr, q,
        NPTS, 128, 128, (long)NF, (long)NF, 0);
    gemm_kernel<true><<<dim3(64, 2, 2), 256, 0, stream>>>(h, Wk, nullptr, bk, nullptr, k,
        NPTS, 128, 128, (long)NF, (long)NF, 0);
    gemm_kernel<true><<<dim3(64, 2, 2), 256, 0, stream>>>(h, Wv, nullptr, bv, nullptr, v,
        NPTS, 128, 128, (long)NF, (long)NF, 0);

    attn_kernel<<<dim3(64, 4, 2), 256, 0, stream>>>(q, k, v, o);

    gemm_kernel<true><<<dim3(64, 2, 2), 256, 0, stream>>>(o, Wo, nullptr, bo, nullptr, o2,
        NPTS, 128, 128, (long)NF, (long)NF, 0);
    ln_res_kernel<<<dim3(NPTS, 2), 128, 0, stream>>>(xf, o2, ln1g, ln1b, feat1);

    gemm_kernel<true><<<dim3(64, 8, 2), 256, 0, stream>>>(feat1, W1, nullptr, b1, nullptr, ff1,
        NPTS, 128, 512, (long)NF, (long)NPTS*FFD, 1);
    gemm_kernel<true><<<dim3(64, 2, 2), 256, 0, stream>>>(ff1, W2, nullptr, b2, nullptr, ff2,
        NPTS, 512, 128, (long)NPTS*FFD, (long)NF, 0);
    ln_res_kernel<<<dim3(NPTS, 2), 128, 0, stream>>>(feat1, ff2, ln2g, ln2b, xfo);

    combine_kernel<<<NF/256, 256, 0, stream>>>(xfo, xfo + NF, x, y, (float*)d_out);
}

// Round 3
// 500.575 us; speedup vs baseline: 5.0090x; 2.3992x over previous
//
#include <hip/hip_runtime.h>
#include <cstddef>

#define NPTS 4096
#define KNBR 80
#define CH   128
#define NF   (NPTS*CH)      // 524288
#define FFD  512
#define KSPLIT 8

typedef unsigned short ushort_t;
typedef short bf16x8 __attribute__((ext_vector_type(8)));
typedef float f32x4 __attribute__((ext_vector_type(4)));

__device__ __forceinline__ float dot4f(float4 a, float4 b){
    return a.x*b.x + a.y*b.y + a.z*b.z + a.w*b.w;
}

__device__ __forceinline__ unsigned short f2bf(float f){
    unsigned int u = __float_as_uint(f);
    unsigned int r = (u + 0x7FFFu + ((u >> 16) & 1u)) >> 16;
    return (unsigned short)r;
}

__device__ __forceinline__ unsigned pack2bf(float a, float b){
    return (unsigned)f2bf(a) | ((unsigned)f2bf(b) << 16);
}

__device__ __forceinline__ void load_lds16(const ushort_t* g, ushort_t* l){
    __builtin_amdgcn_global_load_lds(
        (const __attribute__((address_space(1))) unsigned int*)g,
        (__attribute__((address_space(3))) unsigned int*)l, 16, 0, 0);
}

// ---------------- pos stats ----------------
__global__ void pos_stats_kernel(const float* __restrict__ pos, float* __restrict__ stats){
    __shared__ float red[256];
    int t = threadIdx.x;
    float s = 0.f;
    for (int i = t; i < NPTS; i += 256) s += pos[(size_t)i*3];
    red[t] = s; __syncthreads();
    for (int o = 128; o; o >>= 1){ if (t < o) red[t] += red[t+o]; __syncthreads(); }
    float mean = red[0] / (float)NPTS;
    __syncthreads();
    float ss = 0.f;
    for (int i = t; i < NPTS; i += 256){ float d = pos[(size_t)i*3] - mean; ss += d*d; }
    red[t] = ss; __syncthreads();
    for (int o = 128; o; o >>= 1){ if (t < o) red[t] += red[t+o]; __syncthreads(); }
    if (t == 0){
        float sd = sqrtf(red[0] / (float)(NPTS-1));
        stats[512] = mean;
        stats[513] = 1.f/(sd + 1e-8f);
    }
}

// ---------------- positional encoding ----------------
__global__ void pe_kernel(const float* __restrict__ pos, const float* __restrict__ stats,
                          float* __restrict__ pe){
    int t = blockIdx.x*256 + threadIdx.x;
    int i = t >> 6, m = t & 63;
    float px = (pos[(size_t)i*3] - stats[512]) * stats[513];
    float dv = expf((float)(2*m) * -0.07195578415606394f);
    float ang = px * dv;
    float sv, cv;
    sincosf(ang, &sv, &cv);
    pe[(size_t)i*CH + 2*m]     = sv;
    pe[(size_t)i*CH + 2*m + 1] = cv;
}

// ---------------- W transpose+cast: Wt[f][n][k] = W_f[k][n] (bf16) ----------------
__global__ __launch_bounds__(256) void wt_kernel(const float* __restrict__ Wx,
        const float* __restrict__ Wy, ushort_t* __restrict__ Wt){
    __shared__ float tile[32][33];
    const float* W = blockIdx.z ? Wy : Wx;
    int kb = blockIdx.x, nb = blockIdx.y;
    int tr = threadIdx.x & 31, tc = threadIdx.x >> 5;   // tc 0..7
    #pragma unroll
    for (int rr = 0; rr < 32; rr += 8)
        tile[tc+rr][tr] = W[(size_t)(kb*32 + tc + rr)*128 + nb*32 + tr];
    __syncthreads();
    size_t fo = (size_t)blockIdx.z * 8192 * 128;
    #pragma unroll
    for (int rr = 0; rr < 32; rr += 8)
        Wt[fo + (size_t)(nb*32 + tc + rr)*8192 + kb*32 + tr] = f2bf(tile[tr][tc+rr]);
}

// ---------------- cconv stage 1: per-point C@F -> A (bf16) ----------------
__global__ __launch_bounds__(256, 2) void cf_kernel(
        const float* __restrict__ xin, const float* __restrict__ yin,
        const float* __restrict__ pos, const int* __restrict__ nbr,
        ushort_t* __restrict__ Abuf, int base, int chunk){
    __shared__ __align__(16) float F[KNBR][128];
    __shared__ __align__(16) float Ct[KNBR][64];
    __shared__ int nbl[KNBR];
    __shared__ int cnt;
    int i = base + blockIdx.x;
    int t = threadIdx.x;
    if (t == 0) cnt = 0;
    for (int z = t; z < KNBR*64; z += 256) (&Ct[0][0])[z] = 0.f;
    __syncthreads();
    if (t < KNBR){
        int nb = nbr[(size_t)i*KNBR + t];
        if (nb != i){
            float p0 = pos[(size_t)i*3], p1 = pos[(size_t)i*3+1], p2 = pos[(size_t)i*3+2];
            const float RAD = 0.1125f;
            float rx = (pos[(size_t)nb*3+0]-p0)/RAD;
            float ry = (pos[(size_t)nb*3+1]-p1)/RAD;
            float rz = (pos[(size_t)nb*3+2]-p2)/RAD;
            float r2 = rx*rx + ry*ry + rz*rz;
            float w1 = 1.f - r2;
            float win = fminf(fmaxf(w1*w1*w1, 0.f), 1.f);
            float nrm = sqrtf(fmaxf(r2, 1e-12f));
            float linf = fmaxf(fmaxf(fabsf(rx), fabsf(ry)), fabsf(rz));
            linf = fmaxf(linf, 1e-9f);
            float sc = nrm/linf;
            float gx = fminf(fmaxf((rx*sc+1.f)*0.5f*3.f, 0.f), 3.f);
            float gy = fminf(fmaxf((ry*sc+1.f)*0.5f*3.f, 0.f), 3.f);
            float gz = fminf(fmaxf((rz*sc+1.f)*0.5f*3.f, 0.f), 3.f);
            float fx = fminf(floorf(gx), 2.f), fy = fminf(floorf(gy), 2.f), fz = fminf(floorf(gz), 2.f);
            float tx = gx-fx, ty = gy-fy, tz = gz-fz;
            int ix = (int)fx, iy = (int)fy, iz = (int)fz;
            int cb = (ix<<4) + (iy<<2) + iz;
            float x0 = (1.f-tx)*win, x1 = tx*win;
            float w00 = x0*(1.f-ty), w01 = x0*ty, w10 = x1*(1.f-ty), w11 = x1*ty;
            float z0 = 1.f-tz, z1 = tz;
            int slot = atomicAdd(&cnt, 1);
            nbl[slot] = nb;
            Ct[slot][cb     ] = w00*z0;
            Ct[slot][cb + 1 ] = w00*z1;
            Ct[slot][cb + 4 ] = w01*z0;
            Ct[slot][cb + 5 ] = w01*z1;
            Ct[slot][cb + 16] = w10*z0;
            Ct[slot][cb + 17] = w10*z1;
            Ct[slot][cb + 20] = w11*z0;
            Ct[slot][cb + 21] = w11*z1;
        }
    }
    __syncthreads();
    int n = cnt;
    int g4 = t >> 4, c8 = t & 15;
    int cl = t & 127;
    for (int f = 0; f < 2; ++f){
        const float* feat = f ? yin : xin;
        __syncthreads();
        for (int j = (t >> 7); j < n; j += 2)
            F[j][cl] = feat[(size_t)nbl[j]*128 + cl];
        __syncthreads();
        float acc[4][8] = {};
        for (int j = 0; j < n; ++j){
            float4 cw = *(const float4*)&Ct[j][g4*4];
            float4 f0 = *(const float4*)&F[j][c8*8];
            float4 f1 = *(const float4*)&F[j][c8*8 + 4];
            float cwv[4] = {cw.x, cw.y, cw.z, cw.w};
            float fv[8]  = {f0.x, f0.y, f0.z, f0.w, f1.x, f1.y, f1.z, f1.w};
            #pragma unroll
            for (int r = 0; r < 4; ++r)
                #pragma unroll
                for (int c = 0; c < 8; ++c)
                    acc[r][c] += cwv[r]*fv[c];
        }
        ushort_t* dst = Abuf + ((size_t)f*chunk + blockIdx.x)*8192;
        #pragma unroll
        for (int r = 0; r < 4; ++r){
            uint4 pk;
            pk.x = pack2bf(acc[r][0], acc[r][1]);
            pk.y = pack2bf(acc[r][2], acc[r][3]);
            pk.z = pack2bf(acc[r][4], acc[r][5]);
            pk.w = pack2bf(acc[r][6], acc[r][7]);
            *(uint4*)(dst + (size_t)(g4*4 + r)*128 + c8*8) = pk;
        }
    }
}

// ---------------- cconv stage 2: MFMA GEMM  P = A(bf16) @ Wt^T, split-K ----------------
__global__ __launch_bounds__(256) void mfma_gemm_kernel(
        const ushort_t* __restrict__ Abuf, const ushort_t* __restrict__ Wt,
        float* __restrict__ Pbuf, int chunk){
    __shared__ ushort_t Asm[128*64];
    __shared__ ushort_t Bsm[128*64];
    int tid = threadIdx.x, lane = tid & 63, w = tid >> 6;
    int feat = blockIdx.z >> 3, s = blockIdx.z & 7;
    const ushort_t* Ab = Abuf + (size_t)feat*chunk*8192 + (size_t)blockIdx.x*128*8192;
    const ushort_t* Bb = Wt + (size_t)feat*128*8192;
    int wm = w >> 1, wn = w & 1;
    int lr = lane >> 3, pb = lane & 7, lb = pb ^ lr;
    int quad = lane >> 4, l15 = lane & 15;
    int arow0 = w*32;
    f32x4 acc[4][4] = {};
    const int kk0 = s*(8192/KSPLIT), kk1 = kk0 + 8192/KSPLIT;
    for (int kk = kk0; kk < kk1; kk += 64){
        __syncthreads();
        #pragma unroll
        for (int q = 0; q < 4; ++q){
            int r = arow0 + q*8 + lr;
            load_lds16(Ab + (size_t)r*8192 + kk + lb*8, Asm + (arow0 + q*8)*64);
            load_lds16(Bb + (size_t)r*8192 + kk + lb*8, Bsm + (arow0 + q*8)*64);
        }
        __syncthreads();
        #pragma unroll
        for (int h = 0; h < 2; ++h){
            bf16x8 aF[4], bF[4];
            #pragma unroll
            for (int mt = 0; mt < 4; ++mt){
                int ml = wm*64 + mt*16 + l15;
                int p = (h*4 + quad) ^ (ml & 7);
                aF[mt] = *(const bf16x8*)(Asm + ml*64 + p*8);
            }
            #pragma unroll
            for (int nt = 0; nt < 4; ++nt){
                int nl = wn*64 + nt*16 + l15;
                int p = (h*4 + quad) ^ (nl & 7);
                bF[nt] = *(const bf16x8*)(Bsm + nl*64 + p*8);
            }
            #pragma unroll
            for (int mt = 0; mt < 4; ++mt)
                #pragma unroll
                for (int nt = 0; nt < 4; ++nt)
                    acc[mt][nt] = __builtin_amdgcn_mfma_f32_16x16x32_bf16(
                        aF[mt], bF[nt], acc[mt][nt], 0, 0, 0);
        }
    }
    float* P = Pbuf + (size_t)blockIdx.z*chunk*128 + (size_t)blockIdx.x*128*128;
    #pragma unroll
    for (int mt = 0; mt < 4; ++mt)
        #pragma unroll
        for (int nt = 0; nt < 4; ++nt)
            #pragma unroll
            for (int reg = 0; reg < 4; ++reg){
                int r = wm*64 + mt*16 + quad*4 + reg;
                int c = wn*64 + nt*16 + l15;
                P[(size_t)r*128 + c] = acc[mt][nt][reg];
            }
}

__global__ void reduceP_kernel(const float* __restrict__ P, float* __restrict__ hconv,
                               int chunk, int base){
    int f = blockIdx.y;
    size_t idx = (size_t)blockIdx.x*256 + threadIdx.x;
    float s = 0.f;
    #pragma unroll
    for (int sp = 0; sp < KSPLIT; ++sp)
        s += P[((size_t)(f*KSPLIT + sp))*chunk*128 + idx];
    hconv[(size_t)f*NF + (size_t)base*128 + idx] = s;
}

// ---------------- generic fp32 tiled GEMM (qkv / o / ff) ----------------
template<bool WT>
__global__ __launch_bounds__(256) void gemm_kernel(
        const float* __restrict__ A, const float* __restrict__ W0, const float* __restrict__ W1p,
        const float* __restrict__ b0, const float* __restrict__ b1p,
        float* __restrict__ out, int M, int Cin, int Dout,
        long aZ, long oZ, int relu){
    __shared__ __align__(16) float As[64][36];
    __shared__ __align__(16) float Ws[64][36];
    const float* W    = (blockIdx.z && W1p) ? W1p : W0;
    const float* bias = (blockIdx.z && b1p) ? b1p : b0;
    A   += (long)blockIdx.z * aZ;
    out += (long)blockIdx.z * oZ;
    int r0 = blockIdx.x*64, c0 = blockIdx.y*64;
    int tid = threadIdx.x;
    int rg = tid >> 4, cg = tid & 15;
    float acc[4][4] = {};
    for (int kk = 0; kk < Cin; kk += 32){
        #pragma unroll
        for (int rep = 0; rep < 2; ++rep){
            int idx = tid + rep*256;
            int r = idx >> 3, k4 = (idx & 7)*4;
            *(float4*)&As[r][k4] = *(const float4*)&A[(size_t)(r0+r)*Cin + kk + k4];
        }
        if (WT){
            #pragma unroll
            for (int rep = 0; rep < 2; ++rep){
                int idx = tid + rep*256;
                int c = idx >> 3, k4 = (idx & 7)*4;
                *(float4*)&Ws[c][k4] = *(const float4*)&W[(size_t)(c0+c)*Cin + kk + k4];
            }
        } else {
            #pragma unroll
            for (int rep = 0; rep < 8; ++rep){
                int idx = tid + rep*256;
                int cc = idx & 63, kx = idx >> 6;
                Ws[cc][kx] = W[(size_t)(kk+kx)*Dout + c0 + cc];
            }
        }
        __syncthreads();
        #pragma unroll
        for (int k4 = 0; k4 < 32; k4 += 4){
            float4 a[4], wv[4];
            #pragma unroll
            for (int i = 0; i < 4; ++i) a[i] = *(const float4*)&As[rg*4+i][k4];
            #pragma unroll
            for (int j = 0; j < 4; ++j) wv[j] = *(const float4*)&Ws[cg*4+j][k4];
            #pragma unroll
            for (int i = 0; i < 4; ++i)
                #pragma unroll
                for (int j = 0; j < 4; ++j)
                    acc[i][j] += dot4f(a[i], wv[j]);
        }
        __syncthreads();
    }
    #pragma unroll
    for (int i = 0; i < 4; ++i){
        int r = r0 + rg*4 + i;
        #pragma unroll
        for (int j = 0; j < 4; ++j){
            int c = c0 + cg*4 + j;
            float v = acc[i][j] + (bias ? bias[c] : 0.f);
            if (relu) v = fmaxf(v, 0.f);
            out[(size_t)r*Dout + c] = v;
        }
    }
}

// ---------------- BatchNorm ----------------
__global__ void bn_stats_kernel(const float* __restrict__ hconv, float* __restrict__ stats){
    __shared__ float rs[256];
    __shared__ float rq[256];
    int ch = blockIdx.x, f = blockIdx.y, t = threadIdx.x;
    const float* src = hconv + (size_t)f*NF;
    float s = 0.f, q2 = 0.f;
    for (int r = t; r < NPTS; r += 256){
        float vv = src[(size_t)r*CH + ch];
        s += vv; q2 += vv*vv;
    }
    rs[t] = s; rq[t] = q2; __syncthreads();
    for (int o = 128; o; o >>= 1){
        if (t < o){ rs[t] += rs[t+o]; rq[t] += rq[t+o]; }
        __syncthreads();
    }
    if (t == 0){
        float m = rs[0]/(float)NPTS;
        float var = rq[0]/(float)NPTS - m*m;
        stats[f*128 + ch] = m;
        stats[256 + f*128 + ch] = rsqrtf(var + 1e-5f);
    }
}

// bn apply + relu, also writes h = xf + pe (fused addpe)
__global__ void bn_apply_kernel(const float* __restrict__ hconv, const float* __restrict__ stats,
        const float* __restrict__ gx, const float* __restrict__ bxp,
        const float* __restrict__ gy, const float* __restrict__ byp,
        const float* __restrict__ pe,
        float* __restrict__ xf, float* __restrict__ h){
    int f = blockIdx.y;
    size_t idx = (size_t)blockIdx.x*256 + threadIdx.x;
    int ch = idx & 127;
    const float* g = f ? gy : gx;
    const float* b = f ? byp : bxp;
    float m = stats[f*128 + ch], inv = stats[256 + f*128 + ch];
    float vv = hconv[(size_t)f*NF + idx];
    float r = fmaxf((vv - m)*inv*g[ch] + b[ch], 0.f);
    xf[(size_t)f*NF + idx] = r;
    h[(size_t)f*NF + idx]  = r + pe[idx];
}

// ---------------- attention precasts ----------------
// Qb/Kb: [feat][head][4096][32] bf16 (Q scaled by 1/sqrt(32)); from q,k fp32 [feat][4096][128]
__global__ void qk_cast_kernel(const float* __restrict__ q, const float* __restrict__ k,
                               ushort_t* __restrict__ Qb, ushort_t* __restrict__ Kb){
    int gid = blockIdx.x*256 + threadIdx.x;      // < 2*NF
    int f = gid >> 19;
    int rem = gid & (NF-1);
    int qi = rem >> 7, d = rem & 127;
    int hh = d >> 5, dd = d & 31;
    size_t o = ((size_t)(f*4+hh)*4096 + qi)*32 + dd;
    Qb[o] = f2bf(q[gid] * 0.17677669529663687f);
    Kb[o] = f2bf(k[gid]);
}

// Vt: [feat][head][32][4096] bf16 = V^T
__global__ __launch_bounds__(256) void vt_cast_kernel(const float* __restrict__ v,
                                                      ushort_t* __restrict__ Vt){
    int b = blockIdx.x;                 // 0..255
    int f = b >> 7, d = b & 127;
    const float* src = v + (size_t)f*NF + d;
    ushort_t* dst = Vt + ((size_t)(f*4 + (d>>5))*32 + (d&31))*4096;
    for (int s = threadIdx.x; s < 512; s += 256){
        int k0 = s*8;
        ushort_t u[8];
        #pragma unroll
        for (int i = 0; i < 8; ++i) u[i] = f2bf(src[(size_t)(k0+i)*128]);
        uint4 pk;
        pk.x = (unsigned)u[0] | ((unsigned)u[1]<<16);
        pk.y = (unsigned)u[2] | ((unsigned)u[3]<<16);
        pk.z = (unsigned)u[4] | ((unsigned)u[5]<<16);
        pk.w = (unsigned)u[6] | ((unsigned)u[7]<<16);
        *(uint4*)(dst + k0) = pk;
    }
}

// ---------------- MFMA flash attention ----------------
// grid (4096/64, 4 heads, 2 feats), 256 threads (4 waves), wave = 16 queries.
// S^T formulation: QK^T via mfma(A=K, B=Q) -> keys on row/reg axis.
__global__ __launch_bounds__(256) void attn_mfma_kernel(
        const ushort_t* __restrict__ Qb, const ushort_t* __restrict__ Kb,
        const ushort_t* __restrict__ Vt, float* __restrict__ og){
    __shared__ ushort_t Kl[64*40];     // [key][hd] stride 40
    __shared__ ushort_t Vl[32*72];     // [hd][key] stride 72
    __shared__ ushort_t Pl[64*72];     // [q_local][key] stride 72, wave-private rows
    int tid = threadIdx.x, lane = tid & 63, w = tid >> 6;
    int l15 = lane & 15, quad = lane >> 4;
    int q0 = blockIdx.x*64;
    int head = blockIdx.y, f = blockIdx.z;
    const ushort_t* Qh = Qb + ((size_t)(f*4+head)*4096)*32;
    const ushort_t* Kh = Kb + ((size_t)(f*4+head)*4096)*32;
    const ushort_t* Vh = Vt + ((size_t)(f*4+head)*32)*4096;
    int ql = w*16 + l15;                 // local query row (0..63)
    int qg = q0 + ql;                    // global query
    bf16x8 qfrag = *(const bf16x8*)(Qh + (size_t)qg*32 + quad*8);
    f32x4 oacc[2] = {};
    float mprev = -3.0e38f, l = 0.f;
    int kr = tid >> 2, kseg = tid & 3;
    int vd = tid >> 3, vseg = tid & 7;
    for (int kt = 0; kt < 64; ++kt){
        int k0 = kt*64;
        uint4 tk = *(const uint4*)(Kh + (size_t)(k0+kr)*32 + kseg*8);
        uint4 tv = *(const uint4*)(Vh + (size_t)vd*4096 + k0 + vseg*8);
        __syncthreads();
        *(uint4*)(Kl + kr*40 + kseg*8) = tk;
        *(uint4*)(Vl + vd*72 + vseg*8) = tv;
        __syncthreads();
        // S^T tiles: 4 m-tiles of 16 keys x this wave's 16 queries
        f32x4 sc[4] = {};
        #pragma unroll
        for (int mt = 0; mt < 4; ++mt){
            bf16x8 af = *(const bf16x8*)(Kl + (mt*16 + l15)*40 + quad*8);
            sc[mt] = __builtin_amdgcn_mfma_f32_16x16x32_bf16(af, qfrag, sc[mt], 0, 0, 0);
        }
        // online softmax (per query col = l15)
        float mloc = -3.0e38f;
        #pragma unroll
        for (int mt = 0; mt < 4; ++mt)
            #pragma unroll
            for (int r = 0; r < 4; ++r) mloc = fmaxf(mloc, sc[mt][r]);
        mloc = fmaxf(mloc, __shfl_xor(mloc, 16));
        mloc = fmaxf(mloc, __shfl_xor(mloc, 32));
        float mnew = fmaxf(mprev, mloc);
        float alpha = __expf(mprev - mnew);
        float sump = 0.f;
        #pragma unroll
        for (int mt = 0; mt < 4; ++mt){
            float p0 = __expf(sc[mt][0] - mnew);
            float p1 = __expf(sc[mt][1] - mnew);
            float p2 = __expf(sc[mt][2] - mnew);
            float p3 = __expf(sc[mt][3] - mnew);
            sump += (p0 + p1) + (p2 + p3);
            uint2 pk;
            pk.x = pack2bf(p0, p1);
            pk.y = pack2bf(p2, p3);
            *(uint2*)(Pl + ql*72 + mt*16 + quad*4) = pk;
        }
        sump += __shfl_xor(sump, 16);
        sump += __shfl_xor(sump, 32);
        l = l*alpha + sump;
        mprev = mnew;
        #pragma unroll
        for (int i = 0; i < 2; ++i)
            #pragma unroll
            for (int r = 0; r < 4; ++r) oacc[i][r] *= alpha;
        // O^T += V^T @ P^T  (wave-private Pl rows; no barrier needed)
        #pragma unroll
        for (int ks = 0; ks < 2; ++ks){
            bf16x8 bf = *(const bf16x8*)(Pl + ql*72 + ks*32 + quad*8);
            #pragma unroll
            for (int mtv = 0; mtv < 2; ++mtv){
                bf16x8 af = *(const bf16x8*)(Vl + (mtv*16 + l15)*72 + ks*32 + quad*8);
                oacc[mtv] = __builtin_amdgcn_mfma_f32_16x16x32_bf16(af, bf, oacc[mtv], 0, 0, 0);
            }
        }
    }
    float invl = 1.f / l;
    float* O = og + (size_t)f*NF;
    #pragma unroll
    for (int mtv = 0; mtv < 2; ++mtv)
        #pragma unroll
        for (int r = 0; r < 4; ++r){
            int hd = mtv*16 + quad*4 + r;
            O[(size_t)qg*128 + head*32 + hd] = oacc[mtv][r]*invl;
        }
}

// ---------------- LayerNorm(a + b) ----------------
__global__ __launch_bounds__(128) void ln_res_kernel(const float* __restrict__ a,
        const float* __restrict__ b, const float* __restrict__ g,
        const float* __restrict__ be, float* __restrict__ out){
    __shared__ float red[128];
    int t = threadIdx.x;
    size_t off = (size_t)blockIdx.y*NF + (size_t)blockIdx.x*CH;
    float v = a[off + t] + b[off + t];
    red[t] = v; __syncthreads();
    for (int o = 64; o; o >>= 1){ if (t < o) red[t] += red[t+o]; __syncthreads(); }
    float m = red[0] / 128.f;
    __syncthreads();
    float d = v - m;
    red[t] = d*d; __syncthreads();
    for (int o = 64; o; o >>= 1){ if (t < o) red[t] += red[t+o]; __syncthreads(); }
    float var = red[0] / 128.f;
    out[off + t] = (v - m)*rsqrtf(var + 1e-5f)*g[t] + be[t];
}

__global__ void combine_kernel(const float* __restrict__ xfo, const float* __restrict__ yfo,
        const float* __restrict__ x, const float* __restrict__ y, float* __restrict__ out){
    size_t idx = (size_t)blockIdx.x*256 + threadIdx.x;
    float s = xfo[idx] + yfo[idx];
    float w = 1.f/(1.f + __expf(-s));
    out[idx] = 2.f*x[idx]*w + 2.f*y[idx]*(1.f - w);
}

extern "C" void kernel_launch(void* const* d_in, const int* in_sizes, int n_in,
                              void* d_out, int out_size, void* d_ws, size_t ws_size,
                              hipStream_t stream){
    (void)in_sizes; (void)n_in; (void)out_size;
    const float* x    = (const float*)d_in[0];
    const float* y    = (const float*)d_in[1];
    const float* pos  = (const float*)d_in[2];
    const int*   nbr  = (const int*)  d_in[3];
    const float* Wx   = (const float*)d_in[5];
    const float* bnxg = (const float*)d_in[7];
    const float* bnxb = (const float*)d_in[8];
    const float* Wy   = (const float*)d_in[9];
    const float* bnyg = (const float*)d_in[11];
    const float* bnyb = (const float*)d_in[12];
    const float* Wq   = (const float*)d_in[13];
    const float* bq   = (const float*)d_in[14];
    const float* Wk   = (const float*)d_in[15];
    const float* bk   = (const float*)d_in[16];
    const float* Wv   = (const float*)d_in[17];
    const float* bv   = (const float*)d_in[18];
    const float* Wo   = (const float*)d_in[19];
    const float* bo   = (const float*)d_in[20];
    const float* ln1g = (const float*)d_in[21];
    const float* ln1b = (const float*)d_in[22];
    const float* W1   = (const float*)d_in[23];
    const float* b1   = (const float*)d_in[24];
    const float* W2   = (const float*)d_in[25];
    const float* b2   = (const float*)d_in[26];
    const float* ln2g = (const float*)d_in[27];
    const float* ln2b = (const float*)d_in[28];

    float* ws     = (float*)d_ws;
    float* pe     = ws;
    float* hconv  = ws + (size_t)NF*1;
    float* xf     = ws + (size_t)NF*3;
    float* h      = ws + (size_t)NF*5;
    float* q      = ws + (size_t)NF*7;
    float* k      = ws + (size_t)NF*9;
    float* v      = ws + (size_t)NF*11;
    float* stats  = ws + (size_t)NF*13;
    float* ff1    = stats + 2048;                 // 4*NF
    float* Pbuf   = ff1 + (size_t)4*NF;
    float* o      = hconv;
    float* o2     = h;
    float* feat1  = q;
    float* ff2    = k;
    float* xfo    = xf;

    const size_t fixedFloats = (size_t)17*NF + 2048;
    int chunk = 128;
    const int cand[6] = {4096, 2048, 1024, 512, 256, 128};
    for (int ci = 0; ci < 6; ++ci){
        size_t need = (fixedFloats + (size_t)1048576 + (size_t)1572864 + (size_t)10240*cand[ci]) * 4;
        if (need <= ws_size){ chunk = cand[ci]; break; }
    }
    ushort_t* Wt   = (ushort_t*)(Pbuf + (size_t)2048*chunk);
    ushort_t* Abuf = Wt + (size_t)2*8192*128;
    ushort_t* Qb   = Abuf + (size_t)2*chunk*8192;
    ushort_t* Kb   = Qb + (size_t)2*4*4096*32;
    ushort_t* Vtb  = Kb + (size_t)2*4*4096*32;

    pos_stats_kernel<<<1, 256, 0, stream>>>(pos, stats);
    pe_kernel<<<NPTS*64/256, 256, 0, stream>>>(pos, stats, pe);
    wt_kernel<<<dim3(256, 4, 2), 256, 0, stream>>>(Wx, Wy, Wt);

    for (int base = 0; base < NPTS; base += chunk){
        cf_kernel<<<chunk, 256, 0, stream>>>(x, y, pos, nbr, Abuf, base, chunk);
        mfma_gemm_kernel<<<dim3(chunk/128, 1, 2*KSPLIT), 256, 0, stream>>>(Abuf, Wt, Pbuf, chunk);
        reduceP_kernel<<<dim3(chunk*128/256, 2), 256, 0, stream>>>(Pbuf, hconv, chunk, base);
    }

    bn_stats_kernel<<<dim3(128, 2), 256, 0, stream>>>(hconv, stats);
    bn_apply_kernel<<<dim3(NF/256, 2), 256, 0, stream>>>(hconv, stats, bnxg, bnxb, bnyg, bnyb,
                                                         pe, xf, h);

    gemm_kernel<true><<<dim3(64, 2, 2), 256, 0, stream>>>(h, Wq, nullptr, bq, nullptr, q,
        NPTS, 128, 128, (long)NF, (long)NF, 0);
    gemm_kernel<true><<<dim3(64, 2, 2), 256, 0, stream>>>(h, Wk, nullptr, bk, nullptr, k,
        NPTS, 128, 128, (long)NF, (long)NF, 0);
    gemm_kernel<true><<<dim3(64, 2, 2), 256, 0, stream>>>(h, Wv, nullptr, bv, nullptr, v,
        NPTS, 128, 128, (long)NF, (long)NF, 0);

    qk_cast_kernel<<<2*NF/256, 256, 0, stream>>>(q, k, Qb, Kb);
    vt_cast_kernel<<<256, 256, 0, stream>>>(v, Vtb);
    attn_mfma_kernel<<<dim3(64, 4, 2), 256, 0, stream>>>(Qb, Kb, Vtb, o);

    gemm_kernel<true><<<dim3(64, 2, 2), 256, 0, stream>>>(o, Wo, nullptr, bo, nullptr, o2,
        NPTS, 128, 128, (long)NF, (long)NF, 0);
    ln_res_kernel<<<dim3(NPTS, 2), 128, 0, stream>>>(xf, o2, ln1g, ln1b, feat1);

    gemm_kernel<true><<<dim3(64, 8, 2), 256, 0, stream>>>(feat1, W1, nullptr, b1, nullptr, ff1,
        NPTS, 128, 512, (long)NF, (long)NPTS*FFD, 1);
    gemm_kernel<true><<<dim3(64, 2, 2), 256, 0, stream>>>(ff1, W2, nullptr, b2, nullptr, ff2,
        NPTS, 512, 128, (long)NPTS*FFD, (long)NF, 0);
    ln_res_kernel<<<dim3(NPTS, 2), 128, 0, stream>>>(feat1, ff2, ln2g, ln2b, xfo);

    combine_kernel<<<NF/256, 256, 0, stream>>>(xfo, xfo + NF, x, y, (float*)d_out);
}

// Round 4
// 341.918 us; speedup vs baseline: 7.3332x; 1.4640x over previous
//
#include <hip/hip_runtime.h>
#include <cstddef>

#define NPTS 4096
#define KNBR 80
#define CH   128
#define NF   (NPTS*CH)      // 524288
#define FFD  512
#define KSPLIT 8

typedef unsigned short ushort_t;
typedef short bf16x8 __attribute__((ext_vector_type(8)));
typedef float f32x4 __attribute__((ext_vector_type(4)));

__device__ __forceinline__ unsigned short f2bf(float f){
    unsigned int u = __float_as_uint(f);
    unsigned int r = (u + 0x7FFFu + ((u >> 16) & 1u)) >> 16;
    return (unsigned short)r;
}

__device__ __forceinline__ unsigned pack2bf(float a, float b){
    return (unsigned)f2bf(a) | ((unsigned)f2bf(b) << 16);
}

__device__ __forceinline__ void load_lds16(const ushort_t* g, ushort_t* l){
    __builtin_amdgcn_global_load_lds(
        (const __attribute__((address_space(1))) unsigned int*)g,
        (__attribute__((address_space(3))) unsigned int*)l, 16, 0, 0);
}

// ---------------- pos stats ----------------
__global__ void pos_stats_kernel(const float* __restrict__ pos, float* __restrict__ stats){
    __shared__ float red[256];
    int t = threadIdx.x;
    float s = 0.f;
    for (int i = t; i < NPTS; i += 256) s += pos[(size_t)i*3];
    red[t] = s; __syncthreads();
    for (int o = 128; o; o >>= 1){ if (t < o) red[t] += red[t+o]; __syncthreads(); }
    float mean = red[0] / (float)NPTS;
    __syncthreads();
    float ss = 0.f;
    for (int i = t; i < NPTS; i += 256){ float d = pos[(size_t)i*3] - mean; ss += d*d; }
    red[t] = ss; __syncthreads();
    for (int o = 128; o; o >>= 1){ if (t < o) red[t] += red[t+o]; __syncthreads(); }
    if (t == 0){
        float sd = sqrtf(red[0] / (float)(NPTS-1));
        stats[512] = mean;
        stats[513] = 1.f/(sd + 1e-8f);
    }
}

// ---------------- positional encoding ----------------
__global__ void pe_kernel(const float* __restrict__ pos, const float* __restrict__ stats,
                          float* __restrict__ pe){
    int t = blockIdx.x*256 + threadIdx.x;
    int i = t >> 6, m = t & 63;
    float px = (pos[(size_t)i*3] - stats[512]) * stats[513];
    float dv = expf((float)(2*m) * -0.07195578415606394f);
    float ang = px * dv;
    float sv, cv;
    sincosf(ang, &sv, &cv);
    pe[(size_t)i*CH + 2*m]     = sv;
    pe[(size_t)i*CH + 2*m + 1] = cv;
}

// ---------------- conv W transpose+cast: Wt[f][n][k] = W_f[k][n] (bf16) ----------------
__global__ __launch_bounds__(256) void wt_kernel(const float* __restrict__ Wx,
        const float* __restrict__ Wy, ushort_t* __restrict__ Wt){
    __shared__ float tile[32][33];
    const float* W = blockIdx.z ? Wy : Wx;
    int kb = blockIdx.x, nb = blockIdx.y;
    int tr = threadIdx.x & 31, tc = threadIdx.x >> 5;
    #pragma unroll
    for (int rr = 0; rr < 32; rr += 8)
        tile[tc+rr][tr] = W[(size_t)(kb*32 + tc + rr)*128 + nb*32 + tr];
    __syncthreads();
    size_t fo = (size_t)blockIdx.z * 8192 * 128;
    #pragma unroll
    for (int rr = 0; rr < 32; rr += 8)
        Wt[fo + (size_t)(nb*32 + tc + rr)*8192 + kb*32 + tr] = f2bf(tile[tr][tc+rr]);
}

// ---------------- dense-weight cast (Wq|Wk|Wv|Wo|W1|W2 -> bf16 packed) ----------------
__global__ void wcast_kernel(const float* __restrict__ Wq, const float* __restrict__ Wk,
        const float* __restrict__ Wv, const float* __restrict__ Wo,
        const float* __restrict__ W1, const float* __restrict__ W2,
        ushort_t* __restrict__ dst){
    int i = blockIdx.x*256 + threadIdx.x;     // < 196608
    const float* src; int off;
    if      (i < 16384)  { src = Wq; off = i; }
    else if (i < 32768)  { src = Wk; off = i - 16384; }
    else if (i < 49152)  { src = Wv; off = i - 32768; }
    else if (i < 65536)  { src = Wo; off = i - 49152; }
    else if (i < 131072) { src = W1; off = i - 65536; }
    else                 { src = W2; off = i - 131072; }
    dst[i] = f2bf(src[off]);
}

// ---------------- cconv stage 1 (MFMA): A = Ct(64 x n) @ F(n x 128) -> bf16 ----------------
// block = 1 point, 256 threads / 4 waves; wave w owns 16 cells.
__global__ __launch_bounds__(256) void cf_kernel(
        const float* __restrict__ xin, const float* __restrict__ yin,
        const float* __restrict__ pos, const int* __restrict__ nbr,
        ushort_t* __restrict__ Abuf, int base, int chunk){
    __shared__ ushort_t Ct[64*96];      // [cell][j], stride 96 (K up to 96 >= KNBR)
    __shared__ ushort_t Ft[128*40];     // [ch][j in chunk], stride 40
    __shared__ int nbl[KNBR];
    __shared__ int cnt;
    int i = base + blockIdx.x;
    int t = threadIdx.x;
    // zero Ct + cnt
    for (int z = t; z < 64*96/8; z += 256) ((uint4*)Ct)[z] = uint4{0,0,0,0};
    if (t == 0) cnt = 0;
    __syncthreads();
    if (t < KNBR){
        int nb = nbr[(size_t)i*KNBR + t];
        if (nb != i){
            float p0 = pos[(size_t)i*3], p1 = pos[(size_t)i*3+1], p2 = pos[(size_t)i*3+2];
            const float RAD = 0.1125f;
            float rx = (pos[(size_t)nb*3+0]-p0)/RAD;
            float ry = (pos[(size_t)nb*3+1]-p1)/RAD;
            float rz = (pos[(size_t)nb*3+2]-p2)/RAD;
            float r2 = rx*rx + ry*ry + rz*rz;
            float w1 = 1.f - r2;
            float win = fminf(fmaxf(w1*w1*w1, 0.f), 1.f);
            float nrm = sqrtf(fmaxf(r2, 1e-12f));
            float linf = fmaxf(fmaxf(fabsf(rx), fabsf(ry)), fabsf(rz));
            linf = fmaxf(linf, 1e-9f);
            float sc = nrm/linf;
            float gx = fminf(fmaxf((rx*sc+1.f)*0.5f*3.f, 0.f), 3.f);
            float gy = fminf(fmaxf((ry*sc+1.f)*0.5f*3.f, 0.f), 3.f);
            float gz = fminf(fmaxf((rz*sc+1.f)*0.5f*3.f, 0.f), 3.f);
            float fx = fminf(floorf(gx), 2.f), fy = fminf(floorf(gy), 2.f), fz = fminf(floorf(gz), 2.f);
            float tx = gx-fx, ty = gy-fy, tz = gz-fz;
            int ix = (int)fx, iy = (int)fy, iz = (int)fz;
            int cb = (ix<<4) + (iy<<2) + iz;
            float x0 = (1.f-tx)*win, x1 = tx*win;
            float w00 = x0*(1.f-ty), w01 = x0*ty, w10 = x1*(1.f-ty), w11 = x1*ty;
            float z0 = 1.f-tz, z1 = tz;
            int slot = atomicAdd(&cnt, 1);
            nbl[slot] = nb;
            Ct[(cb     )*96 + slot] = f2bf(w00*z0);
            Ct[(cb + 1 )*96 + slot] = f2bf(w00*z1);
            Ct[(cb + 4 )*96 + slot] = f2bf(w01*z0);
            Ct[(cb + 5 )*96 + slot] = f2bf(w01*z1);
            Ct[(cb + 16)*96 + slot] = f2bf(w10*z0);
            Ct[(cb + 17)*96 + slot] = f2bf(w10*z1);
            Ct[(cb + 20)*96 + slot] = f2bf(w11*z0);
            Ct[(cb + 21)*96 + slot] = f2bf(w11*z1);
        }
    }
    __syncthreads();
    int n = cnt;
    int nch = (n + 31) >> 5;
    int lane = t & 63, w = t >> 6;
    int l15 = lane & 15, quad = lane >> 4;
    int gj = t >> 3, gpart = t & 7;      // gather: neighbor slot, channel-part (16ch)
    for (int f = 0; f < 2; ++f){
        const float* feat = f ? yin : xin;
        f32x4 acc[8] = {};
        for (int ck = 0; ck < nch; ++ck){
            __syncthreads();   // protect Ft from previous chunk's readers
            int js = ck*32 + gj;
            if (js < n){
                const float* src = feat + (size_t)nbl[js]*128 + gpart*16;
                #pragma unroll
                for (int u4 = 0; u4 < 16; u4 += 4){
                    float4 v4 = *(const float4*)(src + u4);
                    Ft[(gpart*16 + u4    )*40 + gj] = f2bf(v4.x);
                    Ft[(gpart*16 + u4 + 1)*40 + gj] = f2bf(v4.y);
                    Ft[(gpart*16 + u4 + 2)*40 + gj] = f2bf(v4.z);
                    Ft[(gpart*16 + u4 + 3)*40 + gj] = f2bf(v4.w);
                }
            } else {
                #pragma unroll
                for (int u = 0; u < 16; ++u)
                    Ft[(gpart*16 + u)*40 + gj] = 0;
            }
            __syncthreads();
            bf16x8 af = *(const bf16x8*)(Ct + (size_t)(w*16 + l15)*96 + ck*32 + quad*8);
            #pragma unroll
            for (int nt = 0; nt < 8; ++nt){
                bf16x8 bfr = *(const bf16x8*)(Ft + (size_t)(nt*16 + l15)*40 + quad*8);
                acc[nt] = __builtin_amdgcn_mfma_f32_16x16x32_bf16(af, bfr, acc[nt], 0, 0, 0);
            }
        }
        ushort_t* dst = Abuf + ((size_t)f*chunk + blockIdx.x)*8192;
        #pragma unroll
        for (int nt = 0; nt < 8; ++nt)
            #pragma unroll
            for (int reg = 0; reg < 4; ++reg){
                int cell = w*16 + quad*4 + reg;
                int c    = nt*16 + l15;
                dst[(size_t)cell*128 + c] = f2bf(acc[nt][reg]);
            }
    }
}

// ---------------- cconv stage 2: MFMA GEMM  P = A(bf16) @ Wt^T, split-K ----------------
__global__ __launch_bounds__(256) void mfma_gemm_kernel(
        const ushort_t* __restrict__ Abuf, const ushort_t* __restrict__ Wt,
        float* __restrict__ Pbuf, int chunk){
    __shared__ ushort_t Asm[128*64];
    __shared__ ushort_t Bsm[128*64];
    int tid = threadIdx.x, lane = tid & 63, w = tid >> 6;
    int feat = blockIdx.z >> 3, s = blockIdx.z & 7;
    const ushort_t* Ab = Abuf + (size_t)feat*chunk*8192 + (size_t)blockIdx.x*128*8192;
    const ushort_t* Bb = Wt + (size_t)feat*128*8192;
    int wm = w >> 1, wn = w & 1;
    int lr = lane >> 3, pb = lane & 7, lb = pb ^ lr;
    int quad = lane >> 4, l15 = lane & 15;
    int arow0 = w*32;
    f32x4 acc[4][4] = {};
    const int kk0 = s*(8192/KSPLIT), kk1 = kk0 + 8192/KSPLIT;
    for (int kk = kk0; kk < kk1; kk += 64){
        __syncthreads();
        #pragma unroll
        for (int q = 0; q < 4; ++q){
            int r = arow0 + q*8 + lr;
            load_lds16(Ab + (size_t)r*8192 + kk + lb*8, Asm + (arow0 + q*8)*64);
            load_lds16(Bb + (size_t)r*8192 + kk + lb*8, Bsm + (arow0 + q*8)*64);
        }
        __syncthreads();
        #pragma unroll
        for (int h = 0; h < 2; ++h){
            bf16x8 aF[4], bF[4];
            #pragma unroll
            for (int mt = 0; mt < 4; ++mt){
                int ml = wm*64 + mt*16 + l15;
                int p = (h*4 + quad) ^ (ml & 7);
                aF[mt] = *(const bf16x8*)(Asm + ml*64 + p*8);
            }
            #pragma unroll
            for (int nt = 0; nt < 4; ++nt){
                int nl = wn*64 + nt*16 + l15;
                int p = (h*4 + quad) ^ (nl & 7);
                bF[nt] = *(const bf16x8*)(Bsm + nl*64 + p*8);
            }
            #pragma unroll
            for (int mt = 0; mt < 4; ++mt)
                #pragma unroll
                for (int nt = 0; nt < 4; ++nt)
                    acc[mt][nt] = __builtin_amdgcn_mfma_f32_16x16x32_bf16(
                        aF[mt], bF[nt], acc[mt][nt], 0, 0, 0);
        }
    }
    float* P = Pbuf + (size_t)blockIdx.z*chunk*128 + (size_t)blockIdx.x*128*128;
    #pragma unroll
    for (int mt = 0; mt < 4; ++mt)
        #pragma unroll
        for (int nt = 0; nt < 4; ++nt)
            #pragma unroll
            for (int reg = 0; reg < 4; ++reg){
                int r = wm*64 + mt*16 + quad*4 + reg;
                int c = wn*64 + nt*16 + l15;
                P[(size_t)r*128 + c] = acc[mt][nt][reg];
            }
}

__global__ void reduceP_kernel(const float* __restrict__ P, float* __restrict__ hconv,
                               int chunk, int base){
    int f = blockIdx.y;
    size_t idx = (size_t)blockIdx.x*256 + threadIdx.x;
    float s = 0.f;
    #pragma unroll
    for (int sp = 0; sp < KSPLIT; ++sp)
        s += P[((size_t)(f*KSPLIT + sp))*chunk*128 + idx];
    hconv[(size_t)f*NF + (size_t)base*128 + idx] = s;
}

// ---------------- generic dense MFMA GEMM: D = A(M x K) @ B(N x K)^T ----------------
// MODE 0: fp32 out (N=128): oF[z*oZ + R*128 + C] = acc + bs0[C]
// MODE 1: bf16 relu out (N=512 via grid.y): oB0[z*2097152 + R*512 + C]
// MODE 2: qkv -> Qb/Kb/Vt bf16 layouts; z = f*3 + {q,k,v}
template<int MODE>
__global__ __launch_bounds__(256) void dgemm_kernel(
        const ushort_t* __restrict__ A, const ushort_t* __restrict__ Bw,
        const float* __restrict__ bs0, const float* __restrict__ bs1,
        const float* __restrict__ bs2,
        float* __restrict__ oF, ushort_t* __restrict__ oB0,
        ushort_t* __restrict__ oB1, ushort_t* __restrict__ oB2,
        int K, long aZ, long oZ){
    __shared__ ushort_t Asm[128*64];
    __shared__ ushort_t Bsm[128*64];
    int tid = threadIdx.x, lane = tid & 63, w = tid >> 6;
    int z = blockIdx.z;
    int f = (MODE == 2) ? (z/3) : z;
    int wsel = (MODE == 2) ? (z - 3*f) : 0;
    const ushort_t* Ab = A + (size_t)f*aZ + (size_t)blockIdx.x*128*K;
    const ushort_t* Bb = Bw + ((MODE == 2) ? (size_t)wsel*16384 : 0)
                            + (size_t)blockIdx.y*128*K;
    int wm = w >> 1, wn = w & 1;
    int lr = lane >> 3, pb = lane & 7, lb = pb ^ lr;
    int quad = lane >> 4, l15 = lane & 15;
    int arow0 = w*32;
    f32x4 acc[4][4] = {};
    for (int kk = 0; kk < K; kk += 64){
        __syncthreads();
        #pragma unroll
        for (int q = 0; q < 4; ++q){
            int r = arow0 + q*8 + lr;
            load_lds16(Ab + (size_t)r*K + kk + lb*8, Asm + (arow0 + q*8)*64);
            load_lds16(Bb + (size_t)r*K + kk + lb*8, Bsm + (arow0 + q*8)*64);
        }
        __syncthreads();
        #pragma unroll
        for (int h = 0; h < 2; ++h){
            bf16x8 aF[4], bF[4];
            #pragma unroll
            for (int mt = 0; mt < 4; ++mt){
                int ml = wm*64 + mt*16 + l15;
                int p = (h*4 + quad) ^ (ml & 7);
                aF[mt] = *(const bf16x8*)(Asm + ml*64 + p*8);
            }
            #pragma unroll
            for (int nt = 0; nt < 4; ++nt){
                int nl = wn*64 + nt*16 + l15;
                int p = (h*4 + quad) ^ (nl & 7);
                bF[nt] = *(const bf16x8*)(Bsm + nl*64 + p*8);
            }
            #pragma unroll
            for (int mt = 0; mt < 4; ++mt)
                #pragma unroll
                for (int nt = 0; nt < 4; ++nt)
                    acc[mt][nt] = __builtin_amdgcn_mfma_f32_16x16x32_bf16(
                        aF[mt], bF[nt], acc[mt][nt], 0, 0, 0);
        }
    }
    int r0 = blockIdx.x*128, c0 = blockIdx.y*128;
    const float* bias = bs0;
    float osc = 1.f;
    if (MODE == 2){
        bias = (wsel == 0) ? bs0 : (wsel == 1 ? bs1 : bs2);
        if (wsel == 0) osc = 0.17677669529663687f;
    }
    #pragma unroll
    for (int mt = 0; mt < 4; ++mt)
        #pragma unroll
        for (int nt = 0; nt < 4; ++nt)
            #pragma unroll
            for (int reg = 0; reg < 4; ++reg){
                int R = r0 + wm*64 + mt*16 + quad*4 + reg;
                int C = c0 + wn*64 + nt*16 + l15;
                float v = acc[mt][nt][reg];
                if (MODE == 0){
                    oF[(size_t)z*oZ + (size_t)R*128 + C] = v + bias[C];
                } else if (MODE == 1){
                    float r = fmaxf(v + bias[C], 0.f);
                    oB0[(size_t)z*2097152 + (size_t)R*512 + C] = f2bf(r);
                } else {
                    float r = (v + bias[C])*osc;
                    int hh = C >> 5, dd = C & 31;
                    if (wsel < 2){
                        ushort_t* dst = wsel ? oB1 : oB0;
                        dst[((size_t)(f*4+hh)*4096 + R)*32 + dd] = f2bf(r);
                    } else {
                        oB2[((size_t)(f*4+hh)*32 + dd)*4096 + R] = f2bf(r);
                    }
                }
            }
}

// ---------------- BatchNorm ----------------
__global__ void bn_stats_kernel(const float* __restrict__ hconv, float* __restrict__ stats){
    __shared__ float rs[256];
    __shared__ float rq[256];
    int ch = blockIdx.x, f = blockIdx.y, t = threadIdx.x;
    const float* src = hconv + (size_t)f*NF;
    float s = 0.f, q2 = 0.f;
    for (int r = t; r < NPTS; r += 256){
        float vv = src[(size_t)r*CH + ch];
        s += vv; q2 += vv*vv;
    }
    rs[t] = s; rq[t] = q2; __syncthreads();
    for (int o = 128; o; o >>= 1){
        if (t < o){ rs[t] += rs[t+o]; rq[t] += rq[t+o]; }
        __syncthreads();
    }
    if (t == 0){
        float m = rs[0]/(float)NPTS;
        float var = rq[0]/(float)NPTS - m*m;
        stats[f*128 + ch] = m;
        stats[256 + f*128 + ch] = rsqrtf(var + 1e-5f);
    }
}

// bn apply + relu -> xf (fp32); h = xf + pe -> hb (bf16)
__global__ void bn_apply_kernel(const float* __restrict__ hconv, const float* __restrict__ stats,
        const float* __restrict__ gx, const float* __restrict__ bxp,
        const float* __restrict__ gy, const float* __restrict__ byp,
        const float* __restrict__ pe,
        float* __restrict__ xf, ushort_t* __restrict__ hb){
    int f = blockIdx.y;
    size_t idx = (size_t)blockIdx.x*256 + threadIdx.x;
    int ch = idx & 127;
    const float* g = f ? gy : gx;
    const float* b = f ? byp : bxp;
    float m = stats[f*128 + ch], inv = stats[256 + f*128 + ch];
    float vv = hconv[(size_t)f*NF + idx];
    float r = fmaxf((vv - m)*inv*g[ch] + b[ch], 0.f);
    xf[(size_t)f*NF + idx] = r;
    hb[(size_t)f*NF + idx] = f2bf(r + pe[idx]);
}

// ---------------- MFMA flash attention (bf16 in, bf16 out) ----------------
__global__ __launch_bounds__(256) void attn_mfma_kernel(
        const ushort_t* __restrict__ Qb, const ushort_t* __restrict__ Kb,
        const ushort_t* __restrict__ Vt, ushort_t* __restrict__ og){
    __shared__ ushort_t Kl[64*40];
    __shared__ ushort_t Vl[32*72];
    __shared__ ushort_t Pl[64*72];
    int tid = threadIdx.x, lane = tid & 63, w = tid >> 6;
    int l15 = lane & 15, quad = lane >> 4;
    int q0 = blockIdx.x*64;
    int head = blockIdx.y, f = blockIdx.z;
    const ushort_t* Qh = Qb + ((size_t)(f*4+head)*4096)*32;
    const ushort_t* Kh = Kb + ((size_t)(f*4+head)*4096)*32;
    const ushort_t* Vh = Vt + ((size_t)(f*4+head)*32)*4096;
    int ql = w*16 + l15;
    int qg = q0 + ql;
    bf16x8 qfrag = *(const bf16x8*)(Qh + (size_t)qg*32 + quad*8);
    f32x4 oacc[2] = {};
    float mprev = -3.0e38f, l = 0.f;
    int kr = tid >> 2, kseg = tid & 3;
    int vd = tid >> 3, vseg = tid & 7;
    for (int kt = 0; kt < 64; ++kt){
        int k0 = kt*64;
        uint4 tk = *(const uint4*)(Kh + (size_t)(k0+kr)*32 + kseg*8);
        uint4 tv = *(const uint4*)(Vh + (size_t)vd*4096 + k0 + vseg*8);
        __syncthreads();
        *(uint4*)(Kl + kr*40 + kseg*8) = tk;
        *(uint4*)(Vl + vd*72 + vseg*8) = tv;
        __syncthreads();
        f32x4 sc[4] = {};
        #pragma unroll
        for (int mt = 0; mt < 4; ++mt){
            bf16x8 af = *(const bf16x8*)(Kl + (mt*16 + l15)*40 + quad*8);
            sc[mt] = __builtin_amdgcn_mfma_f32_16x16x32_bf16(af, qfrag, sc[mt], 0, 0, 0);
        }
        float mloc = -3.0e38f;
        #pragma unroll
        for (int mt = 0; mt < 4; ++mt)
            #pragma unroll
            for (int r = 0; r < 4; ++r) mloc = fmaxf(mloc, sc[mt][r]);
        mloc = fmaxf(mloc, __shfl_xor(mloc, 16));
        mloc = fmaxf(mloc, __shfl_xor(mloc, 32));
        float mnew = fmaxf(mprev, mloc);
        float alpha = __expf(mprev - mnew);
        float sump = 0.f;
        #pragma unroll
        for (int mt = 0; mt < 4; ++mt){
            float p0 = __expf(sc[mt][0] - mnew);
            float p1 = __expf(sc[mt][1] - mnew);
            float p2 = __expf(sc[mt][2] - mnew);
            float p3 = __expf(sc[mt][3] - mnew);
            sump += (p0 + p1) + (p2 + p3);
            uint2 pk;
            pk.x = pack2bf(p0, p1);
            pk.y = pack2bf(p2, p3);
            *(uint2*)(Pl + ql*72 + mt*16 + quad*4) = pk;
        }
        sump += __shfl_xor(sump, 16);
        sump += __shfl_xor(sump, 32);
        l = l*alpha + sump;
        mprev = mnew;
        #pragma unroll
        for (int i = 0; i < 2; ++i)
            #pragma unroll
            for (int r = 0; r < 4; ++r) oacc[i][r] *= alpha;
        #pragma unroll
        for (int ks = 0; ks < 2; ++ks){
            bf16x8 bfr = *(const bf16x8*)(Pl + ql*72 + ks*32 + quad*8);
            #pragma unroll
            for (int mtv = 0; mtv < 2; ++mtv){
                bf16x8 af = *(const bf16x8*)(Vl + (mtv*16 + l15)*72 + ks*32 + quad*8);
                oacc[mtv] = __builtin_amdgcn_mfma_f32_16x16x32_bf16(af, bfr, oacc[mtv], 0, 0, 0);
            }
        }
    }
    float invl = 1.f / l;
    ushort_t* O = og + (size_t)f*NF;
    #pragma unroll
    for (int mtv = 0; mtv < 2; ++mtv)
        #pragma unroll
        for (int r = 0; r < 4; ++r){
            int hd = mtv*16 + quad*4 + r;
            O[(size_t)qg*128 + head*32 + hd] = f2bf(oacc[mtv][r]*invl);
        }
}

// ---------------- LayerNorm(a + b), optional bf16 copy ----------------
__global__ __launch_bounds__(128) void ln_res_kernel(const float* __restrict__ a,
        const float* __restrict__ b, const float* __restrict__ g,
        const float* __restrict__ be, float* __restrict__ out,
        ushort_t* __restrict__ outB){
    __shared__ float red[128];
    int t = threadIdx.x;
    size_t off = (size_t)blockIdx.y*NF + (size_t)blockIdx.x*CH;
    float v = a[off + t] + b[off + t];
    red[t] = v; __syncthreads();
    for (int o = 64; o; o >>= 1){ if (t < o) red[t] += red[t+o]; __syncthreads(); }
    float m = red[0] / 128.f;
    __syncthreads();
    float d = v - m;
    red[t] = d*d; __syncthreads();
    for (int o = 64; o; o >>= 1){ if (t < o) red[t] += red[t+o]; __syncthreads(); }
    float var = red[0] / 128.f;
    float res = (v - m)*rsqrtf(var + 1e-5f)*g[t] + be[t];
    out[off + t] = res;
    if (outB) outB[off + t] = f2bf(res);
}

__global__ void combine_kernel(const float* __restrict__ xfo, const float* __restrict__ yfo,
        const float* __restrict__ x, const float* __restrict__ y, float* __restrict__ out){
    size_t idx = (size_t)blockIdx.x*256 + threadIdx.x;
    float s = xfo[idx] + yfo[idx];
    float w = 1.f/(1.f + __expf(-s));
    out[idx] = 2.f*x[idx]*w + 2.f*y[idx]*(1.f - w);
}

extern "C" void kernel_launch(void* const* d_in, const int* in_sizes, int n_in,
                              void* d_out, int out_size, void* d_ws, size_t ws_size,
                              hipStream_t stream){
    (void)in_sizes; (void)n_in; (void)out_size;
    const float* x    = (const float*)d_in[0];
    const float* y    = (const float*)d_in[1];
    const float* pos  = (const float*)d_in[2];
    const int*   nbr  = (const int*)  d_in[3];
    const float* Wx   = (const float*)d_in[5];
    const float* bnxg = (const float*)d_in[7];
    const float* bnxb = (const float*)d_in[8];
    const float* Wy   = (const float*)d_in[9];
    const float* bnyg = (const float*)d_in[11];
    const float* bnyb = (const float*)d_in[12];
    const float* Wq   = (const float*)d_in[13];
    const float* bq   = (const float*)d_in[14];
    const float* Wk   = (const float*)d_in[15];
    const float* bk   = (const float*)d_in[16];
    const float* Wv   = (const float*)d_in[17];
    const float* bv   = (const float*)d_in[18];
    const float* Wo   = (const float*)d_in[19];
    const float* bo   = (const float*)d_in[20];
    const float* ln1g = (const float*)d_in[21];
    const float* ln1b = (const float*)d_in[22];
    const float* W1   = (const float*)d_in[23];
    const float* b1   = (const float*)d_in[24];
    const float* W2   = (const float*)d_in[25];
    const float* b2   = (const float*)d_in[26];
    const float* ln2g = (const float*)d_in[27];
    const float* ln2b = (const float*)d_in[28];

    float* ws     = (float*)d_ws;
    float* pe     = ws;                       // NF
    float* hconv  = pe + NF;                  // 2NF
    float* xf     = hconv + (size_t)2*NF;     // 2NF
    float* o2     = xf + (size_t)2*NF;        // 2NF
    float* feat1  = o2 + (size_t)2*NF;        // 2NF
    float* ff2    = feat1 + (size_t)2*NF;     // 2NF
    float* stats  = ff2 + (size_t)2*NF;       // 2048
    float* Pbuf   = stats + 2048;             // 2048*chunk
    float* xfo    = xf;

    const size_t fixedFloats = (size_t)11*NF + 2048;
    const size_t fixedUsh = (size_t)2097152 + 196608 + 6*1048576 + 4194304;
    int chunk = 128;
    const int cand[6] = {4096, 2048, 1024, 512, 256, 128};
    for (int ci = 0; ci < 6; ++ci){
        size_t need = (fixedFloats + (size_t)2048*cand[ci])*4
                    + (fixedUsh + (size_t)2*cand[ci]*8192)*2;
        if (need <= ws_size){ chunk = cand[ci]; break; }
    }
    ushort_t* Wt     = (ushort_t*)(Pbuf + (size_t)2048*chunk);
    ushort_t* wbuf   = Wt + 2097152;
    ushort_t* hb     = wbuf + 196608;
    ushort_t* Qb     = hb + 1048576;
    ushort_t* Kb     = Qb + 1048576;
    ushort_t* Vtb    = Kb + 1048576;
    ushort_t* Ob     = Vtb + 1048576;
    ushort_t* feat1b = Ob + 1048576;
    ushort_t* ff1b   = feat1b + 1048576;
    ushort_t* Abuf   = ff1b + 4194304;

    pos_stats_kernel<<<1, 256, 0, stream>>>(pos, stats);
    pe_kernel<<<NPTS*64/256, 256, 0, stream>>>(pos, stats, pe);
    wt_kernel<<<dim3(256, 4, 2), 256, 0, stream>>>(Wx, Wy, Wt);
    wcast_kernel<<<768, 256, 0, stream>>>(Wq, Wk, Wv, Wo, W1, W2, wbuf);

    for (int base = 0; base < NPTS; base += chunk){
        cf_kernel<<<chunk, 256, 0, stream>>>(x, y, pos, nbr, Abuf, base, chunk);
        mfma_gemm_kernel<<<dim3(chunk/128, 1, 2*KSPLIT), 256, 0, stream>>>(Abuf, Wt, Pbuf, chunk);
        reduceP_kernel<<<dim3(chunk*128/256, 2), 256, 0, stream>>>(Pbuf, hconv, chunk, base);
    }

    bn_stats_kernel<<<dim3(128, 2), 256, 0, stream>>>(hconv, stats);
    bn_apply_kernel<<<dim3(NF/256, 2), 256, 0, stream>>>(hconv, stats, bnxg, bnxb, bnyg, bnyb,
                                                         pe, xf, hb);

    // qkv (z = f*3 + {q,k,v}) -> Qb/Kb/Vtb
    dgemm_kernel<2><<<dim3(32, 1, 6), 256, 0, stream>>>(hb, wbuf, bq, bk, bv,
        nullptr, Qb, Kb, Vtb, 128, (long)NF, 0);

    attn_mfma_kernel<<<dim3(64, 4, 2), 256, 0, stream>>>(Qb, Kb, Vtb, Ob);

    // o2 = Ob @ Wo^T + bo
    dgemm_kernel<0><<<dim3(32, 1, 2), 256, 0, stream>>>(Ob, wbuf + 49152, bo, nullptr, nullptr,
        o2, nullptr, nullptr, nullptr, 128, (long)NF, (long)NF);
    ln_res_kernel<<<dim3(NPTS, 2), 128, 0, stream>>>(xf, o2, ln1g, ln1b, feat1, feat1b);

    // ff1 = relu(feat1 @ W1^T + b1) -> bf16
    dgemm_kernel<1><<<dim3(32, 4, 2), 256, 0, stream>>>(feat1b, wbuf + 65536, b1, nullptr, nullptr,
        nullptr, ff1b, nullptr, nullptr, 128, (long)NF, 0);
    // ff2 = ff1 @ W2^T + b2
    dgemm_kernel<0><<<dim3(32, 1, 2), 256, 0, stream>>>(ff1b, wbuf + 131072, b2, nullptr, nullptr,
        ff2, nullptr, nullptr, nullptr, 512, (long)2097152, (long)NF);
    ln_res_kernel<<<dim3(NPTS, 2), 128, 0, stream>>>(feat1, ff2, ln2g, ln2b, xfo, nullptr);

    combine_kernel<<<NF/256, 256, 0, stream>>>(xfo, xfo + NF, x, y, (float*)d_out);
}

// Round 5
// 326.601 us; speedup vs baseline: 7.6771x; 1.0469x over previous
//
#include <hip/hip_runtime.h>
#include <cstddef>

#define NPTS 4096
#define KNBR 80
#define CH   128
#define NF   (NPTS*CH)      // 524288
#define FFD  512
#define KSPLIT 8
#define NSPLIT 4            // attention key-split

typedef unsigned short ushort_t;
typedef short bf16x8 __attribute__((ext_vector_type(8)));
typedef float f32x4 __attribute__((ext_vector_type(4)));

__device__ __forceinline__ unsigned short f2bf(float f){
    unsigned int u = __float_as_uint(f);
    unsigned int r = (u + 0x7FFFu + ((u >> 16) & 1u)) >> 16;
    return (unsigned short)r;
}

// pack two fp32 -> bf16 pair by truncation: low = hi16(a), high = hi16(b)
__device__ __forceinline__ unsigned pack2bf_trunc(float a, float b){
    return __builtin_amdgcn_perm(__float_as_uint(b), __float_as_uint(a), 0x07060302u);
}

__device__ __forceinline__ void load_lds16(const ushort_t* g, ushort_t* l){
    __builtin_amdgcn_global_load_lds(
        (const __attribute__((address_space(1))) unsigned int*)g,
        (__attribute__((address_space(3))) unsigned int*)l, 16, 0, 0);
}

// ---------------- pos stats ----------------
__global__ void pos_stats_kernel(const float* __restrict__ pos, float* __restrict__ stats){
    __shared__ float red[256];
    int t = threadIdx.x;
    float s = 0.f;
    for (int i = t; i < NPTS; i += 256) s += pos[(size_t)i*3];
    red[t] = s; __syncthreads();
    for (int o = 128; o; o >>= 1){ if (t < o) red[t] += red[t+o]; __syncthreads(); }
    float mean = red[0] / (float)NPTS;
    __syncthreads();
    float ss = 0.f;
    for (int i = t; i < NPTS; i += 256){ float d = pos[(size_t)i*3] - mean; ss += d*d; }
    red[t] = ss; __syncthreads();
    for (int o = 128; o; o >>= 1){ if (t < o) red[t] += red[t+o]; __syncthreads(); }
    if (t == 0){
        float sd = sqrtf(red[0] / (float)(NPTS-1));
        stats[512] = mean;
        stats[513] = 1.f/(sd + 1e-8f);
    }
}

// ---------------- positional encoding ----------------
__global__ void pe_kernel(const float* __restrict__ pos, const float* __restrict__ stats,
                          float* __restrict__ pe){
    int t = blockIdx.x*256 + threadIdx.x;
    int i = t >> 6, m = t & 63;
    float px = (pos[(size_t)i*3] - stats[512]) * stats[513];
    float dv = expf((float)(2*m) * -0.07195578415606394f);
    float ang = px * dv;
    float sv, cv;
    sincosf(ang, &sv, &cv);
    pe[(size_t)i*CH + 2*m]     = sv;
    pe[(size_t)i*CH + 2*m + 1] = cv;
}

// ---------------- conv W transpose+cast: Wt[f][n][k] = W_f[k][n] (bf16) ----------------
__global__ __launch_bounds__(256) void wt_kernel(const float* __restrict__ Wx,
        const float* __restrict__ Wy, ushort_t* __restrict__ Wt){
    __shared__ float tile[32][33];
    const float* W = blockIdx.z ? Wy : Wx;
    int kb = blockIdx.x, nb = blockIdx.y;
    int tr = threadIdx.x & 31, tc = threadIdx.x >> 5;
    #pragma unroll
    for (int rr = 0; rr < 32; rr += 8)
        tile[tc+rr][tr] = W[(size_t)(kb*32 + tc + rr)*128 + nb*32 + tr];
    __syncthreads();
    size_t fo = (size_t)blockIdx.z * 8192 * 128;
    #pragma unroll
    for (int rr = 0; rr < 32; rr += 8)
        Wt[fo + (size_t)(nb*32 + tc + rr)*8192 + kb*32 + tr] = f2bf(tile[tr][tc+rr]);
}

// ---------------- dense-weight cast (Wq|Wk|Wv|Wo|W1|W2 -> bf16 packed) ----------------
__global__ void wcast_kernel(const float* __restrict__ Wq, const float* __restrict__ Wk,
        const float* __restrict__ Wv, const float* __restrict__ Wo,
        const float* __restrict__ W1, const float* __restrict__ W2,
        ushort_t* __restrict__ dst){
    int i = blockIdx.x*256 + threadIdx.x;     // < 196608
    const float* src; int off;
    if      (i < 16384)  { src = Wq; off = i; }
    else if (i < 32768)  { src = Wk; off = i - 16384; }
    else if (i < 49152)  { src = Wv; off = i - 32768; }
    else if (i < 65536)  { src = Wo; off = i - 49152; }
    else if (i < 131072) { src = W1; off = i - 65536; }
    else                 { src = W2; off = i - 131072; }
    dst[i] = f2bf(src[off]);
}

// ---------------- cconv stage 1 (MFMA): A = Ct(64 x n) @ F(n x 128) -> bf16 ----------------
__global__ __launch_bounds__(256) void cf_kernel(
        const float* __restrict__ xin, const float* __restrict__ yin,
        const float* __restrict__ pos, const int* __restrict__ nbr,
        ushort_t* __restrict__ Abuf, int base, int chunk){
    __shared__ ushort_t Ct[64*96];
    __shared__ ushort_t Ft[128*40];
    __shared__ int nbl[KNBR];
    __shared__ int cnt;
    int i = base + blockIdx.x;
    int t = threadIdx.x;
    for (int z = t; z < 64*96/8; z += 256) ((uint4*)Ct)[z] = uint4{0,0,0,0};
    if (t == 0) cnt = 0;
    __syncthreads();
    if (t < KNBR){
        int nb = nbr[(size_t)i*KNBR + t];
        if (nb != i){
            float p0 = pos[(size_t)i*3], p1 = pos[(size_t)i*3+1], p2 = pos[(size_t)i*3+2];
            const float RAD = 0.1125f;
            float rx = (pos[(size_t)nb*3+0]-p0)/RAD;
            float ry = (pos[(size_t)nb*3+1]-p1)/RAD;
            float rz = (pos[(size_t)nb*3+2]-p2)/RAD;
            float r2 = rx*rx + ry*ry + rz*rz;
            float w1 = 1.f - r2;
            float win = fminf(fmaxf(w1*w1*w1, 0.f), 1.f);
            float nrm = sqrtf(fmaxf(r2, 1e-12f));
            float linf = fmaxf(fmaxf(fabsf(rx), fabsf(ry)), fabsf(rz));
            linf = fmaxf(linf, 1e-9f);
            float sc = nrm/linf;
            float gx = fminf(fmaxf((rx*sc+1.f)*0.5f*3.f, 0.f), 3.f);
            float gy = fminf(fmaxf((ry*sc+1.f)*0.5f*3.f, 0.f), 3.f);
            float gz = fminf(fmaxf((rz*sc+1.f)*0.5f*3.f, 0.f), 3.f);
            float fx = fminf(floorf(gx), 2.f), fy = fminf(floorf(gy), 2.f), fz = fminf(floorf(gz), 2.f);
            float tx = gx-fx, ty = gy-fy, tz = gz-fz;
            int ix = (int)fx, iy = (int)fy, iz = (int)fz;
            int cb = (ix<<4) + (iy<<2) + iz;
            float x0 = (1.f-tx)*win, x1 = tx*win;
            float w00 = x0*(1.f-ty), w01 = x0*ty, w10 = x1*(1.f-ty), w11 = x1*ty;
            float z0 = 1.f-tz, z1 = tz;
            int slot = atomicAdd(&cnt, 1);
            nbl[slot] = nb;
            Ct[(cb     )*96 + slot] = f2bf(w00*z0);
            Ct[(cb + 1 )*96 + slot] = f2bf(w00*z1);
            Ct[(cb + 4 )*96 + slot] = f2bf(w01*z0);
            Ct[(cb + 5 )*96 + slot] = f2bf(w01*z1);
            Ct[(cb + 16)*96 + slot] = f2bf(w10*z0);
            Ct[(cb + 17)*96 + slot] = f2bf(w10*z1);
            Ct[(cb + 20)*96 + slot] = f2bf(w11*z0);
            Ct[(cb + 21)*96 + slot] = f2bf(w11*z1);
        }
    }
    __syncthreads();
    int n = cnt;
    int nch = (n + 31) >> 5;
    int lane = t & 63, w = t >> 6;
    int l15 = lane & 15, quad = lane >> 4;
    int gj = t >> 3, gpart = t & 7;
    for (int f = 0; f < 2; ++f){
        const float* feat = f ? yin : xin;
        f32x4 acc[8] = {};
        for (int ck = 0; ck < nch; ++ck){
            __syncthreads();
            int js = ck*32 + gj;
            if (js < n){
                const float* src = feat + (size_t)nbl[js]*128 + gpart*16;
                #pragma unroll
                for (int u4 = 0; u4 < 16; u4 += 4){
                    float4 v4 = *(const float4*)(src + u4);
                    Ft[(gpart*16 + u4    )*40 + gj] = f2bf(v4.x);
                    Ft[(gpart*16 + u4 + 1)*40 + gj] = f2bf(v4.y);
                    Ft[(gpart*16 + u4 + 2)*40 + gj] = f2bf(v4.z);
                    Ft[(gpart*16 + u4 + 3)*40 + gj] = f2bf(v4.w);
                }
            } else {
                #pragma unroll
                for (int u = 0; u < 16; ++u)
                    Ft[(gpart*16 + u)*40 + gj] = 0;
            }
            __syncthreads();
            bf16x8 af = *(const bf16x8*)(Ct + (size_t)(w*16 + l15)*96 + ck*32 + quad*8);
            #pragma unroll
            for (int nt = 0; nt < 8; ++nt){
                bf16x8 bfr = *(const bf16x8*)(Ft + (size_t)(nt*16 + l15)*40 + quad*8);
                acc[nt] = __builtin_amdgcn_mfma_f32_16x16x32_bf16(af, bfr, acc[nt], 0, 0, 0);
            }
        }
        ushort_t* dst = Abuf + ((size_t)f*chunk + blockIdx.x)*8192;
        #pragma unroll
        for (int nt = 0; nt < 8; ++nt)
            #pragma unroll
            for (int reg = 0; reg < 4; ++reg){
                int cell = w*16 + quad*4 + reg;
                int c    = nt*16 + l15;
                dst[(size_t)cell*128 + c] = f2bf(acc[nt][reg]);
            }
    }
}

// ---------------- cconv stage 2: MFMA GEMM  P = A(bf16) @ Wt^T, split-K ----------------
__global__ __launch_bounds__(256) void mfma_gemm_kernel(
        const ushort_t* __restrict__ Abuf, const ushort_t* __restrict__ Wt,
        float* __restrict__ Pbuf, int chunk){
    __shared__ ushort_t Asm[128*64];
    __shared__ ushort_t Bsm[128*64];
    int tid = threadIdx.x, lane = tid & 63, w = tid >> 6;
    int feat = blockIdx.z >> 3, s = blockIdx.z & 7;
    const ushort_t* Ab = Abuf + (size_t)feat*chunk*8192 + (size_t)blockIdx.x*128*8192;
    const ushort_t* Bb = Wt + (size_t)feat*128*8192;
    int wm = w >> 1, wn = w & 1;
    int lr = lane >> 3, pb = lane & 7, lb = pb ^ lr;
    int quad = lane >> 4, l15 = lane & 15;
    int arow0 = w*32;
    f32x4 acc[4][4] = {};
    const int kk0 = s*(8192/KSPLIT), kk1 = kk0 + 8192/KSPLIT;
    for (int kk = kk0; kk < kk1; kk += 64){
        __syncthreads();
        #pragma unroll
        for (int q = 0; q < 4; ++q){
            int r = arow0 + q*8 + lr;
            load_lds16(Ab + (size_t)r*8192 + kk + lb*8, Asm + (arow0 + q*8)*64);
            load_lds16(Bb + (size_t)r*8192 + kk + lb*8, Bsm + (arow0 + q*8)*64);
        }
        __syncthreads();
        #pragma unroll
        for (int h = 0; h < 2; ++h){
            bf16x8 aF[4], bF[4];
            #pragma unroll
            for (int mt = 0; mt < 4; ++mt){
                int ml = wm*64 + mt*16 + l15;
                int p = (h*4 + quad) ^ (ml & 7);
                aF[mt] = *(const bf16x8*)(Asm + ml*64 + p*8);
            }
            #pragma unroll
            for (int nt = 0; nt < 4; ++nt){
                int nl = wn*64 + nt*16 + l15;
                int p = (h*4 + quad) ^ (nl & 7);
                bF[nt] = *(const bf16x8*)(Bsm + nl*64 + p*8);
            }
            #pragma unroll
            for (int mt = 0; mt < 4; ++mt)
                #pragma unroll
                for (int nt = 0; nt < 4; ++nt)
                    acc[mt][nt] = __builtin_amdgcn_mfma_f32_16x16x32_bf16(
                        aF[mt], bF[nt], acc[mt][nt], 0, 0, 0);
        }
    }
    float* P = Pbuf + (size_t)blockIdx.z*chunk*128 + (size_t)blockIdx.x*128*128;
    #pragma unroll
    for (int mt = 0; mt < 4; ++mt)
        #pragma unroll
        for (int nt = 0; nt < 4; ++nt)
            #pragma unroll
            for (int reg = 0; reg < 4; ++reg){
                int r = wm*64 + mt*16 + quad*4 + reg;
                int c = wn*64 + nt*16 + l15;
                P[(size_t)r*128 + c] = acc[mt][nt][reg];
            }
}

__global__ void reduceP_kernel(const float* __restrict__ P, float* __restrict__ hconv,
                               int chunk, int base){
    int f = blockIdx.y;
    size_t idx = (size_t)blockIdx.x*256 + threadIdx.x;
    float s = 0.f;
    #pragma unroll
    for (int sp = 0; sp < KSPLIT; ++sp)
        s += P[((size_t)(f*KSPLIT + sp))*chunk*128 + idx];
    hconv[(size_t)f*NF + (size_t)base*128 + idx] = s;
}

// ---------------- generic dense MFMA GEMM: D = A(M x K) @ B(N x K)^T ----------------
template<int MODE>
__global__ __launch_bounds__(256) void dgemm_kernel(
        const ushort_t* __restrict__ A, const ushort_t* __restrict__ Bw,
        const float* __restrict__ bs0, const float* __restrict__ bs1,
        const float* __restrict__ bs2,
        float* __restrict__ oF, ushort_t* __restrict__ oB0,
        ushort_t* __restrict__ oB1, ushort_t* __restrict__ oB2,
        int K, long aZ, long oZ){
    __shared__ ushort_t Asm[128*64];
    __shared__ ushort_t Bsm[128*64];
    int tid = threadIdx.x, lane = tid & 63, w = tid >> 6;
    int z = blockIdx.z;
    int f = (MODE == 2) ? (z/3) : z;
    int wsel = (MODE == 2) ? (z - 3*f) : 0;
    const ushort_t* Ab = A + (size_t)f*aZ + (size_t)blockIdx.x*128*K;
    const ushort_t* Bb = Bw + ((MODE == 2) ? (size_t)wsel*16384 : 0)
                            + (size_t)blockIdx.y*128*K;
    int wm = w >> 1, wn = w & 1;
    int lr = lane >> 3, pb = lane & 7, lb = pb ^ lr;
    int quad = lane >> 4, l15 = lane & 15;
    int arow0 = w*32;
    f32x4 acc[4][4] = {};
    for (int kk = 0; kk < K; kk += 64){
        __syncthreads();
        #pragma unroll
        for (int q = 0; q < 4; ++q){
            int r = arow0 + q*8 + lr;
            load_lds16(Ab + (size_t)r*K + kk + lb*8, Asm + (arow0 + q*8)*64);
            load_lds16(Bb + (size_t)r*K + kk + lb*8, Bsm + (arow0 + q*8)*64);
        }
        __syncthreads();
        #pragma unroll
        for (int h = 0; h < 2; ++h){
            bf16x8 aF[4], bF[4];
            #pragma unroll
            for (int mt = 0; mt < 4; ++mt){
                int ml = wm*64 + mt*16 + l15;
                int p = (h*4 + quad) ^ (ml & 7);
                aF[mt] = *(const bf16x8*)(Asm + ml*64 + p*8);
            }
            #pragma unroll
            for (int nt = 0; nt < 4; ++nt){
                int nl = wn*64 + nt*16 + l15;
                int p = (h*4 + quad) ^ (nl & 7);
                bF[nt] = *(const bf16x8*)(Bsm + nl*64 + p*8);
            }
            #pragma unroll
            for (int mt = 0; mt < 4; ++mt)
                #pragma unroll
                for (int nt = 0; nt < 4; ++nt)
                    acc[mt][nt] = __builtin_amdgcn_mfma_f32_16x16x32_bf16(
                        aF[mt], bF[nt], acc[mt][nt], 0, 0, 0);
        }
    }
    int r0 = blockIdx.x*128, c0 = blockIdx.y*128;
    const float* bias = bs0;
    float osc = 1.f;
    if (MODE == 2){
        bias = (wsel == 0) ? bs0 : (wsel == 1 ? bs1 : bs2);
        // Q scale: log2(e)/sqrt(32)  (softmax runs in exp2 domain)
        if (wsel == 0) osc = 0.25506764057565145f;
    }
    #pragma unroll
    for (int mt = 0; mt < 4; ++mt)
        #pragma unroll
        for (int nt = 0; nt < 4; ++nt)
            #pragma unroll
            for (int reg = 0; reg < 4; ++reg){
                int R = r0 + wm*64 + mt*16 + quad*4 + reg;
                int C = c0 + wn*64 + nt*16 + l15;
                float v = acc[mt][nt][reg];
                if (MODE == 0){
                    oF[(size_t)z*oZ + (size_t)R*128 + C] = v + bias[C];
                } else if (MODE == 1){
                    float r = fmaxf(v + bias[C], 0.f);
                    oB0[(size_t)z*2097152 + (size_t)R*512 + C] = f2bf(r);
                } else {
                    float r = (v + bias[C])*osc;
                    int hh = C >> 5, dd = C & 31;
                    if (wsel < 2){
                        ushort_t* dst = wsel ? oB1 : oB0;
                        dst[((size_t)(f*4+hh)*4096 + R)*32 + dd] = f2bf(r);
                    } else {
                        oB2[((size_t)(f*4+hh)*32 + dd)*4096 + R] = f2bf(r);
                    }
                }
            }
}

// ---------------- BatchNorm ----------------
__global__ void bn_stats_kernel(const float* __restrict__ hconv, float* __restrict__ stats){
    __shared__ float rs[256];
    __shared__ float rq[256];
    int ch = blockIdx.x, f = blockIdx.y, t = threadIdx.x;
    const float* src = hconv + (size_t)f*NF;
    float s = 0.f, q2 = 0.f;
    for (int r = t; r < NPTS; r += 256){
        float vv = src[(size_t)r*CH + ch];
        s += vv; q2 += vv*vv;
    }
    rs[t] = s; rq[t] = q2; __syncthreads();
    for (int o = 128; o; o >>= 1){
        if (t < o){ rs[t] += rs[t+o]; rq[t] += rq[t+o]; }
        __syncthreads();
    }
    if (t == 0){
        float m = rs[0]/(float)NPTS;
        float var = rq[0]/(float)NPTS - m*m;
        stats[f*128 + ch] = m;
        stats[256 + f*128 + ch] = rsqrtf(var + 1e-5f);
    }
}

__global__ void bn_apply_kernel(const float* __restrict__ hconv, const float* __restrict__ stats,
        const float* __restrict__ gx, const float* __restrict__ bxp,
        const float* __restrict__ gy, const float* __restrict__ byp,
        const float* __restrict__ pe,
        float* __restrict__ xf, ushort_t* __restrict__ hb){
    int f = blockIdx.y;
    size_t idx = (size_t)blockIdx.x*256 + threadIdx.x;
    int ch = idx & 127;
    const float* g = f ? gy : gx;
    const float* b = f ? byp : bxp;
    float m = stats[f*128 + ch], inv = stats[256 + f*128 + ch];
    float vv = hconv[(size_t)f*NF + idx];
    float r = fmaxf((vv - m)*inv*g[ch] + b[ch], 0.f);
    xf[(size_t)f*NF + idx] = r;
    hb[(size_t)f*NF + idx] = f2bf(r + pe[idx]);
}

// ---------------- MFMA flash attention, key-split (exp2 domain) ----------------
// grid (64, 4, 2*NSPLIT); block 256 = 4 waves x 16 queries.
// Vl row 32 = ones -> PV MFMA emits row-sum l for free.
__global__ __launch_bounds__(256) void attn_mfma_kernel(
        const ushort_t* __restrict__ Qb, const ushort_t* __restrict__ Kb,
        const ushort_t* __restrict__ Vt, float* __restrict__ Opart,
        float* __restrict__ ml){
    __shared__ ushort_t Kl[64*40];
    __shared__ ushort_t Vl[48*72];
    __shared__ ushort_t Pl[64*72];
    int tid = threadIdx.x, lane = tid & 63, w = tid >> 6;
    int l15 = lane & 15, quad = lane >> 4;
    int q0 = blockIdx.x*64;
    int head = blockIdx.y;
    int f = blockIdx.z >> 2, ksp = blockIdx.z & (NSPLIT-1);
    const ushort_t* Qh = Qb + ((size_t)(f*4+head)*4096)*32;
    const ushort_t* Kh = Kb + ((size_t)(f*4+head)*4096)*32;
    const ushort_t* Vh = Vt + ((size_t)(f*4+head)*32)*4096;
    int ql = w*16 + l15;
    int qg = q0 + ql;
    bf16x8 qfrag = *(const bf16x8*)(Qh + (size_t)qg*32 + quad*8);
    // rows 32..47 of Vl: row 32 = ones (bf16 1.0), rest zero
    for (int z = tid; z < 16*72; z += 256)
        Vl[32*72 + z] = (z < 72) ? (ushort_t)0x3F80 : (ushort_t)0;
    f32x4 oacc[3] = {};
    float mprev = -3.0e38f;
    int kr = tid >> 2, kseg = tid & 3;
    int vd = tid >> 3, vseg = tid & 7;
    for (int kt = 0; kt < 4096/NSPLIT/64; ++kt){
        int k0 = ksp*(4096/NSPLIT) + kt*64;
        uint4 tk = *(const uint4*)(Kh + (size_t)(k0+kr)*32 + kseg*8);
        uint4 tv = *(const uint4*)(Vh + (size_t)vd*4096 + k0 + vseg*8);
        __syncthreads();
        *(uint4*)(Kl + kr*40 + kseg*8) = tk;
        *(uint4*)(Vl + vd*72 + vseg*8) = tv;
        __syncthreads();
        f32x4 sc[4] = {};
        #pragma unroll
        for (int mt = 0; mt < 4; ++mt){
            bf16x8 af = *(const bf16x8*)(Kl + (mt*16 + l15)*40 + quad*8);
            sc[mt] = __builtin_amdgcn_mfma_f32_16x16x32_bf16(af, qfrag, sc[mt], 0, 0, 0);
        }
        float mloc = -3.0e38f;
        #pragma unroll
        for (int mt = 0; mt < 4; ++mt)
            #pragma unroll
            for (int r = 0; r < 4; ++r) mloc = fmaxf(mloc, sc[mt][r]);
        mloc = fmaxf(mloc, __shfl_xor(mloc, 16));
        mloc = fmaxf(mloc, __shfl_xor(mloc, 32));
        float mnew = fmaxf(mprev, mloc);
        float alpha = exp2f(mprev - mnew);
        #pragma unroll
        for (int mt = 0; mt < 4; ++mt){
            float p0 = exp2f(sc[mt][0] - mnew);
            float p1 = exp2f(sc[mt][1] - mnew);
            float p2 = exp2f(sc[mt][2] - mnew);
            float p3 = exp2f(sc[mt][3] - mnew);
            uint2 pk;
            pk.x = pack2bf_trunc(p0, p1);
            pk.y = pack2bf_trunc(p2, p3);
            *(uint2*)(Pl + ql*72 + mt*16 + quad*4) = pk;
        }
        mprev = mnew;
        #pragma unroll
        for (int i = 0; i < 3; ++i)
            #pragma unroll
            for (int r = 0; r < 4; ++r) oacc[i][r] *= alpha;
        #pragma unroll
        for (int ks2 = 0; ks2 < 2; ++ks2){
            bf16x8 bfr = *(const bf16x8*)(Pl + ql*72 + ks2*32 + quad*8);
            #pragma unroll
            for (int mtv = 0; mtv < 3; ++mtv){
                bf16x8 af = *(const bf16x8*)(Vl + (mtv*16 + l15)*72 + ks2*32 + quad*8);
                oacc[mtv] = __builtin_amdgcn_mfma_f32_16x16x32_bf16(af, bfr, oacc[mtv], 0, 0, 0);
            }
        }
    }
    float lval = __shfl(oacc[2][0], l15);   // row 32 (ones) output, held by quad 0
    int slot = (f*4 + head)*NSPLIT + ksp;
    float* Op = Opart + (((size_t)slot*4096 + qg)*32);
    #pragma unroll
    for (int mtv = 0; mtv < 2; ++mtv)
        #pragma unroll
        for (int r = 0; r < 4; ++r)
            Op[mtv*16 + quad*4 + r] = oacc[mtv][r];
    if (quad == 0){
        ml[((size_t)slot*4096 + qg)*2 + 0] = mprev;
        ml[((size_t)slot*4096 + qg)*2 + 1] = lval;
    }
}

// ---------------- attention split combine -> Ob (bf16 [f][q][128]) ----------------
__global__ void attn_combine_kernel(const float* __restrict__ Opart,
        const float* __restrict__ ml, ushort_t* __restrict__ Ob){
    int gid = blockIdx.x*256 + threadIdx.x;     // < 2*4*4096*32
    int fh = gid >> 17;
    int rem = gid & 131071;
    int q = rem >> 5, d = rem & 31;
    float mv[NSPLIT], lv[NSPLIT];
    float mstar = -3.0e38f;
    #pragma unroll
    for (int s = 0; s < NSPLIT; ++s){
        size_t o = (((size_t)fh*NSPLIT + s)*4096 + q)*2;
        mv[s] = ml[o];
        lv[s] = ml[o + 1];
        mstar = fmaxf(mstar, mv[s]);
    }
    float lsum = 0.f, osum = 0.f;
    #pragma unroll
    for (int s = 0; s < NSPLIT; ++s){
        float wgt = exp2f(mv[s] - mstar);
        lsum += lv[s]*wgt;
        osum += Opart[(((size_t)fh*NSPLIT + s)*4096 + q)*32 + d]*wgt;
    }
    int f = fh >> 2, head = fh & 3;
    Ob[(size_t)f*NF + (size_t)q*128 + head*32 + d] = f2bf(osum/lsum);
}

// ---------------- LayerNorm(a + b), optional bf16 copy ----------------
__global__ __launch_bounds__(128) void ln_res_kernel(const float* __restrict__ a,
        const float* __restrict__ b, const float* __restrict__ g,
        const float* __restrict__ be, float* __restrict__ out,
        ushort_t* __restrict__ outB){
    __shared__ float red[128];
    int t = threadIdx.x;
    size_t off = (size_t)blockIdx.y*NF + (size_t)blockIdx.x*CH;
    float v = a[off + t] + b[off + t];
    red[t] = v; __syncthreads();
    for (int o = 64; o; o >>= 1){ if (t < o) red[t] += red[t+o]; __syncthreads(); }
    float m = red[0] / 128.f;
    __syncthreads();
    float d = v - m;
    red[t] = d*d; __syncthreads();
    for (int o = 64; o; o >>= 1){ if (t < o) red[t] += red[t+o]; __syncthreads(); }
    float var = red[0] / 128.f;
    float res = (v - m)*rsqrtf(var + 1e-5f)*g[t] + be[t];
    out[off + t] = res;
    if (outB) outB[off + t] = f2bf(res);
}

__global__ void combine_kernel(const float* __restrict__ xfo, const float* __restrict__ yfo,
        const float* __restrict__ x, const float* __restrict__ y, float* __restrict__ out){
    size_t idx = (size_t)blockIdx.x*256 + threadIdx.x;
    float s = xfo[idx] + yfo[idx];
    float w = 1.f/(1.f + __expf(-s));
    out[idx] = 2.f*x[idx]*w + 2.f*y[idx]*(1.f - w);
}

extern "C" void kernel_launch(void* const* d_in, const int* in_sizes, int n_in,
                              void* d_out, int out_size, void* d_ws, size_t ws_size,
                              hipStream_t stream){
    (void)in_sizes; (void)n_in; (void)out_size;
    const float* x    = (const float*)d_in[0];
    const float* y    = (const float*)d_in[1];
    const float* pos  = (const float*)d_in[2];
    const int*   nbr  = (const int*)  d_in[3];
    const float* Wx   = (const float*)d_in[5];
    const float* bnxg = (const float*)d_in[7];
    const float* bnxb = (const float*)d_in[8];
    const float* Wy   = (const float*)d_in[9];
    const float* bnyg = (const float*)d_in[11];
    const float* bnyb = (const float*)d_in[12];
    const float* Wq   = (const float*)d_in[13];
    const float* bq   = (const float*)d_in[14];
    const float* Wk   = (const float*)d_in[15];
    const float* bk   = (const float*)d_in[16];
    const float* Wv   = (const float*)d_in[17];
    const float* bv   = (const float*)d_in[18];
    const float* Wo   = (const float*)d_in[19];
    const float* bo   = (const float*)d_in[20];
    const float* ln1g = (const float*)d_in[21];
    const float* ln1b = (const float*)d_in[22];
    const float* W1   = (const float*)d_in[23];
    const float* b1   = (const float*)d_in[24];
    const float* W2   = (const float*)d_in[25];
    const float* b2   = (const float*)d_in[26];
    const float* ln2g = (const float*)d_in[27];
    const float* ln2b = (const float*)d_in[28];

    float* ws     = (float*)d_ws;
    float* pe     = ws;                       // NF
    float* hconv  = pe + NF;                  // 2NF
    float* xf     = hconv + (size_t)2*NF;     // 2NF
    float* o2     = xf + (size_t)2*NF;        // 2NF
    float* feat1  = o2 + (size_t)2*NF;        // 2NF
    float* ff2    = feat1 + (size_t)2*NF;     // 2NF
    float* stats  = ff2 + (size_t)2*NF;       // 2048
    float* Opart  = stats + 2048;             // 2*4*NSPLIT*4096*32 = 4194304
    float* mlbuf  = Opart + 4194304;          // 2*4*NSPLIT*4096*2  = 262144
    float* Pbuf   = mlbuf + 262144;           // 2048*chunk
    float* xfo    = xf;

    const size_t fixedFloats = (size_t)11*NF + 2048 + 4194304 + 262144;
    const size_t fixedUsh = (size_t)2097152 + 196608 + 6*1048576 + 4194304;
    int chunk = 128;
    const int cand[6] = {4096, 2048, 1024, 512, 256, 128};
    for (int ci = 0; ci < 6; ++ci){
        size_t need = (fixedFloats + (size_t)2048*cand[ci])*4
                    + (fixedUsh + (size_t)2*cand[ci]*8192)*2;
        if (need <= ws_size){ chunk = cand[ci]; break; }
    }
    ushort_t* Wt     = (ushort_t*)(Pbuf + (size_t)2048*chunk);
    ushort_t* wbuf   = Wt + 2097152;
    ushort_t* hb     = wbuf + 196608;
    ushort_t* Qb     = hb + 1048576;
    ushort_t* Kb     = Qb + 1048576;
    ushort_t* Vtb    = Kb + 1048576;
    ushort_t* Ob     = Vtb + 1048576;
    ushort_t* feat1b = Ob + 1048576;
    ushort_t* ff1b   = feat1b + 1048576;
    ushort_t* Abuf   = ff1b + 4194304;

    pos_stats_kernel<<<1, 256, 0, stream>>>(pos, stats);
    pe_kernel<<<NPTS*64/256, 256, 0, stream>>>(pos, stats, pe);
    wt_kernel<<<dim3(256, 4, 2), 256, 0, stream>>>(Wx, Wy, Wt);
    wcast_kernel<<<768, 256, 0, stream>>>(Wq, Wk, Wv, Wo, W1, W2, wbuf);

    for (int base = 0; base < NPTS; base += chunk){
        cf_kernel<<<chunk, 256, 0, stream>>>(x, y, pos, nbr, Abuf, base, chunk);
        mfma_gemm_kernel<<<dim3(chunk/128, 1, 2*KSPLIT), 256, 0, stream>>>(Abuf, Wt, Pbuf, chunk);
        reduceP_kernel<<<dim3(chunk*128/256, 2), 256, 0, stream>>>(Pbuf, hconv, chunk, base);
    }

    bn_stats_kernel<<<dim3(128, 2), 256, 0, stream>>>(hconv, stats);
    bn_apply_kernel<<<dim3(NF/256, 2), 256, 0, stream>>>(hconv, stats, bnxg, bnxb, bnyg, bnyb,
                                                         pe, xf, hb);

    dgemm_kernel<2><<<dim3(32, 1, 6), 256, 0, stream>>>(hb, wbuf, bq, bk, bv,
        nullptr, Qb, Kb, Vtb, 128, (long)NF, 0);

    attn_mfma_kernel<<<dim3(64, 4, 2*NSPLIT), 256, 0, stream>>>(Qb, Kb, Vtb, Opart, mlbuf);
    attn_combine_kernel<<<4096, 256, 0, stream>>>(Opart, mlbuf, Ob);

    dgemm_kernel<0><<<dim3(32, 1, 2), 256, 0, stream>>>(Ob, wbuf + 49152, bo, nullptr, nullptr,
        o2, nullptr, nullptr, nullptr, 128, (long)NF, (long)NF);
    ln_res_kernel<<<dim3(NPTS, 2), 128, 0, stream>>>(xf, o2, ln1g, ln1b, feat1, feat1b);

    dgemm_kernel<1><<<dim3(32, 4, 2), 256, 0, stream>>>(feat1b, wbuf + 65536, b1, nullptr, nullptr,
        nullptr, ff1b, nullptr, nullptr, 128, (long)NF, 0);
    dgemm_kernel<0><<<dim3(32, 1, 2), 256, 0, stream>>>(ff1b, wbuf + 131072, b2, nullptr, nullptr,
        ff2, nullptr, nullptr, nullptr, 512, (long)2097152, (long)NF);
    ln_res_kernel<<<dim3(NPTS, 2), 128, 0, stream>>>(feat1, ff2, ln2g, ln2b, xfo, nullptr);

    combine_kernel<<<NF/256, 256, 0, stream>>>(xfo, xfo + NF, x, y, (float*)d_out);
}

// Round 6
// 326.458 us; speedup vs baseline: 7.6805x; 1.0004x over previous
//
#include <hip/hip_runtime.h>
#include <cstddef>

#define NPTS 4096
#define KNBR 80
#define CH   128
#define NF   (NPTS*CH)      // 524288
#define FFD  512
#define KSPLIT 8
#define NSPLIT 8            // attention key-split

typedef unsigned short ushort_t;
typedef short bf16x8 __attribute__((ext_vector_type(8)));
typedef float f32x4 __attribute__((ext_vector_type(4)));

__device__ __forceinline__ unsigned short f2bf(float f){
    unsigned int u = __float_as_uint(f);
    unsigned int r = (u + 0x7FFFu + ((u >> 16) & 1u)) >> 16;
    return (unsigned short)r;
}

// pack two fp32 -> bf16 pair by truncation: low = hi16(a), high = hi16(b)
__device__ __forceinline__ unsigned pack2bf_trunc(float a, float b){
    return __builtin_amdgcn_perm(__float_as_uint(b), __float_as_uint(a), 0x07060302u);
}

__device__ __forceinline__ void load_lds16(const ushort_t* g, ushort_t* l){
    __builtin_amdgcn_global_load_lds(
        (const __attribute__((address_space(1))) unsigned int*)g,
        (__attribute__((address_space(3))) unsigned int*)l, 16, 0, 0);
}

// ---------------- pos stats (+ zero BN accumulators) ----------------
__global__ void pos_stats_kernel(const float* __restrict__ pos, float* __restrict__ stats){
    __shared__ float red[256];
    int t = threadIdx.x;
    stats[t] = 0.f;            // BN sum accumulators [0..255]
    stats[256 + t] = 0.f;      // BN sumsq accumulators [256..511]
    float s = 0.f;
    for (int i = t; i < NPTS; i += 256) s += pos[(size_t)i*3];
    red[t] = s; __syncthreads();
    for (int o = 128; o; o >>= 1){ if (t < o) red[t] += red[t+o]; __syncthreads(); }
    float mean = red[0] / (float)NPTS;
    __syncthreads();
    float ss = 0.f;
    for (int i = t; i < NPTS; i += 256){ float d = pos[(size_t)i*3] - mean; ss += d*d; }
    red[t] = ss; __syncthreads();
    for (int o = 128; o; o >>= 1){ if (t < o) red[t] += red[t+o]; __syncthreads(); }
    if (t == 0){
        float sd = sqrtf(red[0] / (float)(NPTS-1));
        stats[512] = mean;
        stats[513] = 1.f/(sd + 1e-8f);
    }
}

// ---------------- positional encoding ----------------
__global__ void pe_kernel(const float* __restrict__ pos, const float* __restrict__ stats,
                          float* __restrict__ pe){
    int t = blockIdx.x*256 + threadIdx.x;
    int i = t >> 6, m = t & 63;
    float px = (pos[(size_t)i*3] - stats[512]) * stats[513];
    float dv = expf((float)(2*m) * -0.07195578415606394f);
    float ang = px * dv;
    float sv, cv;
    sincosf(ang, &sv, &cv);
    pe[(size_t)i*CH + 2*m]     = sv;
    pe[(size_t)i*CH + 2*m + 1] = cv;
}

// ---------------- conv W transpose+cast: Wt[f][n][k] = W_f[k][n] (bf16) ----------------
__global__ __launch_bounds__(256) void wt_kernel(const float* __restrict__ Wx,
        const float* __restrict__ Wy, ushort_t* __restrict__ Wt){
    __shared__ float tile[32][33];
    const float* W = blockIdx.z ? Wy : Wx;
    int kb = blockIdx.x, nb = blockIdx.y;
    int tr = threadIdx.x & 31, tc = threadIdx.x >> 5;
    #pragma unroll
    for (int rr = 0; rr < 32; rr += 8)
        tile[tc+rr][tr] = W[(size_t)(kb*32 + tc + rr)*128 + nb*32 + tr];
    __syncthreads();
    size_t fo = (size_t)blockIdx.z * 8192 * 128;
    #pragma unroll
    for (int rr = 0; rr < 32; rr += 8)
        Wt[fo + (size_t)(nb*32 + tc + rr)*8192 + kb*32 + tr] = f2bf(tile[tr][tc+rr]);
}

// ---------------- dense-weight cast (Wq|Wk|Wv|Wo|W1|W2 -> bf16 packed) ----------------
__global__ void wcast_kernel(const float* __restrict__ Wq, const float* __restrict__ Wk,
        const float* __restrict__ Wv, const float* __restrict__ Wo,
        const float* __restrict__ W1, const float* __restrict__ W2,
        ushort_t* __restrict__ dst){
    int i = blockIdx.x*256 + threadIdx.x;     // < 196608
    const float* src; int off;
    if      (i < 16384)  { src = Wq; off = i; }
    else if (i < 32768)  { src = Wk; off = i - 16384; }
    else if (i < 49152)  { src = Wv; off = i - 32768; }
    else if (i < 65536)  { src = Wo; off = i - 49152; }
    else if (i < 131072) { src = W1; off = i - 65536; }
    else                 { src = W2; off = i - 131072; }
    dst[i] = f2bf(src[off]);
}

// ---------------- cconv stage 1 (MFMA): A = Ct(64 x n) @ F(n x 128) -> bf16 ----------------
__global__ __launch_bounds__(256) void cf_kernel(
        const float* __restrict__ xin, const float* __restrict__ yin,
        const float* __restrict__ pos, const int* __restrict__ nbr,
        ushort_t* __restrict__ Abuf, int base, int chunk){
    __shared__ ushort_t Ct[64*96];
    __shared__ ushort_t Ft[128*40];
    __shared__ int nbl[KNBR];
    __shared__ int cnt;
    int i = base + blockIdx.x;
    int t = threadIdx.x;
    for (int z = t; z < 64*96/8; z += 256) ((uint4*)Ct)[z] = uint4{0,0,0,0};
    if (t == 0) cnt = 0;
    __syncthreads();
    if (t < KNBR){
        int nb = nbr[(size_t)i*KNBR + t];
        if (nb != i){
            float p0 = pos[(size_t)i*3], p1 = pos[(size_t)i*3+1], p2 = pos[(size_t)i*3+2];
            const float RAD = 0.1125f;
            float rx = (pos[(size_t)nb*3+0]-p0)/RAD;
            float ry = (pos[(size_t)nb*3+1]-p1)/RAD;
            float rz = (pos[(size_t)nb*3+2]-p2)/RAD;
            float r2 = rx*rx + ry*ry + rz*rz;
            float w1 = 1.f - r2;
            float win = fminf(fmaxf(w1*w1*w1, 0.f), 1.f);
            float nrm = sqrtf(fmaxf(r2, 1e-12f));
            float linf = fmaxf(fmaxf(fabsf(rx), fabsf(ry)), fabsf(rz));
            linf = fmaxf(linf, 1e-9f);
            float sc = nrm/linf;
            float gx = fminf(fmaxf((rx*sc+1.f)*0.5f*3.f, 0.f), 3.f);
            float gy = fminf(fmaxf((ry*sc+1.f)*0.5f*3.f, 0.f), 3.f);
            float gz = fminf(fmaxf((rz*sc+1.f)*0.5f*3.f, 0.f), 3.f);
            float fx = fminf(floorf(gx), 2.f), fy = fminf(floorf(gy), 2.f), fz = fminf(floorf(gz), 2.f);
            float tx = gx-fx, ty = gy-fy, tz = gz-fz;
            int ix = (int)fx, iy = (int)fy, iz = (int)fz;
            int cb = (ix<<4) + (iy<<2) + iz;
            float x0 = (1.f-tx)*win, x1 = tx*win;
            float w00 = x0*(1.f-ty), w01 = x0*ty, w10 = x1*(1.f-ty), w11 = x1*ty;
            float z0 = 1.f-tz, z1 = tz;
            int slot = atomicAdd(&cnt, 1);
            nbl[slot] = nb;
            Ct[(cb     )*96 + slot] = f2bf(w00*z0);
            Ct[(cb + 1 )*96 + slot] = f2bf(w00*z1);
            Ct[(cb + 4 )*96 + slot] = f2bf(w01*z0);
            Ct[(cb + 5 )*96 + slot] = f2bf(w01*z1);
            Ct[(cb + 16)*96 + slot] = f2bf(w10*z0);
            Ct[(cb + 17)*96 + slot] = f2bf(w10*z1);
            Ct[(cb + 20)*96 + slot] = f2bf(w11*z0);
            Ct[(cb + 21)*96 + slot] = f2bf(w11*z1);
        }
    }
    __syncthreads();
    int n = cnt;
    int nch = (n + 31) >> 5;
    int lane = t & 63, w = t >> 6;
    int l15 = lane & 15, quad = lane >> 4;
    int gj = t >> 3, gpart = t & 7;
    for (int f = 0; f < 2; ++f){
        const float* feat = f ? yin : xin;
        f32x4 acc[8] = {};
        for (int ck = 0; ck < nch; ++ck){
            __syncthreads();
            int js = ck*32 + gj;
            if (js < n){
                const float* src = feat + (size_t)nbl[js]*128 + gpart*16;
                #pragma unroll
                for (int u4 = 0; u4 < 16; u4 += 4){
                    float4 v4 = *(const float4*)(src + u4);
                    Ft[(gpart*16 + u4    )*40 + gj] = f2bf(v4.x);
                    Ft[(gpart*16 + u4 + 1)*40 + gj] = f2bf(v4.y);
                    Ft[(gpart*16 + u4 + 2)*40 + gj] = f2bf(v4.z);
                    Ft[(gpart*16 + u4 + 3)*40 + gj] = f2bf(v4.w);
                }
            } else {
                #pragma unroll
                for (int u = 0; u < 16; ++u)
                    Ft[(gpart*16 + u)*40 + gj] = 0;
            }
            __syncthreads();
            bf16x8 af = *(const bf16x8*)(Ct + (size_t)(w*16 + l15)*96 + ck*32 + quad*8);
            #pragma unroll
            for (int nt = 0; nt < 8; ++nt){
                bf16x8 bfr = *(const bf16x8*)(Ft + (size_t)(nt*16 + l15)*40 + quad*8);
                acc[nt] = __builtin_amdgcn_mfma_f32_16x16x32_bf16(af, bfr, acc[nt], 0, 0, 0);
            }
        }
        ushort_t* dst = Abuf + ((size_t)f*chunk + blockIdx.x)*8192;
        #pragma unroll
        for (int nt = 0; nt < 8; ++nt)
            #pragma unroll
            for (int reg = 0; reg < 4; ++reg){
                int cell = w*16 + quad*4 + reg;
                int c    = nt*16 + l15;
                dst[(size_t)cell*128 + c] = f2bf(acc[nt][reg]);
            }
    }
}

// ---------------- cconv stage 2: MFMA GEMM  P = A(bf16) @ Wt^T, split-K ----------------
__global__ __launch_bounds__(256) void mfma_gemm_kernel(
        const ushort_t* __restrict__ Abuf, const ushort_t* __restrict__ Wt,
        float* __restrict__ Pbuf, int chunk){
    __shared__ ushort_t Asm[128*64];
    __shared__ ushort_t Bsm[128*64];
    int tid = threadIdx.x, lane = tid & 63, w = tid >> 6;
    int feat = blockIdx.z >> 3, s = blockIdx.z & 7;
    const ushort_t* Ab = Abuf + (size_t)feat*chunk*8192 + (size_t)blockIdx.x*128*8192;
    const ushort_t* Bb = Wt + (size_t)feat*128*8192;
    int wm = w >> 1, wn = w & 1;
    int lr = lane >> 3, pb = lane & 7, lb = pb ^ lr;
    int quad = lane >> 4, l15 = lane & 15;
    int arow0 = w*32;
    f32x4 acc[4][4] = {};
    const int kk0 = s*(8192/KSPLIT), kk1 = kk0 + 8192/KSPLIT;
    for (int kk = kk0; kk < kk1; kk += 64){
        __syncthreads();
        #pragma unroll
        for (int q = 0; q < 4; ++q){
            int r = arow0 + q*8 + lr;
            load_lds16(Ab + (size_t)r*8192 + kk + lb*8, Asm + (arow0 + q*8)*64);
            load_lds16(Bb + (size_t)r*8192 + kk + lb*8, Bsm + (arow0 + q*8)*64);
        }
        __syncthreads();
        #pragma unroll
        for (int h = 0; h < 2; ++h){
            bf16x8 aF[4], bF[4];
            #pragma unroll
            for (int mt = 0; mt < 4; ++mt){
                int ml = wm*64 + mt*16 + l15;
                int p = (h*4 + quad) ^ (ml & 7);
                aF[mt] = *(const bf16x8*)(Asm + ml*64 + p*8);
            }
            #pragma unroll
            for (int nt = 0; nt < 4; ++nt){
                int nl = wn*64 + nt*16 + l15;
                int p = (h*4 + quad) ^ (nl & 7);
                bF[nt] = *(const bf16x8*)(Bsm + nl*64 + p*8);
            }
            #pragma unroll
            for (int mt = 0; mt < 4; ++mt)
                #pragma unroll
                for (int nt = 0; nt < 4; ++nt)
                    acc[mt][nt] = __builtin_amdgcn_mfma_f32_16x16x32_bf16(
                        aF[mt], bF[nt], acc[mt][nt], 0, 0, 0);
        }
    }
    float* P = Pbuf + (size_t)blockIdx.z*chunk*128 + (size_t)blockIdx.x*128*128;
    #pragma unroll
    for (int mt = 0; mt < 4; ++mt)
        #pragma unroll
        for (int nt = 0; nt < 4; ++nt)
            #pragma unroll
            for (int reg = 0; reg < 4; ++reg){
                int r = wm*64 + mt*16 + quad*4 + reg;
                int c = wn*64 + nt*16 + l15;
                P[(size_t)r*128 + c] = acc[mt][nt][reg];
            }
}

// ---------------- reduceP + fused BN partial stats ----------------
// grid (chunk*128/2048, 2), 256 threads; thread t handles 8 elements, all with ch = t&127.
__global__ void reduceP_kernel(const float* __restrict__ P, float* __restrict__ hconv,
                               float* __restrict__ stats, int chunk, int base){
    __shared__ float ls[256], lq[256];
    int f = blockIdx.y, t = threadIdx.x;
    size_t base_idx = (size_t)blockIdx.x*2048 + t;
    float sum = 0.f, sq = 0.f;
    #pragma unroll
    for (int k = 0; k < 8; ++k){
        size_t idx = base_idx + (size_t)k*256;
        float s = 0.f;
        #pragma unroll
        for (int sp = 0; sp < KSPLIT; ++sp)
            s += P[((size_t)(f*KSPLIT + sp))*chunk*128 + idx];
        hconv[(size_t)f*NF + (size_t)base*128 + idx] = s;
        sum += s; sq += s*s;
    }
    ls[t] = sum; lq[t] = sq;
    __syncthreads();
    if (t < 128){
        atomicAdd(&stats[f*128 + t], ls[t] + ls[t+128]);
        atomicAdd(&stats[256 + f*128 + t], lq[t] + lq[t+128]);
    }
}

// ---------------- generic dense MFMA GEMM: D = A(M x K) @ B(N x K)^T ----------------
template<int MODE>
__global__ __launch_bounds__(256) void dgemm_kernel(
        const ushort_t* __restrict__ A, const ushort_t* __restrict__ Bw,
        const float* __restrict__ bs0, const float* __restrict__ bs1,
        const float* __restrict__ bs2,
        float* __restrict__ oF, ushort_t* __restrict__ oB0,
        ushort_t* __restrict__ oB1, ushort_t* __restrict__ oB2,
        int K, long aZ, long oZ){
    __shared__ ushort_t Asm[128*64];
    __shared__ ushort_t Bsm[128*64];
    int tid = threadIdx.x, lane = tid & 63, w = tid >> 6;
    int z = blockIdx.z;
    int f = (MODE == 2) ? (z/3) : z;
    int wsel = (MODE == 2) ? (z - 3*f) : 0;
    const ushort_t* Ab = A + (size_t)f*aZ + (size_t)blockIdx.x*128*K;
    const ushort_t* Bb = Bw + ((MODE == 2) ? (size_t)wsel*16384 : 0)
                            + (size_t)blockIdx.y*128*K;
    int wm = w >> 1, wn = w & 1;
    int lr = lane >> 3, pb = lane & 7, lb = pb ^ lr;
    int quad = lane >> 4, l15 = lane & 15;
    int arow0 = w*32;
    f32x4 acc[4][4] = {};
    for (int kk = 0; kk < K; kk += 64){
        __syncthreads();
        #pragma unroll
        for (int q = 0; q < 4; ++q){
            int r = arow0 + q*8 + lr;
            load_lds16(Ab + (size_t)r*K + kk + lb*8, Asm + (arow0 + q*8)*64);
            load_lds16(Bb + (size_t)r*K + kk + lb*8, Bsm + (arow0 + q*8)*64);
        }
        __syncthreads();
        #pragma unroll
        for (int h = 0; h < 2; ++h){
            bf16x8 aF[4], bF[4];
            #pragma unroll
            for (int mt = 0; mt < 4; ++mt){
                int ml = wm*64 + mt*16 + l15;
                int p = (h*4 + quad) ^ (ml & 7);
                aF[mt] = *(const bf16x8*)(Asm + ml*64 + p*8);
            }
            #pragma unroll
            for (int nt = 0; nt < 4; ++nt){
                int nl = wn*64 + nt*16 + l15;
                int p = (h*4 + quad) ^ (nl & 7);
                bF[nt] = *(const bf16x8*)(Bsm + nl*64 + p*8);
            }
            #pragma unroll
            for (int mt = 0; mt < 4; ++mt)
                #pragma unroll
                for (int nt = 0; nt < 4; ++nt)
                    acc[mt][nt] = __builtin_amdgcn_mfma_f32_16x16x32_bf16(
                        aF[mt], bF[nt], acc[mt][nt], 0, 0, 0);
        }
    }
    int r0 = blockIdx.x*128, c0 = blockIdx.y*128;
    const float* bias = bs0;
    float osc = 1.f;
    if (MODE == 2){
        bias = (wsel == 0) ? bs0 : (wsel == 1 ? bs1 : bs2);
        // Q scale: log2(e)/sqrt(32)  (softmax runs in exp2 domain)
        if (wsel == 0) osc = 0.25506764057565145f;
    }
    #pragma unroll
    for (int mt = 0; mt < 4; ++mt)
        #pragma unroll
        for (int nt = 0; nt < 4; ++nt)
            #pragma unroll
            for (int reg = 0; reg < 4; ++reg){
                int R = r0 + wm*64 + mt*16 + quad*4 + reg;
                int C = c0 + wn*64 + nt*16 + l15;
                float v = acc[mt][nt][reg];
                if (MODE == 0){
                    oF[(size_t)z*oZ + (size_t)R*128 + C] = v + bias[C];
                } else if (MODE == 1){
                    float r = fmaxf(v + bias[C], 0.f);
                    oB0[(size_t)z*2097152 + (size_t)R*512 + C] = f2bf(r);
                } else {
                    float r = (v + bias[C])*osc;
                    int hh = C >> 5, dd = C & 31;
                    if (wsel < 2){
                        ushort_t* dst = wsel ? oB1 : oB0;
                        dst[((size_t)(f*4+hh)*4096 + R)*32 + dd] = f2bf(r);
                    } else {
                        oB2[((size_t)(f*4+hh)*32 + dd)*4096 + R] = f2bf(r);
                    }
                }
            }
}

// bn apply (stats = raw sum/sumsq) + relu -> xf; h = xf + pe -> hb (bf16)
__global__ void bn_apply_kernel(const float* __restrict__ hconv, const float* __restrict__ stats,
        const float* __restrict__ gx, const float* __restrict__ bxp,
        const float* __restrict__ gy, const float* __restrict__ byp,
        const float* __restrict__ pe,
        float* __restrict__ xf, ushort_t* __restrict__ hb){
    int f = blockIdx.y;
    size_t idx = (size_t)blockIdx.x*256 + threadIdx.x;
    int ch = idx & 127;
    const float* g = f ? gy : gx;
    const float* b = f ? byp : bxp;
    float m  = stats[f*128 + ch] * (1.f/NPTS);
    float var = stats[256 + f*128 + ch] * (1.f/NPTS) - m*m;
    float inv = rsqrtf(var + 1e-5f);
    float vv = hconv[(size_t)f*NF + idx];
    float r = fmaxf((vv - m)*inv*g[ch] + b[ch], 0.f);
    xf[(size_t)f*NF + idx] = r;
    hb[(size_t)f*NF + idx] = f2bf(r + pe[idx]);
}

// ---------------- MFMA flash attention, key-split (exp2 domain) ----------------
// grid (64, 4, 2*NSPLIT); block 256 = 4 waves x 16 queries.
// Vl row 32 = ones -> PV MFMA emits row-sum l for free.
__global__ __launch_bounds__(256) void attn_mfma_kernel(
        const ushort_t* __restrict__ Qb, const ushort_t* __restrict__ Kb,
        const ushort_t* __restrict__ Vt, float* __restrict__ Opart,
        float* __restrict__ ml){
    __shared__ ushort_t Kl[64*40];
    __shared__ ushort_t Vl[48*72];
    __shared__ ushort_t Pl[64*72];
    int tid = threadIdx.x, lane = tid & 63, w = tid >> 6;
    int l15 = lane & 15, quad = lane >> 4;
    int q0 = blockIdx.x*64;
    int head = blockIdx.y;
    int f = blockIdx.z >> 3, ksp = blockIdx.z & (NSPLIT-1);
    const ushort_t* Qh = Qb + ((size_t)(f*4+head)*4096)*32;
    const ushort_t* Kh = Kb + ((size_t)(f*4+head)*4096)*32;
    const ushort_t* Vh = Vt + ((size_t)(f*4+head)*32)*4096;
    int ql = w*16 + l15;
    int qg = q0 + ql;
    bf16x8 qfrag = *(const bf16x8*)(Qh + (size_t)qg*32 + quad*8);
    for (int z = tid; z < 16*72; z += 256)
        Vl[32*72 + z] = (z < 72) ? (ushort_t)0x3F80 : (ushort_t)0;
    f32x4 oacc[3] = {};
    float mprev = -3.0e38f;
    int kr = tid >> 2, kseg = tid & 3;
    int vd = tid >> 3, vseg = tid & 7;
    for (int kt = 0; kt < 4096/NSPLIT/64; ++kt){
        int k0 = ksp*(4096/NSPLIT) + kt*64;
        uint4 tk = *(const uint4*)(Kh + (size_t)(k0+kr)*32 + kseg*8);
        uint4 tv = *(const uint4*)(Vh + (size_t)vd*4096 + k0 + vseg*8);
        __syncthreads();
        *(uint4*)(Kl + kr*40 + kseg*8) = tk;
        *(uint4*)(Vl + vd*72 + vseg*8) = tv;
        __syncthreads();
        f32x4 sc[4] = {};
        #pragma unroll
        for (int mt = 0; mt < 4; ++mt){
            bf16x8 af = *(const bf16x8*)(Kl + (mt*16 + l15)*40 + quad*8);
            sc[mt] = __builtin_amdgcn_mfma_f32_16x16x32_bf16(af, qfrag, sc[mt], 0, 0, 0);
        }
        float mloc = -3.0e38f;
        #pragma unroll
        for (int mt = 0; mt < 4; ++mt)
            #pragma unroll
            for (int r = 0; r < 4; ++r) mloc = fmaxf(mloc, sc[mt][r]);
        mloc = fmaxf(mloc, __shfl_xor(mloc, 16));
        mloc = fmaxf(mloc, __shfl_xor(mloc, 32));
        float mnew = fmaxf(mprev, mloc);
        float alpha = exp2f(mprev - mnew);
        #pragma unroll
        for (int mt = 0; mt < 4; ++mt){
            float p0 = exp2f(sc[mt][0] - mnew);
            float p1 = exp2f(sc[mt][1] - mnew);
            float p2 = exp2f(sc[mt][2] - mnew);
            float p3 = exp2f(sc[mt][3] - mnew);
            uint2 pk;
            pk.x = pack2bf_trunc(p0, p1);
            pk.y = pack2bf_trunc(p2, p3);
            *(uint2*)(Pl + ql*72 + mt*16 + quad*4) = pk;
        }
        mprev = mnew;
        #pragma unroll
        for (int i = 0; i < 3; ++i)
            #pragma unroll
            for (int r = 0; r < 4; ++r) oacc[i][r] *= alpha;
        #pragma unroll
        for (int ks2 = 0; ks2 < 2; ++ks2){
            bf16x8 bfr = *(const bf16x8*)(Pl + ql*72 + ks2*32 + quad*8);
            #pragma unroll
            for (int mtv = 0; mtv < 3; ++mtv){
                bf16x8 af = *(const bf16x8*)(Vl + (mtv*16 + l15)*72 + ks2*32 + quad*8);
                oacc[mtv] = __builtin_amdgcn_mfma_f32_16x16x32_bf16(af, bfr, oacc[mtv], 0, 0, 0);
            }
        }
    }
    float lval = __shfl(oacc[2][0], l15);   // row 32 (ones) output, held by quad 0
    int slot = (f*4 + head)*NSPLIT + ksp;
    float* Op = Opart + (((size_t)slot*4096 + qg)*32);
    #pragma unroll
    for (int mtv = 0; mtv < 2; ++mtv)
        #pragma unroll
        for (int r = 0; r < 4; ++r)
            Op[mtv*16 + quad*4 + r] = oacc[mtv][r];
    if (quad == 0){
        ml[((size_t)slot*4096 + qg)*2 + 0] = mprev;
        ml[((size_t)slot*4096 + qg)*2 + 1] = lval;
    }
}

// ---------------- attention split combine -> Ob (bf16 [f][q][128]) ----------------
__global__ void attn_combine_kernel(const float* __restrict__ Opart,
        const float* __restrict__ ml, ushort_t* __restrict__ Ob){
    int gid = blockIdx.x*256 + threadIdx.x;     // < 2*4*4096*32
    int fh = gid >> 17;
    int rem = gid & 131071;
    int q = rem >> 5, d = rem & 31;
    float mv[NSPLIT], lv[NSPLIT];
    float mstar = -3.0e38f;
    #pragma unroll
    for (int s = 0; s < NSPLIT; ++s){
        size_t o = (((size_t)fh*NSPLIT + s)*4096 + q)*2;
        mv[s] = ml[o];
        lv[s] = ml[o + 1];
        mstar = fmaxf(mstar, mv[s]);
    }
    float lsum = 0.f, osum = 0.f;
    #pragma unroll
    for (int s = 0; s < NSPLIT; ++s){
        float wgt = exp2f(mv[s] - mstar);
        lsum += lv[s]*wgt;
        osum += Opart[(((size_t)fh*NSPLIT + s)*4096 + q)*32 + d]*wgt;
    }
    int f = fh >> 2, head = fh & 3;
    Ob[(size_t)f*NF + (size_t)q*128 + head*32 + d] = f2bf(osum/lsum);
}

// ---------------- LayerNorm(a + b), optional bf16 copy ----------------
__global__ __launch_bounds__(128) void ln_res_kernel(const float* __restrict__ a,
        const float* __restrict__ b, const float* __restrict__ g,
        const float* __restrict__ be, float* __restrict__ out,
        ushort_t* __restrict__ outB){
    __shared__ float red[128];
    int t = threadIdx.x;
    size_t off = (size_t)blockIdx.y*NF + (size_t)blockIdx.x*CH;
    float v = a[off + t] + b[off + t];
    red[t] = v; __syncthreads();
    for (int o = 64; o; o >>= 1){ if (t < o) red[t] += red[t+o]; __syncthreads(); }
    float m = red[0] / 128.f;
    __syncthreads();
    float d = v - m;
    red[t] = d*d; __syncthreads();
    for (int o = 64; o; o >>= 1){ if (t < o) red[t] += red[t+o]; __syncthreads(); }
    float var = red[0] / 128.f;
    float res = (v - m)*rsqrtf(var + 1e-5f)*g[t] + be[t];
    out[off + t] = res;
    if (outB) outB[off + t] = f2bf(res);
}

__global__ void combine_kernel(const float* __restrict__ xfo, const float* __restrict__ yfo,
        const float* __restrict__ x, const float* __restrict__ y, float* __restrict__ out){
    size_t idx = (size_t)blockIdx.x*256 + threadIdx.x;
    float s = xfo[idx] + yfo[idx];
    float w = 1.f/(1.f + __expf(-s));
    out[idx] = 2.f*x[idx]*w + 2.f*y[idx]*(1.f - w);
}

extern "C" void kernel_launch(void* const* d_in, const int* in_sizes, int n_in,
                              void* d_out, int out_size, void* d_ws, size_t ws_size,
                              hipStream_t stream){
    (void)in_sizes; (void)n_in; (void)out_size;
    const float* x    = (const float*)d_in[0];
    const float* y    = (const float*)d_in[1];
    const float* pos  = (const float*)d_in[2];
    const int*   nbr  = (const int*)  d_in[3];
    const float* Wx   = (const float*)d_in[5];
    const float* bnxg = (const float*)d_in[7];
    const float* bnxb = (const float*)d_in[8];
    const float* Wy   = (const float*)d_in[9];
    const float* bnyg = (const float*)d_in[11];
    const float* bnyb = (const float*)d_in[12];
    const float* Wq   = (const float*)d_in[13];
    const float* bq   = (const float*)d_in[14];
    const float* Wk   = (const float*)d_in[15];
    const float* bk   = (const float*)d_in[16];
    const float* Wv   = (const float*)d_in[17];
    const float* bv   = (const float*)d_in[18];
    const float* Wo   = (const float*)d_in[19];
    const float* bo   = (const float*)d_in[20];
    const float* ln1g = (const float*)d_in[21];
    const float* ln1b = (const float*)d_in[22];
    const float* W1   = (const float*)d_in[23];
    const float* b1   = (const float*)d_in[24];
    const float* W2   = (const float*)d_in[25];
    const float* b2   = (const float*)d_in[26];
    const float* ln2g = (const float*)d_in[27];
    const float* ln2b = (const float*)d_in[28];

    float* ws     = (float*)d_ws;
    float* pe     = ws;                       // NF
    float* hconv  = pe + NF;                  // 2NF
    float* xf     = hconv + (size_t)2*NF;     // 2NF
    float* o2     = xf + (size_t)2*NF;        // 2NF
    float* feat1  = o2 + (size_t)2*NF;        // 2NF
    float* ff2    = feat1 + (size_t)2*NF;     // 2NF
    float* stats  = ff2 + (size_t)2*NF;       // 2048
    float* Opart  = stats + 2048;             // 2*4*NSPLIT*4096*32 = 8388608
    float* mlbuf  = Opart + (size_t)2*4*NSPLIT*4096*32;   // 2*4*NSPLIT*4096*2
    float* Pbuf   = mlbuf + (size_t)2*4*NSPLIT*4096*2;    // 2048*chunk
    float* xfo    = xf;

    const size_t fixedFloats = (size_t)11*NF + 2048
                             + (size_t)2*4*NSPLIT*4096*32 + (size_t)2*4*NSPLIT*4096*2;
    const size_t fixedUsh = (size_t)2097152 + 196608 + 6*1048576 + 4194304;
    int chunk = 128;
    const int cand[6] = {4096, 2048, 1024, 512, 256, 128};
    for (int ci = 0; ci < 6; ++ci){
        size_t need = (fixedFloats + (size_t)2048*cand[ci])*4
                    + (fixedUsh + (size_t)2*cand[ci]*8192)*2;
        if (need <= ws_size){ chunk = cand[ci]; break; }
    }
    ushort_t* Wt     = (ushort_t*)(Pbuf + (size_t)2048*chunk);
    ushort_t* wbuf   = Wt + 2097152;
    ushort_t* hb     = wbuf + 196608;
    ushort_t* Qb     = hb + 1048576;
    ushort_t* Kb     = Qb + 1048576;
    ushort_t* Vtb    = Kb + 1048576;
    ushort_t* Ob     = Vtb + 1048576;
    ushort_t* feat1b = Ob + 1048576;
    ushort_t* ff1b   = feat1b + 1048576;
    ushort_t* Abuf   = ff1b + 4194304;

    pos_stats_kernel<<<1, 256, 0, stream>>>(pos, stats);
    pe_kernel<<<NPTS*64/256, 256, 0, stream>>>(pos, stats, pe);
    wt_kernel<<<dim3(256, 4, 2), 256, 0, stream>>>(Wx, Wy, Wt);
    wcast_kernel<<<768, 256, 0, stream>>>(Wq, Wk, Wv, Wo, W1, W2, wbuf);

    for (int base = 0; base < NPTS; base += chunk){
        cf_kernel<<<chunk, 256, 0, stream>>>(x, y, pos, nbr, Abuf, base, chunk);
        mfma_gemm_kernel<<<dim3(chunk/128, 1, 2*KSPLIT), 256, 0, stream>>>(Abuf, Wt, Pbuf, chunk);
        reduceP_kernel<<<dim3(chunk*128/2048, 2), 256, 0, stream>>>(Pbuf, hconv, stats, chunk, base);
    }

    bn_apply_kernel<<<dim3(NF/256, 2), 256, 0, stream>>>(hconv, stats, bnxg, bnxb, bnyg, bnyb,
                                                         pe, xf, hb);

    dgemm_kernel<2><<<dim3(32, 1, 6), 256, 0, stream>>>(hb, wbuf, bq, bk, bv,
        nullptr, Qb, Kb, Vtb, 128, (long)NF, 0);

    attn_mfma_kernel<<<dim3(64, 4, 2*NSPLIT), 256, 0, stream>>>(Qb, Kb, Vtb, Opart, mlbuf);
    attn_combine_kernel<<<4096, 256, 0, stream>>>(Opart, mlbuf, Ob);

    dgemm_kernel<0><<<dim3(32, 1, 2), 256, 0, stream>>>(Ob, wbuf + 49152, bo, nullptr, nullptr,
        o2, nullptr, nullptr, nullptr, 128, (long)NF, (long)NF);
    ln_res_kernel<<<dim3(NPTS, 2), 128, 0, stream>>>(xf, o2, ln1g, ln1b, feat1, feat1b);

    dgemm_kernel<1><<<dim3(32, 4, 2), 256, 0, stream>>>(feat1b, wbuf + 65536, b1, nullptr, nullptr,
        nullptr, ff1b, nullptr, nullptr, 128, (long)NF, 0);
    dgemm_kernel<0><<<dim3(32, 1, 2), 256, 0, stream>>>(ff1b, wbuf + 131072, b2, nullptr, nullptr,
        ff2, nullptr, nullptr, nullptr, 512, (long)2097152, (long)NF);
    ln_res_kernel<<<dim3(NPTS, 2), 128, 0, stream>>>(feat1, ff2, ln2g, ln2b, xfo, nullptr);

    combine_kernel<<<NF/256, 256, 0, stream>>>(xfo, xfo + NF, x, y, (float*)d_out);
}

// Round 7
// 315.353 us; speedup vs baseline: 7.9510x; 1.0352x over previous
//
#include <hip/hip_runtime.h>
#include <cstddef>

#define NPTS 4096
#define KNBR 80
#define CH   128
#define NF   (NPTS*CH)      // 524288
#define FFD  512
#define KSPLIT 8
#define NSPLIT 8            // attention key-split

typedef unsigned short ushort_t;
typedef short bf16x8 __attribute__((ext_vector_type(8)));
typedef float f32x4 __attribute__((ext_vector_type(4)));

__device__ __forceinline__ unsigned short f2bf(float f){
    unsigned int u = __float_as_uint(f);
    unsigned int r = (u + 0x7FFFu + ((u >> 16) & 1u)) >> 16;
    return (unsigned short)r;
}

// pack two fp32 -> bf16 pair by truncation: low = hi16(a), high = hi16(b)
__device__ __forceinline__ unsigned pack2bf_trunc(float a, float b){
    return __builtin_amdgcn_perm(__float_as_uint(b), __float_as_uint(a), 0x07060302u);
}

__device__ __forceinline__ void load_lds16(const ushort_t* g, ushort_t* l){
    __builtin_amdgcn_global_load_lds(
        (const __attribute__((address_space(1))) unsigned int*)g,
        (__attribute__((address_space(3))) unsigned int*)l, 16, 0, 0);
}

// ---------------- pos stats (+ zero BN accumulators) ----------------
__global__ void pos_stats_kernel(const float* __restrict__ pos, float* __restrict__ stats){
    __shared__ float red[256];
    int t = threadIdx.x;
    stats[t] = 0.f;            // BN sum accumulators [0..255]
    stats[256 + t] = 0.f;      // BN sumsq accumulators [256..511]
    float s = 0.f;
    for (int i = t; i < NPTS; i += 256) s += pos[(size_t)i*3];
    red[t] = s; __syncthreads();
    for (int o = 128; o; o >>= 1){ if (t < o) red[t] += red[t+o]; __syncthreads(); }
    float mean = red[0] / (float)NPTS;
    __syncthreads();
    float ss = 0.f;
    for (int i = t; i < NPTS; i += 256){ float d = pos[(size_t)i*3] - mean; ss += d*d; }
    red[t] = ss; __syncthreads();
    for (int o = 128; o; o >>= 1){ if (t < o) red[t] += red[t+o]; __syncthreads(); }
    if (t == 0){
        float sd = sqrtf(red[0] / (float)(NPTS-1));
        stats[512] = mean;
        stats[513] = 1.f/(sd + 1e-8f);
    }
}

// ---------------- positional encoding ----------------
__global__ void pe_kernel(const float* __restrict__ pos, const float* __restrict__ stats,
                          float* __restrict__ pe){
    int t = blockIdx.x*256 + threadIdx.x;
    int i = t >> 6, m = t & 63;
    float px = (pos[(size_t)i*3] - stats[512]) * stats[513];
    float dv = expf((float)(2*m) * -0.07195578415606394f);
    float ang = px * dv;
    float sv, cv;
    sincosf(ang, &sv, &cv);
    pe[(size_t)i*CH + 2*m]     = sv;
    pe[(size_t)i*CH + 2*m + 1] = cv;
}

// ---------------- conv W transpose+cast: Wt[f][n][k] = W_f[k][n] (bf16) ----------------
__global__ __launch_bounds__(256) void wt_kernel(const float* __restrict__ Wx,
        const float* __restrict__ Wy, ushort_t* __restrict__ Wt){
    __shared__ float tile[32][33];
    const float* W = blockIdx.z ? Wy : Wx;
    int kb = blockIdx.x, nb = blockIdx.y;
    int tr = threadIdx.x & 31, tc = threadIdx.x >> 5;
    #pragma unroll
    for (int rr = 0; rr < 32; rr += 8)
        tile[tc+rr][tr] = W[(size_t)(kb*32 + tc + rr)*128 + nb*32 + tr];
    __syncthreads();
    size_t fo = (size_t)blockIdx.z * 8192 * 128;
    #pragma unroll
    for (int rr = 0; rr < 32; rr += 8)
        Wt[fo + (size_t)(nb*32 + tc + rr)*8192 + kb*32 + tr] = f2bf(tile[tr][tc+rr]);
}

// ---------------- dense-weight cast (Wq|Wk|Wv|Wo|W1|W2 -> bf16 packed) ----------------
__global__ void wcast_kernel(const float* __restrict__ Wq, const float* __restrict__ Wk,
        const float* __restrict__ Wv, const float* __restrict__ Wo,
        const float* __restrict__ W1, const float* __restrict__ W2,
        ushort_t* __restrict__ dst){
    int i = blockIdx.x*256 + threadIdx.x;     // < 196608
    const float* src; int off;
    if      (i < 16384)  { src = Wq; off = i; }
    else if (i < 32768)  { src = Wk; off = i - 16384; }
    else if (i < 49152)  { src = Wv; off = i - 32768; }
    else if (i < 65536)  { src = Wo; off = i - 49152; }
    else if (i < 131072) { src = W1; off = i - 65536; }
    else                 { src = W2; off = i - 131072; }
    dst[i] = f2bf(src[off]);
}

// ---------------- cconv stage 1 (MFMA): A = Ct(64 x n) @ F(n x 128) -> bf16 ----------------
__global__ __launch_bounds__(256) void cf_kernel(
        const float* __restrict__ xin, const float* __restrict__ yin,
        const float* __restrict__ pos, const int* __restrict__ nbr,
        ushort_t* __restrict__ Abuf, int base, int chunk){
    __shared__ ushort_t Ct[64*96];
    __shared__ ushort_t Ft[128*40];
    __shared__ int nbl[KNBR];
    __shared__ int cnt;
    int i = base + blockIdx.x;
    int t = threadIdx.x;
    for (int z = t; z < 64*96/8; z += 256) ((uint4*)Ct)[z] = uint4{0,0,0,0};
    if (t == 0) cnt = 0;
    __syncthreads();
    if (t < KNBR){
        int nb = nbr[(size_t)i*KNBR + t];
        if (nb != i){
            float p0 = pos[(size_t)i*3], p1 = pos[(size_t)i*3+1], p2 = pos[(size_t)i*3+2];
            const float RAD = 0.1125f;
            float rx = (pos[(size_t)nb*3+0]-p0)/RAD;
            float ry = (pos[(size_t)nb*3+1]-p1)/RAD;
            float rz = (pos[(size_t)nb*3+2]-p2)/RAD;
            float r2 = rx*rx + ry*ry + rz*rz;
            float w1 = 1.f - r2;
            float win = fminf(fmaxf(w1*w1*w1, 0.f), 1.f);
            float nrm = sqrtf(fmaxf(r2, 1e-12f));
            float linf = fmaxf(fmaxf(fabsf(rx), fabsf(ry)), fabsf(rz));
            linf = fmaxf(linf, 1e-9f);
            float sc = nrm/linf;
            float gx = fminf(fmaxf((rx*sc+1.f)*0.5f*3.f, 0.f), 3.f);
            float gy = fminf(fmaxf((ry*sc+1.f)*0.5f*3.f, 0.f), 3.f);
            float gz = fminf(fmaxf((rz*sc+1.f)*0.5f*3.f, 0.f), 3.f);
            float fx = fminf(floorf(gx), 2.f), fy = fminf(floorf(gy), 2.f), fz = fminf(floorf(gz), 2.f);
            float tx = gx-fx, ty = gy-fy, tz = gz-fz;
            int ix = (int)fx, iy = (int)fy, iz = (int)fz;
            int cb = (ix<<4) + (iy<<2) + iz;
            float x0 = (1.f-tx)*win, x1 = tx*win;
            float w00 = x0*(1.f-ty), w01 = x0*ty, w10 = x1*(1.f-ty), w11 = x1*ty;
            float z0 = 1.f-tz, z1 = tz;
            int slot = atomicAdd(&cnt, 1);
            nbl[slot] = nb;
            Ct[(cb     )*96 + slot] = f2bf(w00*z0);
            Ct[(cb + 1 )*96 + slot] = f2bf(w00*z1);
            Ct[(cb + 4 )*96 + slot] = f2bf(w01*z0);
            Ct[(cb + 5 )*96 + slot] = f2bf(w01*z1);
            Ct[(cb + 16)*96 + slot] = f2bf(w10*z0);
            Ct[(cb + 17)*96 + slot] = f2bf(w10*z1);
            Ct[(cb + 20)*96 + slot] = f2bf(w11*z0);
            Ct[(cb + 21)*96 + slot] = f2bf(w11*z1);
        }
    }
    __syncthreads();
    int n = cnt;
    int nch = (n + 31) >> 5;
    int lane = t & 63, w = t >> 6;
    int l15 = lane & 15, quad = lane >> 4;
    int gj = t >> 3, gpart = t & 7;
    for (int f = 0; f < 2; ++f){
        const float* feat = f ? yin : xin;
        f32x4 acc[8] = {};
        for (int ck = 0; ck < nch; ++ck){
            __syncthreads();
            int js = ck*32 + gj;
            if (js < n){
                const float* src = feat + (size_t)nbl[js]*128 + gpart*16;
                #pragma unroll
                for (int u4 = 0; u4 < 16; u4 += 4){
                    float4 v4 = *(const float4*)(src + u4);
                    Ft[(gpart*16 + u4    )*40 + gj] = f2bf(v4.x);
                    Ft[(gpart*16 + u4 + 1)*40 + gj] = f2bf(v4.y);
                    Ft[(gpart*16 + u4 + 2)*40 + gj] = f2bf(v4.z);
                    Ft[(gpart*16 + u4 + 3)*40 + gj] = f2bf(v4.w);
                }
            } else {
                #pragma unroll
                for (int u = 0; u < 16; ++u)
                    Ft[(gpart*16 + u)*40 + gj] = 0;
            }
            __syncthreads();
            bf16x8 af = *(const bf16x8*)(Ct + (size_t)(w*16 + l15)*96 + ck*32 + quad*8);
            #pragma unroll
            for (int nt = 0; nt < 8; ++nt){
                bf16x8 bfr = *(const bf16x8*)(Ft + (size_t)(nt*16 + l15)*40 + quad*8);
                acc[nt] = __builtin_amdgcn_mfma_f32_16x16x32_bf16(af, bfr, acc[nt], 0, 0, 0);
            }
        }
        ushort_t* dst = Abuf + ((size_t)f*chunk + blockIdx.x)*8192;
        #pragma unroll
        for (int nt = 0; nt < 8; ++nt)
            #pragma unroll
            for (int reg = 0; reg < 4; ++reg){
                int cell = w*16 + quad*4 + reg;
                int c    = nt*16 + l15;
                dst[(size_t)cell*128 + c] = f2bf(acc[nt][reg]);
            }
    }
}

// ---------------- cconv stage 2: MFMA GEMM  P = A(bf16) @ Wt^T, split-K ----------------
__global__ __launch_bounds__(256) void mfma_gemm_kernel(
        const ushort_t* __restrict__ Abuf, const ushort_t* __restrict__ Wt,
        float* __restrict__ Pbuf, int chunk){
    __shared__ ushort_t Asm[128*64];
    __shared__ ushort_t Bsm[128*64];
    int tid = threadIdx.x, lane = tid & 63, w = tid >> 6;
    int feat = blockIdx.z >> 3, s = blockIdx.z & 7;
    const ushort_t* Ab = Abuf + (size_t)feat*chunk*8192 + (size_t)blockIdx.x*128*8192;
    const ushort_t* Bb = Wt + (size_t)feat*128*8192;
    int wm = w >> 1, wn = w & 1;
    int lr = lane >> 3, pb = lane & 7, lb = pb ^ lr;
    int quad = lane >> 4, l15 = lane & 15;
    int arow0 = w*32;
    f32x4 acc[4][4] = {};
    const int kk0 = s*(8192/KSPLIT), kk1 = kk0 + 8192/KSPLIT;
    for (int kk = kk0; kk < kk1; kk += 64){
        __syncthreads();
        #pragma unroll
        for (int q = 0; q < 4; ++q){
            int r = arow0 + q*8 + lr;
            load_lds16(Ab + (size_t)r*8192 + kk + lb*8, Asm + (arow0 + q*8)*64);
            load_lds16(Bb + (size_t)r*8192 + kk + lb*8, Bsm + (arow0 + q*8)*64);
        }
        __syncthreads();
        #pragma unroll
        for (int h = 0; h < 2; ++h){
            bf16x8 aF[4], bF[4];
            #pragma unroll
            for (int mt = 0; mt < 4; ++mt){
                int ml = wm*64 + mt*16 + l15;
                int p = (h*4 + quad) ^ (ml & 7);
                aF[mt] = *(const bf16x8*)(Asm + ml*64 + p*8);
            }
            #pragma unroll
            for (int nt = 0; nt < 4; ++nt){
                int nl = wn*64 + nt*16 + l15;
                int p = (h*4 + quad) ^ (nl & 7);
                bF[nt] = *(const bf16x8*)(Bsm + nl*64 + p*8);
            }
            #pragma unroll
            for (int mt = 0; mt < 4; ++mt)
                #pragma unroll
                for (int nt = 0; nt < 4; ++nt)
                    acc[mt][nt] = __builtin_amdgcn_mfma_f32_16x16x32_bf16(
                        aF[mt], bF[nt], acc[mt][nt], 0, 0, 0);
        }
    }
    float* P = Pbuf + (size_t)blockIdx.z*chunk*128 + (size_t)blockIdx.x*128*128;
    #pragma unroll
    for (int mt = 0; mt < 4; ++mt)
        #pragma unroll
        for (int nt = 0; nt < 4; ++nt)
            #pragma unroll
            for (int reg = 0; reg < 4; ++reg){
                int r = wm*64 + mt*16 + quad*4 + reg;
                int c = wn*64 + nt*16 + l15;
                P[(size_t)r*128 + c] = acc[mt][nt][reg];
            }
}

// ---------------- reduceP + fused BN partial stats ----------------
__global__ void reduceP_kernel(const float* __restrict__ P, float* __restrict__ hconv,
                               float* __restrict__ stats, int chunk, int base){
    __shared__ float ls[256], lq[256];
    int f = blockIdx.y, t = threadIdx.x;
    size_t base_idx = (size_t)blockIdx.x*2048 + t;
    float sum = 0.f, sq = 0.f;
    #pragma unroll
    for (int k = 0; k < 8; ++k){
        size_t idx = base_idx + (size_t)k*256;
        float s = 0.f;
        #pragma unroll
        for (int sp = 0; sp < KSPLIT; ++sp)
            s += P[((size_t)(f*KSPLIT + sp))*chunk*128 + idx];
        hconv[(size_t)f*NF + (size_t)base*128 + idx] = s;
        sum += s; sq += s*s;
    }
    ls[t] = sum; lq[t] = sq;
    __syncthreads();
    if (t < 128){
        atomicAdd(&stats[f*128 + t], ls[t] + ls[t+128]);
        atomicAdd(&stats[256 + f*128 + t], lq[t] + lq[t+128]);
    }
}

// ---------------- generic dense MFMA GEMM: D = A(M x K) @ B(N x K)^T ----------------
template<int MODE>
__global__ __launch_bounds__(256) void dgemm_kernel(
        const ushort_t* __restrict__ A, const ushort_t* __restrict__ Bw,
        const float* __restrict__ bs0, const float* __restrict__ bs1,
        const float* __restrict__ bs2,
        float* __restrict__ oF, ushort_t* __restrict__ oB0,
        ushort_t* __restrict__ oB1, ushort_t* __restrict__ oB2,
        int K, long aZ, long oZ){
    __shared__ ushort_t Asm[128*64];
    __shared__ ushort_t Bsm[128*64];
    int tid = threadIdx.x, lane = tid & 63, w = tid >> 6;
    int z = blockIdx.z;
    int f = (MODE == 2) ? (z/3) : z;
    int wsel = (MODE == 2) ? (z - 3*f) : 0;
    const ushort_t* Ab = A + (size_t)f*aZ + (size_t)blockIdx.x*128*K;
    const ushort_t* Bb = Bw + ((MODE == 2) ? (size_t)wsel*16384 : 0)
                            + (size_t)blockIdx.y*128*K;
    int wm = w >> 1, wn = w & 1;
    int lr = lane >> 3, pb = lane & 7, lb = pb ^ lr;
    int quad = lane >> 4, l15 = lane & 15;
    int arow0 = w*32;
    f32x4 acc[4][4] = {};
    for (int kk = 0; kk < K; kk += 64){
        __syncthreads();
        #pragma unroll
        for (int q = 0; q < 4; ++q){
            int r = arow0 + q*8 + lr;
            load_lds16(Ab + (size_t)r*K + kk + lb*8, Asm + (arow0 + q*8)*64);
            load_lds16(Bb + (size_t)r*K + kk + lb*8, Bsm + (arow0 + q*8)*64);
        }
        __syncthreads();
        #pragma unroll
        for (int h = 0; h < 2; ++h){
            bf16x8 aF[4], bF[4];
            #pragma unroll
            for (int mt = 0; mt < 4; ++mt){
                int ml = wm*64 + mt*16 + l15;
                int p = (h*4 + quad) ^ (ml & 7);
                aF[mt] = *(const bf16x8*)(Asm + ml*64 + p*8);
            }
            #pragma unroll
            for (int nt = 0; nt < 4; ++nt){
                int nl = wn*64 + nt*16 + l15;
                int p = (h*4 + quad) ^ (nl & 7);
                bF[nt] = *(const bf16x8*)(Bsm + nl*64 + p*8);
            }
            #pragma unroll
            for (int mt = 0; mt < 4; ++mt)
                #pragma unroll
                for (int nt = 0; nt < 4; ++nt)
                    acc[mt][nt] = __builtin_amdgcn_mfma_f32_16x16x32_bf16(
                        aF[mt], bF[nt], acc[mt][nt], 0, 0, 0);
        }
    }
    int r0 = blockIdx.x*128, c0 = blockIdx.y*128;
    const float* bias = bs0;
    float osc = 1.f;
    if (MODE == 2){
        bias = (wsel == 0) ? bs0 : (wsel == 1 ? bs1 : bs2);
        // Q scale: log2(e)/sqrt(32)  (softmax runs in exp2 domain)
        if (wsel == 0) osc = 0.25506764057565145f;
    }
    #pragma unroll
    for (int mt = 0; mt < 4; ++mt)
        #pragma unroll
        for (int nt = 0; nt < 4; ++nt)
            #pragma unroll
            for (int reg = 0; reg < 4; ++reg){
                int R = r0 + wm*64 + mt*16 + quad*4 + reg;
                int C = c0 + wn*64 + nt*16 + l15;
                float v = acc[mt][nt][reg];
                if (MODE == 0){
                    oF[(size_t)z*oZ + (size_t)R*128 + C] = v + bias[C];
                } else if (MODE == 1){
                    float r = fmaxf(v + bias[C], 0.f);
                    oB0[(size_t)z*2097152 + (size_t)R*512 + C] = f2bf(r);
                } else {
                    float r = (v + bias[C])*osc;
                    int hh = C >> 5, dd = C & 31;
                    if (wsel < 2){
                        ushort_t* dst = wsel ? oB1 : oB0;
                        dst[((size_t)(f*4+hh)*4096 + R)*32 + dd] = f2bf(r);
                    } else {
                        oB2[((size_t)(f*4+hh)*32 + dd)*4096 + R] = f2bf(r);
                    }
                }
            }
}

// bn apply (stats = raw sum/sumsq) + relu -> xf; h = xf + pe -> hb (bf16)
__global__ void bn_apply_kernel(const float* __restrict__ hconv, const float* __restrict__ stats,
        const float* __restrict__ gx, const float* __restrict__ bxp,
        const float* __restrict__ gy, const float* __restrict__ byp,
        const float* __restrict__ pe,
        float* __restrict__ xf, ushort_t* __restrict__ hb){
    int f = blockIdx.y;
    size_t idx = (size_t)blockIdx.x*256 + threadIdx.x;
    int ch = idx & 127;
    const float* g = f ? gy : gx;
    const float* b = f ? byp : bxp;
    float m  = stats[f*128 + ch] * (1.f/NPTS);
    float var = stats[256 + f*128 + ch] * (1.f/NPTS) - m*m;
    float inv = rsqrtf(var + 1e-5f);
    float vv = hconv[(size_t)f*NF + idx];
    float r = fmaxf((vv - m)*inv*g[ch] + b[ch], 0.f);
    xf[(size_t)f*NF + idx] = r;
    hb[(size_t)f*NF + idx] = f2bf(r + pe[idx]);
}

// ---------------- MFMA flash attention, key-split, NO max-subtraction ----------------
// Softmax is shift-invariant; scores in exp2 domain are O(+-10) (std ~1.4), and
// fp32/bf16 exponent range (2^+-126) makes exp2(s) overflow-free with ~2^110 margin.
// Vl row 32 = ones -> PV MFMA emits row-sum l for free.
__global__ __launch_bounds__(256) void attn_mfma_kernel(
        const ushort_t* __restrict__ Qb, const ushort_t* __restrict__ Kb,
        const ushort_t* __restrict__ Vt, float* __restrict__ Opart,
        float* __restrict__ ml){
    __shared__ ushort_t Kl[64*40];
    __shared__ ushort_t Vl[48*72];
    __shared__ ushort_t Pl[64*72];
    int tid = threadIdx.x, lane = tid & 63, w = tid >> 6;
    int l15 = lane & 15, quad = lane >> 4;
    int q0 = blockIdx.x*64;
    int head = blockIdx.y;
    int f = blockIdx.z >> 3, ksp = blockIdx.z & (NSPLIT-1);
    const ushort_t* Qh = Qb + ((size_t)(f*4+head)*4096)*32;
    const ushort_t* Kh = Kb + ((size_t)(f*4+head)*4096)*32;
    const ushort_t* Vh = Vt + ((size_t)(f*4+head)*32)*4096;
    int ql = w*16 + l15;
    int qg = q0 + ql;
    bf16x8 qfrag = *(const bf16x8*)(Qh + (size_t)qg*32 + quad*8);
    for (int z = tid; z < 16*72; z += 256)
        Vl[32*72 + z] = (z < 72) ? (ushort_t)0x3F80 : (ushort_t)0;
    f32x4 oacc[3] = {};
    int kr = tid >> 2, kseg = tid & 3;
    int vd = tid >> 3, vseg = tid & 7;
    for (int kt = 0; kt < 4096/NSPLIT/64; ++kt){
        int k0 = ksp*(4096/NSPLIT) + kt*64;
        uint4 tk = *(const uint4*)(Kh + (size_t)(k0+kr)*32 + kseg*8);
        uint4 tv = *(const uint4*)(Vh + (size_t)vd*4096 + k0 + vseg*8);
        __syncthreads();
        *(uint4*)(Kl + kr*40 + kseg*8) = tk;
        *(uint4*)(Vl + vd*72 + vseg*8) = tv;
        __syncthreads();
        f32x4 sc[4] = {};
        #pragma unroll
        for (int mt = 0; mt < 4; ++mt){
            bf16x8 af = *(const bf16x8*)(Kl + (mt*16 + l15)*40 + quad*8);
            sc[mt] = __builtin_amdgcn_mfma_f32_16x16x32_bf16(af, qfrag, sc[mt], 0, 0, 0);
        }
        #pragma unroll
        for (int mt = 0; mt < 4; ++mt){
            float p0 = exp2f(sc[mt][0]);
            float p1 = exp2f(sc[mt][1]);
            float p2 = exp2f(sc[mt][2]);
            float p3 = exp2f(sc[mt][3]);
            uint2 pk;
            pk.x = pack2bf_trunc(p0, p1);
            pk.y = pack2bf_trunc(p2, p3);
            *(uint2*)(Pl + ql*72 + mt*16 + quad*4) = pk;
        }
        #pragma unroll
        for (int ks2 = 0; ks2 < 2; ++ks2){
            bf16x8 bfr = *(const bf16x8*)(Pl + ql*72 + ks2*32 + quad*8);
            #pragma unroll
            for (int mtv = 0; mtv < 3; ++mtv){
                bf16x8 af = *(const bf16x8*)(Vl + (mtv*16 + l15)*72 + ks2*32 + quad*8);
                oacc[mtv] = __builtin_amdgcn_mfma_f32_16x16x32_bf16(af, bfr, oacc[mtv], 0, 0, 0);
            }
        }
    }
    float lval = __shfl(oacc[2][0], l15);   // row 32 (ones) output, held by quad 0
    int slot = (f*4 + head)*NSPLIT + ksp;
    float* Op = Opart + (((size_t)slot*4096 + qg)*32);
    #pragma unroll
    for (int mtv = 0; mtv < 2; ++mtv)
        #pragma unroll
        for (int r = 0; r < 4; ++r)
            Op[mtv*16 + quad*4 + r] = oacc[mtv][r];
    if (lane < 16)
        ml[(size_t)slot*4096 + qg] = lval;
}

// ---------------- attention split combine (plain sums) -> Ob (bf16 [f][q][128]) ----------------
__global__ void attn_combine_kernel(const float* __restrict__ Opart,
        const float* __restrict__ ml, ushort_t* __restrict__ Ob){
    int gid = blockIdx.x*256 + threadIdx.x;     // < 2*4*4096*32
    int fh = gid >> 17;
    int rem = gid & 131071;
    int q = rem >> 5, d = rem & 31;
    float lsum = 0.f, osum = 0.f;
    #pragma unroll
    for (int s = 0; s < NSPLIT; ++s){
        lsum += ml[((size_t)fh*NSPLIT + s)*4096 + q];
        osum += Opart[(((size_t)fh*NSPLIT + s)*4096 + q)*32 + d];
    }
    int f = fh >> 2, head = fh & 3;
    Ob[(size_t)f*NF + (size_t)q*128 + head*32 + d] = f2bf(osum/lsum);
}

// ---------------- LayerNorm(a + b), optional bf16 copy ----------------
__global__ __launch_bounds__(128) void ln_res_kernel(const float* __restrict__ a,
        const float* __restrict__ b, const float* __restrict__ g,
        const float* __restrict__ be, float* __restrict__ out,
        ushort_t* __restrict__ outB){
    __shared__ float red[128];
    int t = threadIdx.x;
    size_t off = (size_t)blockIdx.y*NF + (size_t)blockIdx.x*CH;
    float v = a[off + t] + b[off + t];
    red[t] = v; __syncthreads();
    for (int o = 64; o; o >>= 1){ if (t < o) red[t] += red[t+o]; __syncthreads(); }
    float m = red[0] / 128.f;
    __syncthreads();
    float d = v - m;
    red[t] = d*d; __syncthreads();
    for (int o = 64; o; o >>= 1){ if (t < o) red[t] += red[t+o]; __syncthreads(); }
    float var = red[0] / 128.f;
    float res = (v - m)*rsqrtf(var + 1e-5f)*g[t] + be[t];
    out[off + t] = res;
    if (outB) outB[off + t] = f2bf(res);
}

// ---------------- fused final: LN2 (both feats) + sigmoid gate ----------------
// grid NPTS, block 128. Does ln(feat1+ff2) for f=0,1, then the output gate.
__global__ __launch_bounds__(128) void ln2_combine_kernel(
        const float* __restrict__ a, const float* __restrict__ b,
        const float* __restrict__ g, const float* __restrict__ be,
        const float* __restrict__ x, const float* __restrict__ y,
        float* __restrict__ out){
    __shared__ float red0[128], red1[128];
    int t = threadIdx.x;
    size_t off = (size_t)blockIdx.x*CH;
    float v0 = a[off + t] + b[off + t];
    float v1 = a[NF + off + t] + b[NF + off + t];
    red0[t] = v0; red1[t] = v1; __syncthreads();
    for (int o = 64; o; o >>= 1){
        if (t < o){ red0[t] += red0[t+o]; red1[t] += red1[t+o]; }
        __syncthreads();
    }
    float m0 = red0[0] / 128.f, m1 = red1[0] / 128.f;
    __syncthreads();
    float d0 = v0 - m0, d1 = v1 - m1;
    red0[t] = d0*d0; red1[t] = d1*d1; __syncthreads();
    for (int o = 64; o; o >>= 1){
        if (t < o){ red0[t] += red0[t+o]; red1[t] += red1[t+o]; }
        __syncthreads();
    }
    float r0 = d0*rsqrtf(red0[0]/128.f + 1e-5f)*g[t] + be[t];
    float r1 = d1*rsqrtf(red1[0]/128.f + 1e-5f)*g[t] + be[t];
    float wgt = 1.f/(1.f + __expf(-(r0 + r1)));
    out[off + t] = 2.f*x[off + t]*wgt + 2.f*y[off + t]*(1.f - wgt);
}

extern "C" void kernel_launch(void* const* d_in, const int* in_sizes, int n_in,
                              void* d_out, int out_size, void* d_ws, size_t ws_size,
                              hipStream_t stream){
    (void)in_sizes; (void)n_in; (void)out_size;
    const float* x    = (const float*)d_in[0];
    const float* y    = (const float*)d_in[1];
    const float* pos  = (const float*)d_in[2];
    const int*   nbr  = (const int*)  d_in[3];
    const float* Wx   = (const float*)d_in[5];
    const float* bnxg = (const float*)d_in[7];
    const float* bnxb = (const float*)d_in[8];
    const float* Wy   = (const float*)d_in[9];
    const float* bnyg = (const float*)d_in[11];
    const float* bnyb = (const float*)d_in[12];
    const float* Wq   = (const float*)d_in[13];
    const float* bq   = (const float*)d_in[14];
    const float* Wk   = (const float*)d_in[15];
    const float* bk   = (const float*)d_in[16];
    const float* Wv   = (const float*)d_in[17];
    const float* bv   = (const float*)d_in[18];
    const float* Wo   = (const float*)d_in[19];
    const float* bo   = (const float*)d_in[20];
    const float* ln1g = (const float*)d_in[21];
    const float* ln1b = (const float*)d_in[22];
    const float* W1   = (const float*)d_in[23];
    const float* b1   = (const float*)d_in[24];
    const float* W2   = (const float*)d_in[25];
    const float* b2   = (const float*)d_in[26];
    const float* ln2g = (const float*)d_in[27];
    const float* ln2b = (const float*)d_in[28];

    float* ws     = (float*)d_ws;
    float* pe     = ws;                       // NF
    float* hconv  = pe + NF;                  // 2NF
    float* xf     = hconv + (size_t)2*NF;     // 2NF
    float* o2     = xf + (size_t)2*NF;        // 2NF
    float* feat1  = o2 + (size_t)2*NF;        // 2NF
    float* ff2    = feat1 + (size_t)2*NF;     // 2NF
    float* stats  = ff2 + (size_t)2*NF;       // 2048
    float* Opart  = stats + 2048;             // 2*4*NSPLIT*4096*32
    float* mlbuf  = Opart + (size_t)2*4*NSPLIT*4096*32;   // 2*4*NSPLIT*4096
    float* Pbuf   = mlbuf + (size_t)2*4*NSPLIT*4096;      // 2048*chunk

    const size_t fixedFloats = (size_t)11*NF + 2048
                             + (size_t)2*4*NSPLIT*4096*32 + (size_t)2*4*NSPLIT*4096;
    const size_t fixedUsh = (size_t)2097152 + 196608 + 6*1048576 + 4194304;
    int chunk = 128;
    const int cand[6] = {4096, 2048, 1024, 512, 256, 128};
    for (int ci = 0; ci < 6; ++ci){
        size_t need = (fixedFloats + (size_t)2048*cand[ci])*4
                    + (fixedUsh + (size_t)2*cand[ci]*8192)*2;
        if (need <= ws_size){ chunk = cand[ci]; break; }
    }
    ushort_t* Wt     = (ushort_t*)(Pbuf + (size_t)2048*chunk);
    ushort_t* wbuf   = Wt + 2097152;
    ushort_t* hb     = wbuf + 196608;
    ushort_t* Qb     = hb + 1048576;
    ushort_t* Kb     = Qb + 1048576;
    ushort_t* Vtb    = Kb + 1048576;
    ushort_t* Ob     = Vtb + 1048576;
    ushort_t* feat1b = Ob + 1048576;
    ushort_t* ff1b   = feat1b + 1048576;
    ushort_t* Abuf   = ff1b + 4194304;

    pos_stats_kernel<<<1, 256, 0, stream>>>(pos, stats);
    pe_kernel<<<NPTS*64/256, 256, 0, stream>>>(pos, stats, pe);
    wt_kernel<<<dim3(256, 4, 2), 256, 0, stream>>>(Wx, Wy, Wt);
    wcast_kernel<<<768, 256, 0, stream>>>(Wq, Wk, Wv, Wo, W1, W2, wbuf);

    for (int base = 0; base < NPTS; base += chunk){
        cf_kernel<<<chunk, 256, 0, stream>>>(x, y, pos, nbr, Abuf, base, chunk);
        mfma_gemm_kernel<<<dim3(chunk/128, 1, 2*KSPLIT), 256, 0, stream>>>(Abuf, Wt, Pbuf, chunk);
        reduceP_kernel<<<dim3(chunk*128/2048, 2), 256, 0, stream>>>(Pbuf, hconv, stats, chunk, base);
    }

    bn_apply_kernel<<<dim3(NF/256, 2), 256, 0, stream>>>(hconv, stats, bnxg, bnxb, bnyg, bnyb,
                                                         pe, xf, hb);

    dgemm_kernel<2><<<dim3(32, 1, 6), 256, 0, stream>>>(hb, wbuf, bq, bk, bv,
        nullptr, Qb, Kb, Vtb, 128, (long)NF, 0);

    attn_mfma_kernel<<<dim3(64, 4, 2*NSPLIT), 256, 0, stream>>>(Qb, Kb, Vtb, Opart, mlbuf);
    attn_combine_kernel<<<4096, 256, 0, stream>>>(Opart, mlbuf, Ob);

    dgemm_kernel<0><<<dim3(32, 1, 2), 256, 0, stream>>>(Ob, wbuf + 49152, bo, nullptr, nullptr,
        o2, nullptr, nullptr, nullptr, 128, (long)NF, (long)NF);
    ln_res_kernel<<<dim3(NPTS, 2), 128, 0, stream>>>(xf, o2, ln1g, ln1b, feat1, feat1b);

    dgemm_kernel<1><<<dim3(32, 4, 2), 256, 0, stream>>>(feat1b, wbuf + 65536, b1, nullptr, nullptr,
        nullptr, ff1b, nullptr, nullptr, 128, (long)NF, 0);
    dgemm_kernel<0><<<dim3(32, 1, 2), 256, 0, stream>>>(ff1b, wbuf + 131072, b2, nullptr, nullptr,
        ff2, nullptr, nullptr, nullptr, 512, (long)2097152, (long)NF);

    ln2_combine_kernel<<<NPTS, 128, 0, stream>>>(feat1, ff2, ln2g, ln2b, x, y, (float*)d_out);
}

// Round 8
// 312.187 us; speedup vs baseline: 8.0316x; 1.0101x over previous
//
#include <hip/hip_runtime.h>
#include <cstddef>

#define NPTS 4096
#define KNBR 80
#define CH   128
#define NF   (NPTS*CH)      // 524288
#define FFD  512
#define KSPLIT 8
#define NSPLIT 8            // attention key-split

typedef unsigned short ushort_t;
typedef short bf16x8 __attribute__((ext_vector_type(8)));
typedef float f32x4 __attribute__((ext_vector_type(4)));

__device__ __forceinline__ unsigned short f2bf(float f){
    unsigned int u = __float_as_uint(f);
    unsigned int r = (u + 0x7FFFu + ((u >> 16) & 1u)) >> 16;
    return (unsigned short)r;
}

// pack two fp32 -> bf16 pair by truncation: low = hi16(a), high = hi16(b)
__device__ __forceinline__ unsigned pack2bf_trunc(float a, float b){
    return __builtin_amdgcn_perm(__float_as_uint(b), __float_as_uint(a), 0x07060302u);
}

__device__ __forceinline__ void load_lds16(const ushort_t* g, ushort_t* l){
    __builtin_amdgcn_global_load_lds(
        (const __attribute__((address_space(1))) unsigned int*)g,
        (__attribute__((address_space(3))) unsigned int*)l, 16, 0, 0);
}

// ---------------- pos stats (+ zero BN accumulators) ----------------
__global__ void pos_stats_kernel(const float* __restrict__ pos, float* __restrict__ stats){
    __shared__ float red[256];
    int t = threadIdx.x;
    stats[t] = 0.f;            // BN sum accumulators [0..255]
    stats[256 + t] = 0.f;      // BN sumsq accumulators [256..511]
    float s = 0.f;
    for (int i = t; i < NPTS; i += 256) s += pos[(size_t)i*3];
    red[t] = s; __syncthreads();
    for (int o = 128; o; o >>= 1){ if (t < o) red[t] += red[t+o]; __syncthreads(); }
    float mean = red[0] / (float)NPTS;
    __syncthreads();
    float ss = 0.f;
    for (int i = t; i < NPTS; i += 256){ float d = pos[(size_t)i*3] - mean; ss += d*d; }
    red[t] = ss; __syncthreads();
    for (int o = 128; o; o >>= 1){ if (t < o) red[t] += red[t+o]; __syncthreads(); }
    if (t == 0){
        float sd = sqrtf(red[0] / (float)(NPTS-1));
        stats[512] = mean;
        stats[513] = 1.f/(sd + 1e-8f);
    }
}

// ---------------- positional encoding ----------------
__global__ void pe_kernel(const float* __restrict__ pos, const float* __restrict__ stats,
                          float* __restrict__ pe){
    int t = blockIdx.x*256 + threadIdx.x;
    int i = t >> 6, m = t & 63;
    float px = (pos[(size_t)i*3] - stats[512]) * stats[513];
    float dv = expf((float)(2*m) * -0.07195578415606394f);
    float ang = px * dv;
    float sv, cv;
    sincosf(ang, &sv, &cv);
    pe[(size_t)i*CH + 2*m]     = sv;
    pe[(size_t)i*CH + 2*m + 1] = cv;
}

// ---------------- conv W transpose+cast: Wt[f][n][k] = W_f[k][n] (bf16) ----------------
__global__ __launch_bounds__(256) void wt_kernel(const float* __restrict__ Wx,
        const float* __restrict__ Wy, ushort_t* __restrict__ Wt){
    __shared__ float tile[32][33];
    const float* W = blockIdx.z ? Wy : Wx;
    int kb = blockIdx.x, nb = blockIdx.y;
    int tr = threadIdx.x & 31, tc = threadIdx.x >> 5;
    #pragma unroll
    for (int rr = 0; rr < 32; rr += 8)
        tile[tc+rr][tr] = W[(size_t)(kb*32 + tc + rr)*128 + nb*32 + tr];
    __syncthreads();
    size_t fo = (size_t)blockIdx.z * 8192 * 128;
    #pragma unroll
    for (int rr = 0; rr < 32; rr += 8)
        Wt[fo + (size_t)(nb*32 + tc + rr)*8192 + kb*32 + tr] = f2bf(tile[tr][tc+rr]);
}

// ---------------- dense-weight cast (Wq|Wk|Wv|Wo|W1|W2 -> bf16 packed) ----------------
__global__ void wcast_kernel(const float* __restrict__ Wq, const float* __restrict__ Wk,
        const float* __restrict__ Wv, const float* __restrict__ Wo,
        const float* __restrict__ W1, const float* __restrict__ W2,
        ushort_t* __restrict__ dst){
    int i = blockIdx.x*256 + threadIdx.x;     // < 196608
    const float* src; int off;
    if      (i < 16384)  { src = Wq; off = i; }
    else if (i < 32768)  { src = Wk; off = i - 16384; }
    else if (i < 49152)  { src = Wv; off = i - 32768; }
    else if (i < 65536)  { src = Wo; off = i - 49152; }
    else if (i < 131072) { src = W1; off = i - 65536; }
    else                 { src = W2; off = i - 131072; }
    dst[i] = f2bf(src[off]);
}

// ---------------- cconv stage 1 (MFMA): A = Ct(64 x n) @ F(n x 128) -> bf16 ----------------
__global__ __launch_bounds__(256) void cf_kernel(
        const float* __restrict__ xin, const float* __restrict__ yin,
        const float* __restrict__ pos, const int* __restrict__ nbr,
        ushort_t* __restrict__ Abuf, int base, int chunk){
    __shared__ ushort_t Ct[64*96];
    __shared__ ushort_t Ft[128*40];
    __shared__ int nbl[KNBR];
    __shared__ int cnt;
    int i = base + blockIdx.x;
    int t = threadIdx.x;
    for (int z = t; z < 64*96/8; z += 256) ((uint4*)Ct)[z] = uint4{0,0,0,0};
    if (t == 0) cnt = 0;
    __syncthreads();
    if (t < KNBR){
        int nb = nbr[(size_t)i*KNBR + t];
        if (nb != i){
            float p0 = pos[(size_t)i*3], p1 = pos[(size_t)i*3+1], p2 = pos[(size_t)i*3+2];
            const float RAD = 0.1125f;
            float rx = (pos[(size_t)nb*3+0]-p0)/RAD;
            float ry = (pos[(size_t)nb*3+1]-p1)/RAD;
            float rz = (pos[(size_t)nb*3+2]-p2)/RAD;
            float r2 = rx*rx + ry*ry + rz*rz;
            float w1 = 1.f - r2;
            float win = fminf(fmaxf(w1*w1*w1, 0.f), 1.f);
            float nrm = sqrtf(fmaxf(r2, 1e-12f));
            float linf = fmaxf(fmaxf(fabsf(rx), fabsf(ry)), fabsf(rz));
            linf = fmaxf(linf, 1e-9f);
            float sc = nrm/linf;
            float gx = fminf(fmaxf((rx*sc+1.f)*0.5f*3.f, 0.f), 3.f);
            float gy = fminf(fmaxf((ry*sc+1.f)*0.5f*3.f, 0.f), 3.f);
            float gz = fminf(fmaxf((rz*sc+1.f)*0.5f*3.f, 0.f), 3.f);
            float fx = fminf(floorf(gx), 2.f), fy = fminf(floorf(gy), 2.f), fz = fminf(floorf(gz), 2.f);
            float tx = gx-fx, ty = gy-fy, tz = gz-fz;
            int ix = (int)fx, iy = (int)fy, iz = (int)fz;
            int cb = (ix<<4) + (iy<<2) + iz;
            float x0 = (1.f-tx)*win, x1 = tx*win;
            float w00 = x0*(1.f-ty), w01 = x0*ty, w10 = x1*(1.f-ty), w11 = x1*ty;
            float z0 = 1.f-tz, z1 = tz;
            int slot = atomicAdd(&cnt, 1);
            nbl[slot] = nb;
            Ct[(cb     )*96 + slot] = f2bf(w00*z0);
            Ct[(cb + 1 )*96 + slot] = f2bf(w00*z1);
            Ct[(cb + 4 )*96 + slot] = f2bf(w01*z0);
            Ct[(cb + 5 )*96 + slot] = f2bf(w01*z1);
            Ct[(cb + 16)*96 + slot] = f2bf(w10*z0);
            Ct[(cb + 17)*96 + slot] = f2bf(w10*z1);
            Ct[(cb + 20)*96 + slot] = f2bf(w11*z0);
            Ct[(cb + 21)*96 + slot] = f2bf(w11*z1);
        }
    }
    __syncthreads();
    int n = cnt;
    int nch = (n + 31) >> 5;
    int lane = t & 63, w = t >> 6;
    int l15 = lane & 15, quad = lane >> 4;
    int jp = t & 15, cg = t >> 4;     // gather: j-pair 0..15, channel-group(8) 0..15
    for (int f = 0; f < 2; ++f){
        const float* feat = f ? yin : xin;
        f32x4 acc[8] = {};
        for (int ck = 0; ck < nch; ++ck){
            __syncthreads();
            int js0 = ck*32 + 2*jp;
            float4 a0 = float4{0,0,0,0}, a1 = float4{0,0,0,0};
            float4 b0 = float4{0,0,0,0}, b1 = float4{0,0,0,0};
            if (js0 < n){
                const float* s0 = feat + (size_t)nbl[js0]*128 + cg*8;
                a0 = *(const float4*)s0; a1 = *(const float4*)(s0 + 4);
            }
            if (js0 + 1 < n){
                const float* s1 = feat + (size_t)nbl[js0+1]*128 + cg*8;
                b0 = *(const float4*)s1; b1 = *(const float4*)(s1 + 4);
            }
            unsigned* Fd = (unsigned*)Ft;   // row stride 40 ushorts = 20 dwords
            int ch0 = cg*8;
            Fd[(ch0+0)*20 + jp] = pack2bf_trunc(a0.x, b0.x);
            Fd[(ch0+1)*20 + jp] = pack2bf_trunc(a0.y, b0.y);
            Fd[(ch0+2)*20 + jp] = pack2bf_trunc(a0.z, b0.z);
            Fd[(ch0+3)*20 + jp] = pack2bf_trunc(a0.w, b0.w);
            Fd[(ch0+4)*20 + jp] = pack2bf_trunc(a1.x, b1.x);
            Fd[(ch0+5)*20 + jp] = pack2bf_trunc(a1.y, b1.y);
            Fd[(ch0+6)*20 + jp] = pack2bf_trunc(a1.z, b1.z);
            Fd[(ch0+7)*20 + jp] = pack2bf_trunc(a1.w, b1.w);
            __syncthreads();
            bf16x8 af = *(const bf16x8*)(Ct + (size_t)(w*16 + l15)*96 + ck*32 + quad*8);
            #pragma unroll
            for (int nt = 0; nt < 8; ++nt){
                bf16x8 bfr = *(const bf16x8*)(Ft + (size_t)(nt*16 + l15)*40 + quad*8);
                acc[nt] = __builtin_amdgcn_mfma_f32_16x16x32_bf16(af, bfr, acc[nt], 0, 0, 0);
            }
        }
        ushort_t* dst = Abuf + ((size_t)f*chunk + blockIdx.x)*8192;
        #pragma unroll
        for (int nt = 0; nt < 8; ++nt)
            #pragma unroll
            for (int reg = 0; reg < 4; ++reg){
                int cell = w*16 + quad*4 + reg;
                int c    = nt*16 + l15;
                dst[(size_t)cell*128 + c] = f2bf(acc[nt][reg]);
            }
    }
}

// ---------------- cconv stage 2: MFMA GEMM  P = A(bf16) @ Wt^T, split-K ----------------
__global__ __launch_bounds__(256) void mfma_gemm_kernel(
        const ushort_t* __restrict__ Abuf, const ushort_t* __restrict__ Wt,
        float* __restrict__ Pbuf, int chunk){
    __shared__ ushort_t Asm[128*64];
    __shared__ ushort_t Bsm[128*64];
    int tid = threadIdx.x, lane = tid & 63, w = tid >> 6;
    int feat = blockIdx.z >> 3, s = blockIdx.z & 7;
    const ushort_t* Ab = Abuf + (size_t)feat*chunk*8192 + (size_t)blockIdx.x*128*8192;
    const ushort_t* Bb = Wt + (size_t)feat*128*8192;
    int wm = w >> 1, wn = w & 1;
    int lr = lane >> 3, pb = lane & 7, lb = pb ^ lr;
    int quad = lane >> 4, l15 = lane & 15;
    int arow0 = w*32;
    f32x4 acc[4][4] = {};
    const int kk0 = s*(8192/KSPLIT), kk1 = kk0 + 8192/KSPLIT;
    for (int kk = kk0; kk < kk1; kk += 64){
        __syncthreads();
        #pragma unroll
        for (int q = 0; q < 4; ++q){
            int r = arow0 + q*8 + lr;
            load_lds16(Ab + (size_t)r*8192 + kk + lb*8, Asm + (arow0 + q*8)*64);
            load_lds16(Bb + (size_t)r*8192 + kk + lb*8, Bsm + (arow0 + q*8)*64);
        }
        __syncthreads();
        #pragma unroll
        for (int h = 0; h < 2; ++h){
            bf16x8 aF[4], bF[4];
            #pragma unroll
            for (int mt = 0; mt < 4; ++mt){
                int ml = wm*64 + mt*16 + l15;
                int p = (h*4 + quad) ^ (ml & 7);
                aF[mt] = *(const bf16x8*)(Asm + ml*64 + p*8);
            }
            #pragma unroll
            for (int nt = 0; nt < 4; ++nt){
                int nl = wn*64 + nt*16 + l15;
                int p = (h*4 + quad) ^ (nl & 7);
                bF[nt] = *(const bf16x8*)(Bsm + nl*64 + p*8);
            }
            #pragma unroll
            for (int mt = 0; mt < 4; ++mt)
                #pragma unroll
                for (int nt = 0; nt < 4; ++nt)
                    acc[mt][nt] = __builtin_amdgcn_mfma_f32_16x16x32_bf16(
                        aF[mt], bF[nt], acc[mt][nt], 0, 0, 0);
        }
    }
    float* P = Pbuf + (size_t)blockIdx.z*chunk*128 + (size_t)blockIdx.x*128*128;
    #pragma unroll
    for (int mt = 0; mt < 4; ++mt)
        #pragma unroll
        for (int nt = 0; nt < 4; ++nt)
            #pragma unroll
            for (int reg = 0; reg < 4; ++reg){
                int r = wm*64 + mt*16 + quad*4 + reg;
                int c = wn*64 + nt*16 + l15;
                P[(size_t)r*128 + c] = acc[mt][nt][reg];
            }
}

// ---------------- reduceP + fused BN partial stats ----------------
__global__ void reduceP_kernel(const float* __restrict__ P, float* __restrict__ hconv,
                               float* __restrict__ stats, int chunk, int base){
    __shared__ float ls[256], lq[256];
    int f = blockIdx.y, t = threadIdx.x;
    size_t base_idx = (size_t)blockIdx.x*2048 + t;
    float sum = 0.f, sq = 0.f;
    #pragma unroll
    for (int k = 0; k < 8; ++k){
        size_t idx = base_idx + (size_t)k*256;
        float s = 0.f;
        #pragma unroll
        for (int sp = 0; sp < KSPLIT; ++sp)
            s += P[((size_t)(f*KSPLIT + sp))*chunk*128 + idx];
        hconv[(size_t)f*NF + (size_t)base*128 + idx] = s;
        sum += s; sq += s*s;
    }
    ls[t] = sum; lq[t] = sq;
    __syncthreads();
    if (t < 128){
        atomicAdd(&stats[f*128 + t], ls[t] + ls[t+128]);
        atomicAdd(&stats[256 + f*128 + t], lq[t] + lq[t+128]);
    }
}

// ---------------- generic dense MFMA GEMM: D = A(M x K) @ B(N x K)^T ----------------
template<int MODE>
__global__ __launch_bounds__(256) void dgemm_kernel(
        const ushort_t* __restrict__ A, const ushort_t* __restrict__ Bw,
        const float* __restrict__ bs0, const float* __restrict__ bs1,
        const float* __restrict__ bs2,
        float* __restrict__ oF, ushort_t* __restrict__ oB0,
        ushort_t* __restrict__ oB1, ushort_t* __restrict__ oB2,
        int K, long aZ, long oZ){
    __shared__ ushort_t Asm[128*64];
    __shared__ ushort_t Bsm[128*64];
    int tid = threadIdx.x, lane = tid & 63, w = tid >> 6;
    int z = blockIdx.z;
    int f = (MODE == 2) ? (z/3) : z;
    int wsel = (MODE == 2) ? (z - 3*f) : 0;
    const ushort_t* Ab = A + (size_t)f*aZ + (size_t)blockIdx.x*128*K;
    const ushort_t* Bb = Bw + ((MODE == 2) ? (size_t)wsel*16384 : 0)
                            + (size_t)blockIdx.y*128*K;
    int wm = w >> 1, wn = w & 1;
    int lr = lane >> 3, pb = lane & 7, lb = pb ^ lr;
    int quad = lane >> 4, l15 = lane & 15;
    int arow0 = w*32;
    f32x4 acc[4][4] = {};
    for (int kk = 0; kk < K; kk += 64){
        __syncthreads();
        #pragma unroll
        for (int q = 0; q < 4; ++q){
            int r = arow0 + q*8 + lr;
            load_lds16(Ab + (size_t)r*K + kk + lb*8, Asm + (arow0 + q*8)*64);
            load_lds16(Bb + (size_t)r*K + kk + lb*8, Bsm + (arow0 + q*8)*64);
        }
        __syncthreads();
        #pragma unroll
        for (int h = 0; h < 2; ++h){
            bf16x8 aF[4], bF[4];
            #pragma unroll
            for (int mt = 0; mt < 4; ++mt){
                int ml = wm*64 + mt*16 + l15;
                int p = (h*4 + quad) ^ (ml & 7);
                aF[mt] = *(const bf16x8*)(Asm + ml*64 + p*8);
            }
            #pragma unroll
            for (int nt = 0; nt < 4; ++nt){
                int nl = wn*64 + nt*16 + l15;
                int p = (h*4 + quad) ^ (nl & 7);
                bF[nt] = *(const bf16x8*)(Bsm + nl*64 + p*8);
            }
            #pragma unroll
            for (int mt = 0; mt < 4; ++mt)
                #pragma unroll
                for (int nt = 0; nt < 4; ++nt)
                    acc[mt][nt] = __builtin_amdgcn_mfma_f32_16x16x32_bf16(
                        aF[mt], bF[nt], acc[mt][nt], 0, 0, 0);
        }
    }
    int r0 = blockIdx.x*128, c0 = blockIdx.y*128;
    const float* bias = bs0;
    float osc = 1.f;
    if (MODE == 2){
        bias = (wsel == 0) ? bs0 : (wsel == 1 ? bs1 : bs2);
        // Q scale: log2(e)/sqrt(32)  (softmax runs in exp2 domain)
        if (wsel == 0) osc = 0.25506764057565145f;
    }
    #pragma unroll
    for (int mt = 0; mt < 4; ++mt)
        #pragma unroll
        for (int nt = 0; nt < 4; ++nt)
            #pragma unroll
            for (int reg = 0; reg < 4; ++reg){
                int R = r0 + wm*64 + mt*16 + quad*4 + reg;
                int C = c0 + wn*64 + nt*16 + l15;
                float v = acc[mt][nt][reg];
                if (MODE == 0){
                    oF[(size_t)z*oZ + (size_t)R*128 + C] = v + bias[C];
                } else if (MODE == 1){
                    float r = fmaxf(v + bias[C], 0.f);
                    oB0[(size_t)z*2097152 + (size_t)R*512 + C] = f2bf(r);
                } else {
                    float r = (v + bias[C])*osc;
                    int hh = C >> 5, dd = C & 31;
                    if (wsel < 2){
                        ushort_t* dst = wsel ? oB1 : oB0;
                        dst[((size_t)(f*4+hh)*4096 + R)*32 + dd] = f2bf(r);
                    } else {
                        oB2[((size_t)(f*4+hh)*32 + dd)*4096 + R] = f2bf(r);
                    }
                }
            }
}

// bn apply (stats = raw sum/sumsq) + relu -> xf; h = xf + pe -> hb (bf16)
__global__ void bn_apply_kernel(const float* __restrict__ hconv, const float* __restrict__ stats,
        const float* __restrict__ gx, const float* __restrict__ bxp,
        const float* __restrict__ gy, const float* __restrict__ byp,
        const float* __restrict__ pe,
        float* __restrict__ xf, ushort_t* __restrict__ hb){
    int f = blockIdx.y;
    size_t idx = (size_t)blockIdx.x*256 + threadIdx.x;
    int ch = idx & 127;
    const float* g = f ? gy : gx;
    const float* b = f ? byp : bxp;
    float m  = stats[f*128 + ch] * (1.f/NPTS);
    float var = stats[256 + f*128 + ch] * (1.f/NPTS) - m*m;
    float inv = rsqrtf(var + 1e-5f);
    float vv = hconv[(size_t)f*NF + idx];
    float r = fmaxf((vv - m)*inv*g[ch] + b[ch], 0.f);
    xf[(size_t)f*NF + idx] = r;
    hb[(size_t)f*NF + idx] = f2bf(r + pe[idx]);
}

// ---------------- MFMA flash attention, key-split, Schraudolph exp2 ----------------
// No max-subtraction (shift-invariance + fp32 exponent headroom); exp2 computed by the
// integer bit-trick fma(s,2^23,127*2^23) -> the int IS the fp32 pattern of ~2^s; its
// ripple and global scale cancel in the softmax normalization (l from same P values).
// Vl row 32 = ones -> PV MFMA emits row-sum l for free. Opart stored as bf16 pairs.
__global__ __launch_bounds__(256) void attn_mfma_kernel(
        const ushort_t* __restrict__ Qb, const ushort_t* __restrict__ Kb,
        const ushort_t* __restrict__ Vt, ushort_t* __restrict__ Opartb,
        float* __restrict__ ml){
    __shared__ ushort_t Kl[64*40];
    __shared__ ushort_t Vl[48*72];
    __shared__ ushort_t Pl[64*72];
    int tid = threadIdx.x, lane = tid & 63, w = tid >> 6;
    int l15 = lane & 15, quad = lane >> 4;
    int q0 = blockIdx.x*64;
    int head = blockIdx.y;
    int f = blockIdx.z >> 3, ksp = blockIdx.z & (NSPLIT-1);
    const ushort_t* Qh = Qb + ((size_t)(f*4+head)*4096)*32;
    const ushort_t* Kh = Kb + ((size_t)(f*4+head)*4096)*32;
    const ushort_t* Vh = Vt + ((size_t)(f*4+head)*32)*4096;
    int ql = w*16 + l15;
    int qg = q0 + ql;
    bf16x8 qfrag = *(const bf16x8*)(Qh + (size_t)qg*32 + quad*8);
    for (int z = tid; z < 16*72; z += 256)
        Vl[32*72 + z] = (z < 72) ? (ushort_t)0x3F80 : (ushort_t)0;
    f32x4 oacc[3] = {};
    const float S23 = 8388608.0f;       // 2^23
    const float B23 = 1065353216.0f;    // 127 * 2^23
    int kr = tid >> 2, kseg = tid & 3;
    int vd = tid >> 3, vseg = tid & 7;
    for (int kt = 0; kt < 4096/NSPLIT/64; ++kt){
        int k0 = ksp*(4096/NSPLIT) + kt*64;
        uint4 tk = *(const uint4*)(Kh + (size_t)(k0+kr)*32 + kseg*8);
        uint4 tv = *(const uint4*)(Vh + (size_t)vd*4096 + k0 + vseg*8);
        __syncthreads();
        *(uint4*)(Kl + kr*40 + kseg*8) = tk;
        *(uint4*)(Vl + vd*72 + vseg*8) = tv;
        __syncthreads();
        f32x4 sc[4] = {};
        #pragma unroll
        for (int mt = 0; mt < 4; ++mt){
            bf16x8 af = *(const bf16x8*)(Kl + (mt*16 + l15)*40 + quad*8);
            sc[mt] = __builtin_amdgcn_mfma_f32_16x16x32_bf16(af, qfrag, sc[mt], 0, 0, 0);
        }
        #pragma unroll
        for (int mt = 0; mt < 4; ++mt){
            unsigned i0 = (unsigned)fmaf(sc[mt][0], S23, B23);
            unsigned i1 = (unsigned)fmaf(sc[mt][1], S23, B23);
            unsigned i2 = (unsigned)fmaf(sc[mt][2], S23, B23);
            unsigned i3 = (unsigned)fmaf(sc[mt][3], S23, B23);
            uint2 pk;
            pk.x = __builtin_amdgcn_perm(i1, i0, 0x07060302u);
            pk.y = __builtin_amdgcn_perm(i3, i2, 0x07060302u);
            *(uint2*)(Pl + ql*72 + mt*16 + quad*4) = pk;
        }
        #pragma unroll
        for (int ks2 = 0; ks2 < 2; ++ks2){
            bf16x8 bfr = *(const bf16x8*)(Pl + ql*72 + ks2*32 + quad*8);
            #pragma unroll
            for (int mtv = 0; mtv < 3; ++mtv){
                bf16x8 af = *(const bf16x8*)(Vl + (mtv*16 + l15)*72 + ks2*32 + quad*8);
                oacc[mtv] = __builtin_amdgcn_mfma_f32_16x16x32_bf16(af, bfr, oacc[mtv], 0, 0, 0);
            }
        }
    }
    float lval = __shfl(oacc[2][0], l15);   // row 32 (ones) output, held by quad 0
    int slot = (f*4 + head)*NSPLIT + ksp;
    ushort_t* Op = Opartb + (((size_t)slot*4096 + qg)*32);
    #pragma unroll
    for (int mtv = 0; mtv < 2; ++mtv){
        *(unsigned*)(Op + mtv*16 + quad*4)     = pack2bf_trunc(oacc[mtv][0], oacc[mtv][1]);
        *(unsigned*)(Op + mtv*16 + quad*4 + 2) = pack2bf_trunc(oacc[mtv][2], oacc[mtv][3]);
    }
    if (lane < 16)
        ml[(size_t)slot*4096 + qg] = lval;
}

// ---------------- attention split combine (plain sums) -> Ob (bf16 [f][q][128]) ----------------
__global__ void attn_combine_kernel(const ushort_t* __restrict__ Opartb,
        const float* __restrict__ ml, ushort_t* __restrict__ Ob){
    int gid = blockIdx.x*256 + threadIdx.x;     // < 2*4*4096*16 (d-pairs)
    int fh = gid >> 16;
    int rem = gid & 65535;
    int q = rem >> 4, d2 = rem & 15;
    float lsum = 0.f, o0 = 0.f, o1 = 0.f;
    #pragma unroll
    for (int s = 0; s < NSPLIT; ++s){
        lsum += ml[((size_t)fh*NSPLIT + s)*4096 + q];
        unsigned u = *(const unsigned*)(Opartb + (((size_t)(fh*NSPLIT + s))*4096 + q)*32 + 2*d2);
        o0 += __uint_as_float(u << 16);
        o1 += __uint_as_float(u & 0xFFFF0000u);
    }
    float inv = 1.f/lsum;
    int f = fh >> 2, head = fh & 3;
    *(unsigned*)(Ob + (size_t)f*NF + (size_t)q*128 + head*32 + 2*d2) =
        pack2bf_trunc(o0*inv, o1*inv);
}

// ---------------- LayerNorm(a + b), optional bf16 copy ----------------
__global__ __launch_bounds__(128) void ln_res_kernel(const float* __restrict__ a,
        const float* __restrict__ b, const float* __restrict__ g,
        const float* __restrict__ be, float* __restrict__ out,
        ushort_t* __restrict__ outB){
    __shared__ float red[128];
    int t = threadIdx.x;
    size_t off = (size_t)blockIdx.y*NF + (size_t)blockIdx.x*CH;
    float v = a[off + t] + b[off + t];
    red[t] = v; __syncthreads();
    for (int o = 64; o; o >>= 1){ if (t < o) red[t] += red[t+o]; __syncthreads(); }
    float m = red[0] / 128.f;
    __syncthreads();
    float d = v - m;
    red[t] = d*d; __syncthreads();
    for (int o = 64; o; o >>= 1){ if (t < o) red[t] += red[t+o]; __syncthreads(); }
    float var = red[0] / 128.f;
    float res = (v - m)*rsqrtf(var + 1e-5f)*g[t] + be[t];
    out[off + t] = res;
    if (outB) outB[off + t] = f2bf(res);
}

// ---------------- fused final: LN2 (both feats) + sigmoid gate ----------------
__global__ __launch_bounds__(128) void ln2_combine_kernel(
        const float* __restrict__ a, const float* __restrict__ b,
        const float* __restrict__ g, const float* __restrict__ be,
        const float* __restrict__ x, const float* __restrict__ y,
        float* __restrict__ out){
    __shared__ float red0[128], red1[128];
    int t = threadIdx.x;
    size_t off = (size_t)blockIdx.x*CH;
    float v0 = a[off + t] + b[off + t];
    float v1 = a[NF + off + t] + b[NF + off + t];
    red0[t] = v0; red1[t] = v1; __syncthreads();
    for (int o = 64; o; o >>= 1){
        if (t < o){ red0[t] += red0[t+o]; red1[t] += red1[t+o]; }
        __syncthreads();
    }
    float m0 = red0[0] / 128.f, m1 = red1[0] / 128.f;
    __syncthreads();
    float d0 = v0 - m0, d1 = v1 - m1;
    red0[t] = d0*d0; red1[t] = d1*d1; __syncthreads();
    for (int o = 64; o; o >>= 1){
        if (t < o){ red0[t] += red0[t+o]; red1[t] += red1[t+o]; }
        __syncthreads();
    }
    float r0 = d0*rsqrtf(red0[0]/128.f + 1e-5f)*g[t] + be[t];
    float r1 = d1*rsqrtf(red1[0]/128.f + 1e-5f)*g[t] + be[t];
    float wgt = 1.f/(1.f + __expf(-(r0 + r1)));
    out[off + t] = 2.f*x[off + t]*wgt + 2.f*y[off + t]*(1.f - wgt);
}

extern "C" void kernel_launch(void* const* d_in, const int* in_sizes, int n_in,
                              void* d_out, int out_size, void* d_ws, size_t ws_size,
                              hipStream_t stream){
    (void)in_sizes; (void)n_in; (void)out_size;
    const float* x    = (const float*)d_in[0];
    const float* y    = (const float*)d_in[1];
    const float* pos  = (const float*)d_in[2];
    const int*   nbr  = (const int*)  d_in[3];
    const float* Wx   = (const float*)d_in[5];
    const float* bnxg = (const float*)d_in[7];
    const float* bnxb = (const float*)d_in[8];
    const float* Wy   = (const float*)d_in[9];
    const float* bnyg = (const float*)d_in[11];
    const float* bnyb = (const float*)d_in[12];
    const float* Wq   = (const float*)d_in[13];
    const float* bq   = (const float*)d_in[14];
    const float* Wk   = (const float*)d_in[15];
    const float* bk   = (const float*)d_in[16];
    const float* Wv   = (const float*)d_in[17];
    const float* bv   = (const float*)d_in[18];
    const float* Wo   = (const float*)d_in[19];
    const float* bo   = (const float*)d_in[20];
    const float* ln1g = (const float*)d_in[21];
    const float* ln1b = (const float*)d_in[22];
    const float* W1   = (const float*)d_in[23];
    const float* b1   = (const float*)d_in[24];
    const float* W2   = (const float*)d_in[25];
    const float* b2   = (const float*)d_in[26];
    const float* ln2g = (const float*)d_in[27];
    const float* ln2b = (const float*)d_in[28];

    float* ws     = (float*)d_ws;
    float* pe     = ws;                       // NF
    float* hconv  = pe + NF;                  // 2NF
    float* xf     = hconv + (size_t)2*NF;     // 2NF
    float* o2     = xf + (size_t)2*NF;        // 2NF
    float* feat1  = o2 + (size_t)2*NF;        // 2NF
    float* ff2    = feat1 + (size_t)2*NF;     // 2NF
    float* stats  = ff2 + (size_t)2*NF;       // 2048
    float* mlbuf  = stats + 2048;             // 2*4*NSPLIT*4096
    float* Pbuf   = mlbuf + (size_t)2*4*NSPLIT*4096;      // 2048*chunk

    const size_t fixedFloats = (size_t)11*NF + 2048 + (size_t)2*4*NSPLIT*4096;
    const size_t fixedUsh = (size_t)2097152 + 196608 + 6*1048576 + 4194304
                          + (size_t)2*4*NSPLIT*4096*32;   // + Opartb (bf16)
    int chunk = 128;
    const int cand[6] = {4096, 2048, 1024, 512, 256, 128};
    for (int ci = 0; ci < 6; ++ci){
        size_t need = (fixedFloats + (size_t)2048*cand[ci])*4
                    + (fixedUsh + (size_t)2*cand[ci]*8192)*2;
        if (need <= ws_size){ chunk = cand[ci]; break; }
    }
    ushort_t* Wt     = (ushort_t*)(Pbuf + (size_t)2048*chunk);
    ushort_t* wbuf   = Wt + 2097152;
    ushort_t* hb     = wbuf + 196608;
    ushort_t* Qb     = hb + 1048576;
    ushort_t* Kb     = Qb + 1048576;
    ushort_t* Vtb    = Kb + 1048576;
    ushort_t* Ob     = Vtb + 1048576;
    ushort_t* feat1b = Ob + 1048576;
    ushort_t* ff1b   = feat1b + 1048576;
    ushort_t* Opartb = ff1b + 4194304;
    ushort_t* Abuf   = Opartb + (size_t)2*4*NSPLIT*4096*32;

    pos_stats_kernel<<<1, 256, 0, stream>>>(pos, stats);
    pe_kernel<<<NPTS*64/256, 256, 0, stream>>>(pos, stats, pe);
    wt_kernel<<<dim3(256, 4, 2), 256, 0, stream>>>(Wx, Wy, Wt);
    wcast_kernel<<<768, 256, 0, stream>>>(Wq, Wk, Wv, Wo, W1, W2, wbuf);

    for (int base = 0; base < NPTS; base += chunk){
        cf_kernel<<<chunk, 256, 0, stream>>>(x, y, pos, nbr, Abuf, base, chunk);
        mfma_gemm_kernel<<<dim3(chunk/128, 1, 2*KSPLIT), 256, 0, stream>>>(Abuf, Wt, Pbuf, chunk);
        reduceP_kernel<<<dim3(chunk*128/2048, 2), 256, 0, stream>>>(Pbuf, hconv, stats, chunk, base);
    }

    bn_apply_kernel<<<dim3(NF/256, 2), 256, 0, stream>>>(hconv, stats, bnxg, bnxb, bnyg, bnyb,
                                                         pe, xf, hb);

    dgemm_kernel<2><<<dim3(32, 1, 6), 256, 0, stream>>>(hb, wbuf, bq, bk, bv,
        nullptr, Qb, Kb, Vtb, 128, (long)NF, 0);

    attn_mfma_kernel<<<dim3(64, 4, 2*NSPLIT), 256, 0, stream>>>(Qb, Kb, Vtb, Opartb, mlbuf);
    attn_combine_kernel<<<2048, 256, 0, stream>>>(Opartb, mlbuf, Ob);

    dgemm_kernel<0><<<dim3(32, 1, 2), 256, 0, stream>>>(Ob, wbuf + 49152, bo, nullptr, nullptr,
        o2, nullptr, nullptr, nullptr, 128, (long)NF, (long)NF);
    ln_res_kernel<<<dim3(NPTS, 2), 128, 0, stream>>>(xf, o2, ln1g, ln1b, feat1, feat1b);

    dgemm_kernel<1><<<dim3(32, 4, 2), 256, 0, stream>>>(feat1b, wbuf + 65536, b1, nullptr, nullptr,
        nullptr, ff1b, nullptr, nullptr, 128, (long)NF, 0);
    dgemm_kernel<0><<<dim3(32, 1, 2), 256, 0, stream>>>(ff1b, wbuf + 131072, b2, nullptr, nullptr,
        ff2, nullptr, nullptr, nullptr, 512, (long)2097152, (long)NF);

    ln2_combine_kernel<<<NPTS, 128, 0, stream>>>(feat1, ff2, ln2g, ln2b, x, y, (float*)d_out);
}

// Round 9
// 296.580 us; speedup vs baseline: 8.4542x; 1.0526x over previous
//
#include <hip/hip_runtime.h>
#include <cstddef>

#define NPTS 4096
#define KNBR 80
#define CH   128
#define NF   (NPTS*CH)      // 524288
#define FFD  512
#define KSPLIT 8
#define NSPLIT 8            // attention key-split

typedef unsigned short ushort_t;
typedef short bf16x8 __attribute__((ext_vector_type(8)));
typedef float f32x4 __attribute__((ext_vector_type(4)));
typedef float f32x16 __attribute__((ext_vector_type(16)));

__device__ __forceinline__ unsigned short f2bf(float f){
    unsigned int u = __float_as_uint(f);
    unsigned int r = (u + 0x7FFFu + ((u >> 16) & 1u)) >> 16;
    return (unsigned short)r;
}

// pack two fp32 -> bf16 pair by truncation: low = hi16(a), high = hi16(b)
__device__ __forceinline__ unsigned pack2bf_trunc(float a, float b){
    return __builtin_amdgcn_perm(__float_as_uint(b), __float_as_uint(a), 0x07060302u);
}

__device__ __forceinline__ void load_lds16(const ushort_t* g, ushort_t* l){
    __builtin_amdgcn_global_load_lds(
        (const __attribute__((address_space(1))) unsigned int*)g,
        (__attribute__((address_space(3))) unsigned int*)l, 16, 0, 0);
}

// ---------------- pos stats (+ zero BN accumulators) ----------------
__global__ void pos_stats_kernel(const float* __restrict__ pos, float* __restrict__ stats){
    __shared__ float red[256];
    int t = threadIdx.x;
    stats[t] = 0.f;            // BN sum accumulators [0..255]
    stats[256 + t] = 0.f;      // BN sumsq accumulators [256..511]
    float s = 0.f;
    for (int i = t; i < NPTS; i += 256) s += pos[(size_t)i*3];
    red[t] = s; __syncthreads();
    for (int o = 128; o; o >>= 1){ if (t < o) red[t] += red[t+o]; __syncthreads(); }
    float mean = red[0] / (float)NPTS;
    __syncthreads();
    float ss = 0.f;
    for (int i = t; i < NPTS; i += 256){ float d = pos[(size_t)i*3] - mean; ss += d*d; }
    red[t] = ss; __syncthreads();
    for (int o = 128; o; o >>= 1){ if (t < o) red[t] += red[t+o]; __syncthreads(); }
    if (t == 0){
        float sd = sqrtf(red[0] / (float)(NPTS-1));
        stats[512] = mean;
        stats[513] = 1.f/(sd + 1e-8f);
    }
}

// ---------------- positional encoding ----------------
__global__ void pe_kernel(const float* __restrict__ pos, const float* __restrict__ stats,
                          float* __restrict__ pe){
    int t = blockIdx.x*256 + threadIdx.x;
    int i = t >> 6, m = t & 63;
    float px = (pos[(size_t)i*3] - stats[512]) * stats[513];
    float dv = expf((float)(2*m) * -0.07195578415606394f);
    float ang = px * dv;
    float sv, cv;
    sincosf(ang, &sv, &cv);
    pe[(size_t)i*CH + 2*m]     = sv;
    pe[(size_t)i*CH + 2*m + 1] = cv;
}

// ---------------- conv W transpose+cast: Wt[f][n][k] = W_f[k][n] (bf16) ----------------
__global__ __launch_bounds__(256) void wt_kernel(const float* __restrict__ Wx,
        const float* __restrict__ Wy, ushort_t* __restrict__ Wt){
    __shared__ float tile[32][33];
    const float* W = blockIdx.z ? Wy : Wx;
    int kb = blockIdx.x, nb = blockIdx.y;
    int tr = threadIdx.x & 31, tc = threadIdx.x >> 5;
    #pragma unroll
    for (int rr = 0; rr < 32; rr += 8)
        tile[tc+rr][tr] = W[(size_t)(kb*32 + tc + rr)*128 + nb*32 + tr];
    __syncthreads();
    size_t fo = (size_t)blockIdx.z * 8192 * 128;
    #pragma unroll
    for (int rr = 0; rr < 32; rr += 8)
        Wt[fo + (size_t)(nb*32 + tc + rr)*8192 + kb*32 + tr] = f2bf(tile[tr][tc+rr]);
}

// ---------------- dense-weight cast (Wq|Wk|Wv|Wo|W1|W2 -> bf16 packed) ----------------
__global__ void wcast_kernel(const float* __restrict__ Wq, const float* __restrict__ Wk,
        const float* __restrict__ Wv, const float* __restrict__ Wo,
        const float* __restrict__ W1, const float* __restrict__ W2,
        ushort_t* __restrict__ dst){
    int i = blockIdx.x*256 + threadIdx.x;     // < 196608
    const float* src; int off;
    if      (i < 16384)  { src = Wq; off = i; }
    else if (i < 32768)  { src = Wk; off = i - 16384; }
    else if (i < 49152)  { src = Wv; off = i - 32768; }
    else if (i < 65536)  { src = Wo; off = i - 49152; }
    else if (i < 131072) { src = W1; off = i - 65536; }
    else                 { src = W2; off = i - 131072; }
    dst[i] = f2bf(src[off]);
}

// ---------------- cconv stage 1 (MFMA): A = Ct(64 x n) @ F(n x 128) -> bf16 ----------------
__global__ __launch_bounds__(256) void cf_kernel(
        const float* __restrict__ xin, const float* __restrict__ yin,
        const float* __restrict__ pos, const int* __restrict__ nbr,
        ushort_t* __restrict__ Abuf, int base, int chunk){
    __shared__ ushort_t Ct[64*96];
    __shared__ ushort_t Ft[128*40];
    __shared__ int nbl[KNBR];
    __shared__ int cnt;
    int i = base + blockIdx.x;
    int t = threadIdx.x;
    for (int z = t; z < 64*96/8; z += 256) ((uint4*)Ct)[z] = uint4{0,0,0,0};
    if (t == 0) cnt = 0;
    __syncthreads();
    if (t < KNBR){
        int nb = nbr[(size_t)i*KNBR + t];
        if (nb != i){
            float p0 = pos[(size_t)i*3], p1 = pos[(size_t)i*3+1], p2 = pos[(size_t)i*3+2];
            const float RAD = 0.1125f;
            float rx = (pos[(size_t)nb*3+0]-p0)/RAD;
            float ry = (pos[(size_t)nb*3+1]-p1)/RAD;
            float rz = (pos[(size_t)nb*3+2]-p2)/RAD;
            float r2 = rx*rx + ry*ry + rz*rz;
            float w1 = 1.f - r2;
            float win = fminf(fmaxf(w1*w1*w1, 0.f), 1.f);
            float nrm = sqrtf(fmaxf(r2, 1e-12f));
            float linf = fmaxf(fmaxf(fabsf(rx), fabsf(ry)), fabsf(rz));
            linf = fmaxf(linf, 1e-9f);
            float sc = nrm/linf;
            float gx = fminf(fmaxf((rx*sc+1.f)*0.5f*3.f, 0.f), 3.f);
            float gy = fminf(fmaxf((ry*sc+1.f)*0.5f*3.f, 0.f), 3.f);
            float gz = fminf(fmaxf((rz*sc+1.f)*0.5f*3.f, 0.f), 3.f);
            float fx = fminf(floorf(gx), 2.f), fy = fminf(floorf(gy), 2.f), fz = fminf(floorf(gz), 2.f);
            float tx = gx-fx, ty = gy-fy, tz = gz-fz;
            int ix = (int)fx, iy = (int)fy, iz = (int)fz;
            int cb = (ix<<4) + (iy<<2) + iz;
            float x0 = (1.f-tx)*win, x1 = tx*win;
            float w00 = x0*(1.f-ty), w01 = x0*ty, w10 = x1*(1.f-ty), w11 = x1*ty;
            float z0 = 1.f-tz, z1 = tz;
            int slot = atomicAdd(&cnt, 1);
            nbl[slot] = nb;
            Ct[(cb     )*96 + slot] = f2bf(w00*z0);
            Ct[(cb + 1 )*96 + slot] = f2bf(w00*z1);
            Ct[(cb + 4 )*96 + slot] = f2bf(w01*z0);
            Ct[(cb + 5 )*96 + slot] = f2bf(w01*z1);
            Ct[(cb + 16)*96 + slot] = f2bf(w10*z0);
            Ct[(cb + 17)*96 + slot] = f2bf(w10*z1);
            Ct[(cb + 20)*96 + slot] = f2bf(w11*z0);
            Ct[(cb + 21)*96 + slot] = f2bf(w11*z1);
        }
    }
    __syncthreads();
    int n = cnt;
    int nch = (n + 31) >> 5;
    int lane = t & 63, w = t >> 6;
    int l15 = lane & 15, quad = lane >> 4;
    int jp = t & 15, cg = t >> 4;     // gather: j-pair 0..15, channel-group(8) 0..15
    for (int f = 0; f < 2; ++f){
        const float* feat = f ? yin : xin;
        f32x4 acc[8] = {};
        for (int ck = 0; ck < nch; ++ck){
            __syncthreads();
            int js0 = ck*32 + 2*jp;
            float4 a0 = float4{0,0,0,0}, a1 = float4{0,0,0,0};
            float4 b0 = float4{0,0,0,0}, b1 = float4{0,0,0,0};
            if (js0 < n){
                const float* s0 = feat + (size_t)nbl[js0]*128 + cg*8;
                a0 = *(const float4*)s0; a1 = *(const float4*)(s0 + 4);
            }
            if (js0 + 1 < n){
                const float* s1 = feat + (size_t)nbl[js0+1]*128 + cg*8;
                b0 = *(const float4*)s1; b1 = *(const float4*)(s1 + 4);
            }
            unsigned* Fd = (unsigned*)Ft;   // row stride 40 ushorts = 20 dwords
            int ch0 = cg*8;
            Fd[(ch0+0)*20 + jp] = pack2bf_trunc(a0.x, b0.x);
            Fd[(ch0+1)*20 + jp] = pack2bf_trunc(a0.y, b0.y);
            Fd[(ch0+2)*20 + jp] = pack2bf_trunc(a0.z, b0.z);
            Fd[(ch0+3)*20 + jp] = pack2bf_trunc(a0.w, b0.w);
            Fd[(ch0+4)*20 + jp] = pack2bf_trunc(a1.x, b1.x);
            Fd[(ch0+5)*20 + jp] = pack2bf_trunc(a1.y, b1.y);
            Fd[(ch0+6)*20 + jp] = pack2bf_trunc(a1.z, b1.z);
            Fd[(ch0+7)*20 + jp] = pack2bf_trunc(a1.w, b1.w);
            __syncthreads();
            bf16x8 af = *(const bf16x8*)(Ct + (size_t)(w*16 + l15)*96 + ck*32 + quad*8);
            #pragma unroll
            for (int nt = 0; nt < 8; ++nt){
                bf16x8 bfr = *(const bf16x8*)(Ft + (size_t)(nt*16 + l15)*40 + quad*8);
                acc[nt] = __builtin_amdgcn_mfma_f32_16x16x32_bf16(af, bfr, acc[nt], 0, 0, 0);
            }
        }
        ushort_t* dst = Abuf + ((size_t)f*chunk + blockIdx.x)*8192;
        #pragma unroll
        for (int nt = 0; nt < 8; ++nt)
            #pragma unroll
            for (int reg = 0; reg < 4; ++reg){
                int cell = w*16 + quad*4 + reg;
                int c    = nt*16 + l15;
                dst[(size_t)cell*128 + c] = f2bf(acc[nt][reg]);
            }
    }
}

// ---------------- cconv stage 2: MFMA GEMM  P = A(bf16) @ Wt^T, split-K ----------------
__global__ __launch_bounds__(256) void mfma_gemm_kernel(
        const ushort_t* __restrict__ Abuf, const ushort_t* __restrict__ Wt,
        float* __restrict__ Pbuf, int chunk){
    __shared__ ushort_t Asm[128*64];
    __shared__ ushort_t Bsm[128*64];
    int tid = threadIdx.x, lane = tid & 63, w = tid >> 6;
    int feat = blockIdx.z >> 3, s = blockIdx.z & 7;
    const ushort_t* Ab = Abuf + (size_t)feat*chunk*8192 + (size_t)blockIdx.x*128*8192;
    const ushort_t* Bb = Wt + (size_t)feat*128*8192;
    int wm = w >> 1, wn = w & 1;
    int lr = lane >> 3, pb = lane & 7, lb = pb ^ lr;
    int quad = lane >> 4, l15 = lane & 15;
    int arow0 = w*32;
    f32x4 acc[4][4] = {};
    const int kk0 = s*(8192/KSPLIT), kk1 = kk0 + 8192/KSPLIT;
    for (int kk = kk0; kk < kk1; kk += 64){
        __syncthreads();
        #pragma unroll
        for (int q = 0; q < 4; ++q){
            int r = arow0 + q*8 + lr;
            load_lds16(Ab + (size_t)r*8192 + kk + lb*8, Asm + (arow0 + q*8)*64);
            load_lds16(Bb + (size_t)r*8192 + kk + lb*8, Bsm + (arow0 + q*8)*64);
        }
        __syncthreads();
        #pragma unroll
        for (int h = 0; h < 2; ++h){
            bf16x8 aF[4], bF[4];
            #pragma unroll
            for (int mt = 0; mt < 4; ++mt){
                int ml = wm*64 + mt*16 + l15;
                int p = (h*4 + quad) ^ (ml & 7);
                aF[mt] = *(const bf16x8*)(Asm + ml*64 + p*8);
            }
            #pragma unroll
            for (int nt = 0; nt < 4; ++nt){
                int nl = wn*64 + nt*16 + l15;
                int p = (h*4 + quad) ^ (nl & 7);
                bF[nt] = *(const bf16x8*)(Bsm + nl*64 + p*8);
            }
            #pragma unroll
            for (int mt = 0; mt < 4; ++mt)
                #pragma unroll
                for (int nt = 0; nt < 4; ++nt)
                    acc[mt][nt] = __builtin_amdgcn_mfma_f32_16x16x32_bf16(
                        aF[mt], bF[nt], acc[mt][nt], 0, 0, 0);
        }
    }
    float* P = Pbuf + (size_t)blockIdx.z*chunk*128 + (size_t)blockIdx.x*128*128;
    #pragma unroll
    for (int mt = 0; mt < 4; ++mt)
        #pragma unroll
        for (int nt = 0; nt < 4; ++nt)
            #pragma unroll
            for (int reg = 0; reg < 4; ++reg){
                int r = wm*64 + mt*16 + quad*4 + reg;
                int c = wn*64 + nt*16 + l15;
                P[(size_t)r*128 + c] = acc[mt][nt][reg];
            }
}

// ---------------- reduceP + fused BN partial stats ----------------
__global__ void reduceP_kernel(const float* __restrict__ P, float* __restrict__ hconv,
                               float* __restrict__ stats, int chunk, int base){
    __shared__ float ls[256], lq[256];
    int f = blockIdx.y, t = threadIdx.x;
    size_t base_idx = (size_t)blockIdx.x*2048 + t;
    float sum = 0.f, sq = 0.f;
    #pragma unroll
    for (int k = 0; k < 8; ++k){
        size_t idx = base_idx + (size_t)k*256;
        float s = 0.f;
        #pragma unroll
        for (int sp = 0; sp < KSPLIT; ++sp)
            s += P[((size_t)(f*KSPLIT + sp))*chunk*128 + idx];
        hconv[(size_t)f*NF + (size_t)base*128 + idx] = s;
        sum += s; sq += s*s;
    }
    ls[t] = sum; lq[t] = sq;
    __syncthreads();
    if (t < 128){
        atomicAdd(&stats[f*128 + t], ls[t] + ls[t+128]);
        atomicAdd(&stats[256 + f*128 + t], lq[t] + lq[t+128]);
    }
}

// ---------------- generic dense MFMA GEMM: D = A(M x K) @ B(N x K)^T ----------------
template<int MODE>
__global__ __launch_bounds__(256) void dgemm_kernel(
        const ushort_t* __restrict__ A, const ushort_t* __restrict__ Bw,
        const float* __restrict__ bs0, const float* __restrict__ bs1,
        const float* __restrict__ bs2,
        float* __restrict__ oF, ushort_t* __restrict__ oB0,
        ushort_t* __restrict__ oB1, ushort_t* __restrict__ oB2,
        int K, long aZ, long oZ){
    __shared__ ushort_t Asm[128*64];
    __shared__ ushort_t Bsm[128*64];
    int tid = threadIdx.x, lane = tid & 63, w = tid >> 6;
    int z = blockIdx.z;
    int f = (MODE == 2) ? (z/3) : z;
    int wsel = (MODE == 2) ? (z - 3*f) : 0;
    const ushort_t* Ab = A + (size_t)f*aZ + (size_t)blockIdx.x*128*K;
    const ushort_t* Bb = Bw + ((MODE == 2) ? (size_t)wsel*16384 : 0)
                            + (size_t)blockIdx.y*128*K;
    int wm = w >> 1, wn = w & 1;
    int lr = lane >> 3, pb = lane & 7, lb = pb ^ lr;
    int quad = lane >> 4, l15 = lane & 15;
    int arow0 = w*32;
    f32x4 acc[4][4] = {};
    for (int kk = 0; kk < K; kk += 64){
        __syncthreads();
        #pragma unroll
        for (int q = 0; q < 4; ++q){
            int r = arow0 + q*8 + lr;
            load_lds16(Ab + (size_t)r*K + kk + lb*8, Asm + (arow0 + q*8)*64);
            load_lds16(Bb + (size_t)r*K + kk + lb*8, Bsm + (arow0 + q*8)*64);
        }
        __syncthreads();
        #pragma unroll
        for (int h = 0; h < 2; ++h){
            bf16x8 aF[4], bF[4];
            #pragma unroll
            for (int mt = 0; mt < 4; ++mt){
                int ml = wm*64 + mt*16 + l15;
                int p = (h*4 + quad) ^ (ml & 7);
                aF[mt] = *(const bf16x8*)(Asm + ml*64 + p*8);
            }
            #pragma unroll
            for (int nt = 0; nt < 4; ++nt){
                int nl = wn*64 + nt*16 + l15;
                int p = (h*4 + quad) ^ (nl & 7);
                bF[nt] = *(const bf16x8*)(Bsm + nl*64 + p*8);
            }
            #pragma unroll
            for (int mt = 0; mt < 4; ++mt)
                #pragma unroll
                for (int nt = 0; nt < 4; ++nt)
                    acc[mt][nt] = __builtin_amdgcn_mfma_f32_16x16x32_bf16(
                        aF[mt], bF[nt], acc[mt][nt], 0, 0, 0);
        }
    }
    int r0 = blockIdx.x*128, c0 = blockIdx.y*128;
    const float* bias = bs0;
    float osc = 1.f;
    if (MODE == 2){
        bias = (wsel == 0) ? bs0 : (wsel == 1 ? bs1 : bs2);
        // Q scale: log2(e)/sqrt(32)  (softmax runs in exp2 domain)
        if (wsel == 0) osc = 0.25506764057565145f;
    }
    #pragma unroll
    for (int mt = 0; mt < 4; ++mt)
        #pragma unroll
        for (int nt = 0; nt < 4; ++nt)
            #pragma unroll
            for (int reg = 0; reg < 4; ++reg){
                int R = r0 + wm*64 + mt*16 + quad*4 + reg;
                int C = c0 + wn*64 + nt*16 + l15;
                float v = acc[mt][nt][reg];
                if (MODE == 0){
                    oF[(size_t)z*oZ + (size_t)R*128 + C] = v + bias[C];
                } else if (MODE == 1){
                    float r = fmaxf(v + bias[C], 0.f);
                    oB0[(size_t)z*2097152 + (size_t)R*512 + C] = f2bf(r);
                } else {
                    float r = (v + bias[C])*osc;
                    int hh = C >> 5, dd = C & 31;
                    if (wsel < 2){
                        ushort_t* dst = wsel ? oB1 : oB0;
                        dst[((size_t)(f*4+hh)*4096 + R)*32 + dd] = f2bf(r);
                    } else {
                        oB2[((size_t)(f*4+hh)*32 + dd)*4096 + R] = f2bf(r);
                    }
                }
            }
}

// bn apply (stats = raw sum/sumsq) + relu -> xf; h = xf + pe -> hb (bf16)
__global__ void bn_apply_kernel(const float* __restrict__ hconv, const float* __restrict__ stats,
        const float* __restrict__ gx, const float* __restrict__ bxp,
        const float* __restrict__ gy, const float* __restrict__ byp,
        const float* __restrict__ pe,
        float* __restrict__ xf, ushort_t* __restrict__ hb){
    int f = blockIdx.y;
    size_t idx = (size_t)blockIdx.x*256 + threadIdx.x;
    int ch = idx & 127;
    const float* g = f ? gy : gx;
    const float* b = f ? byp : bxp;
    float m  = stats[f*128 + ch] * (1.f/NPTS);
    float var = stats[256 + f*128 + ch] * (1.f/NPTS) - m*m;
    float inv = rsqrtf(var + 1e-5f);
    float vv = hconv[(size_t)f*NF + idx];
    float r = fmaxf((vv - m)*inv*g[ch] + b[ch], 0.f);
    xf[(size_t)f*NF + idx] = r;
    hb[(size_t)f*NF + idx] = f2bf(r + pe[idx]);
}

// ---------------- MFMA flash attention: 32x32x16 fragments, key-split, Schraudolph ----------------
// Wave = 32 queries; block = 4 waves = 128 queries. grid (32, 4, 2*NSPLIT).
// 32x32x16 layouts: A[m=lane&31][k=8*(lane>>5)+j], B[k][n=lane&31],
// C/D: col=lane&31, row=(reg&3)+8*(reg>>2)+4*(lane>>5)  [m74/m101-verified].
// No max-subtraction (shift-invariance + fp32 exponent headroom); exp2 via the
// Schraudolph bit-trick. l computed by VALU sum (+shfl_xor 32) from fp32 p-values.
__global__ __launch_bounds__(256) void attn_mfma_kernel(
        const ushort_t* __restrict__ Qb, const ushort_t* __restrict__ Kb,
        const ushort_t* __restrict__ Vt, ushort_t* __restrict__ Opartb,
        float* __restrict__ ml){
    __shared__ ushort_t Kl[64*40];      // [key][d]  stride 40
    __shared__ ushort_t Vl[32*72];      // [d][key]  stride 72
    __shared__ ushort_t Pl[128*72];     // [q_local][key] stride 72, wave-private rows
    int tid = threadIdx.x, lane = tid & 63, w = tid >> 6;
    int q31 = lane & 31, hi = lane >> 5;
    int q0 = blockIdx.x*128;
    int head = blockIdx.y;
    int f = blockIdx.z >> 3, ksp = blockIdx.z & (NSPLIT-1);
    const ushort_t* Qh = Qb + ((size_t)(f*4+head)*4096)*32;
    const ushort_t* Kh = Kb + ((size_t)(f*4+head)*4096)*32;
    const ushort_t* Vh = Vt + ((size_t)(f*4+head)*32)*4096;
    int ql = w*32 + q31;
    int qg = q0 + ql;
    bf16x8 qfrag[2];
    qfrag[0] = *(const bf16x8*)(Qh + (size_t)qg*32 + hi*8);
    qfrag[1] = *(const bf16x8*)(Qh + (size_t)qg*32 + 16 + hi*8);
    f32x16 oacc = {};
    float lsum = 0.f;
    const float S23 = 8388608.0f;       // 2^23
    const float B23 = 1065353216.0f;    // 127 * 2^23
    int kr = tid >> 2, kseg = tid & 3;
    int vd = tid >> 3, vseg = tid & 7;
    for (int kt = 0; kt < 4096/NSPLIT/64; ++kt){
        int k0 = ksp*(4096/NSPLIT) + kt*64;
        uint4 tk = *(const uint4*)(Kh + (size_t)(k0+kr)*32 + kseg*8);
        uint4 tv = *(const uint4*)(Vh + (size_t)vd*4096 + k0 + vseg*8);
        __syncthreads();
        *(uint4*)(Kl + kr*40 + kseg*8) = tk;
        *(uint4*)(Vl + vd*72 + vseg*8) = tv;
        __syncthreads();
        #pragma unroll
        for (int mt = 0; mt < 2; ++mt){
            f32x16 sc = {};
            #pragma unroll
            for (int c = 0; c < 2; ++c){
                bf16x8 kf = *(const bf16x8*)(Kl + (size_t)(mt*32 + q31)*40 + c*16 + hi*8);
                sc = __builtin_amdgcn_mfma_f32_32x32x16_bf16(kf, qfrag[c], sc, 0, 0, 0);
            }
            #pragma unroll
            for (int r = 0; r < 4; ++r){
                unsigned i0 = (unsigned)fmaf(sc[4*r+0], S23, B23);
                unsigned i1 = (unsigned)fmaf(sc[4*r+1], S23, B23);
                unsigned i2 = (unsigned)fmaf(sc[4*r+2], S23, B23);
                unsigned i3 = (unsigned)fmaf(sc[4*r+3], S23, B23);
                lsum += (__uint_as_float(i0) + __uint_as_float(i1))
                      + (__uint_as_float(i2) + __uint_as_float(i3));
                uint2 pk;
                pk.x = __builtin_amdgcn_perm(i1, i0, 0x07060302u);
                pk.y = __builtin_amdgcn_perm(i3, i2, 0x07060302u);
                // keys mt*32 + 8r + 4hi + {0..3}
                *(uint2*)(Pl + (size_t)ql*72 + mt*32 + r*8 + hi*4) = pk;
            }
        }
        #pragma unroll
        for (int kc = 0; kc < 4; ++kc){
            bf16x8 vf = *(const bf16x8*)(Vl + (size_t)q31*72 + kc*16 + hi*8);
            bf16x8 pf = *(const bf16x8*)(Pl + (size_t)ql*72 + kc*16 + hi*8);
            oacc = __builtin_amdgcn_mfma_f32_32x32x16_bf16(vf, pf, oacc, 0, 0, 0);
        }
    }
    lsum += __shfl_xor(lsum, 32);
    int slot = (f*4 + head)*NSPLIT + ksp;
    ushort_t* Op = Opartb + ((size_t)slot*4096 + qg)*32;
    #pragma unroll
    for (int r2 = 0; r2 < 4; ++r2){
        // d = 8*r2 + 4*hi + {0..3} <- regs 4*r2..4*r2+3
        *(unsigned*)(Op + 8*r2 + 4*hi)     = pack2bf_trunc(oacc[4*r2+0], oacc[4*r2+1]);
        *(unsigned*)(Op + 8*r2 + 4*hi + 2) = pack2bf_trunc(oacc[4*r2+2], oacc[4*r2+3]);
    }
    if (hi == 0)
        ml[(size_t)slot*4096 + qg] = lsum;
}

// ---------------- attention split combine (plain sums) -> Ob (bf16 [f][q][128]) ----------------
__global__ void attn_combine_kernel(const ushort_t* __restrict__ Opartb,
        const float* __restrict__ ml, ushort_t* __restrict__ Ob){
    int gid = blockIdx.x*256 + threadIdx.x;     // < 2*4*4096*16 (d-pairs)
    int fh = gid >> 16;
    int rem = gid & 65535;
    int q = rem >> 4, d2 = rem & 15;
    float lsum = 0.f, o0 = 0.f, o1 = 0.f;
    #pragma unroll
    for (int s = 0; s < NSPLIT; ++s){
        lsum += ml[((size_t)fh*NSPLIT + s)*4096 + q];
        unsigned u = *(const unsigned*)(Opartb + (((size_t)(fh*NSPLIT + s))*4096 + q)*32 + 2*d2);
        o0 += __uint_as_float(u << 16);
        o1 += __uint_as_float(u & 0xFFFF0000u);
    }
    float inv = 1.f/lsum;
    int f = fh >> 2, head = fh & 3;
    *(unsigned*)(Ob + (size_t)f*NF + (size_t)q*128 + head*32 + 2*d2) =
        pack2bf_trunc(o0*inv, o1*inv);
}

// ---------------- LayerNorm(a + b), optional bf16 copy ----------------
__global__ __launch_bounds__(128) void ln_res_kernel(const float* __restrict__ a,
        const float* __restrict__ b, const float* __restrict__ g,
        const float* __restrict__ be, float* __restrict__ out,
        ushort_t* __restrict__ outB){
    __shared__ float red[128];
    int t = threadIdx.x;
    size_t off = (size_t)blockIdx.y*NF + (size_t)blockIdx.x*CH;
    float v = a[off + t] + b[off + t];
    red[t] = v; __syncthreads();
    for (int o = 64; o; o >>= 1){ if (t < o) red[t] += red[t+o]; __syncthreads(); }
    float m = red[0] / 128.f;
    __syncthreads();
    float d = v - m;
    red[t] = d*d; __syncthreads();
    for (int o = 64; o; o >>= 1){ if (t < o) red[t] += red[t+o]; __syncthreads(); }
    float var = red[0] / 128.f;
    float res = (v - m)*rsqrtf(var + 1e-5f)*g[t] + be[t];
    out[off + t] = res;
    if (outB) outB[off + t] = f2bf(res);
}

// ---------------- fused final: LN2 (both feats) + sigmoid gate ----------------
__global__ __launch_bounds__(128) void ln2_combine_kernel(
        const float* __restrict__ a, const float* __restrict__ b,
        const float* __restrict__ g, const float* __restrict__ be,
        const float* __restrict__ x, const float* __restrict__ y,
        float* __restrict__ out){
    __shared__ float red0[128], red1[128];
    int t = threadIdx.x;
    size_t off = (size_t)blockIdx.x*CH;
    float v0 = a[off + t] + b[off + t];
    float v1 = a[NF + off + t] + b[NF + off + t];
    red0[t] = v0; red1[t] = v1; __syncthreads();
    for (int o = 64; o; o >>= 1){
        if (t < o){ red0[t] += red0[t+o]; red1[t] += red1[t+o]; }
        __syncthreads();
    }
    float m0 = red0[0] / 128.f, m1 = red1[0] / 128.f;
    __syncthreads();
    float d0 = v0 - m0, d1 = v1 - m1;
    red0[t] = d0*d0; red1[t] = d1*d1; __syncthreads();
    for (int o = 64; o; o >>= 1){
        if (t < o){ red0[t] += red0[t+o]; red1[t] += red1[t+o]; }
        __syncthreads();
    }
    float r0 = d0*rsqrtf(red0[0]/128.f + 1e-5f)*g[t] + be[t];
    float r1 = d1*rsqrtf(red1[0]/128.f + 1e-5f)*g[t] + be[t];
    float wgt = 1.f/(1.f + __expf(-(r0 + r1)));
    out[off + t] = 2.f*x[off + t]*wgt + 2.f*y[off + t]*(1.f - wgt);
}

extern "C" void kernel_launch(void* const* d_in, const int* in_sizes, int n_in,
                              void* d_out, int out_size, void* d_ws, size_t ws_size,
                              hipStream_t stream){
    (void)in_sizes; (void)n_in; (void)out_size;
    const float* x    = (const float*)d_in[0];
    const float* y    = (const float*)d_in[1];
    const float* pos  = (const float*)d_in[2];
    const int*   nbr  = (const int*)  d_in[3];
    const float* Wx   = (const float*)d_in[5];
    const float* bnxg = (const float*)d_in[7];
    const float* bnxb = (const float*)d_in[8];
    const float* Wy   = (const float*)d_in[9];
    const float* bnyg = (const float*)d_in[11];
    const float* bnyb = (const float*)d_in[12];
    const float* Wq   = (const float*)d_in[13];
    const float* bq   = (const float*)d_in[14];
    const float* Wk   = (const float*)d_in[15];
    const float* bk   = (const float*)d_in[16];
    const float* Wv   = (const float*)d_in[17];
    const float* bv   = (const float*)d_in[18];
    const float* Wo   = (const float*)d_in[19];
    const float* bo   = (const float*)d_in[20];
    const float* ln1g = (const float*)d_in[21];
    const float* ln1b = (const float*)d_in[22];
    const float* W1   = (const float*)d_in[23];
    const float* b1   = (const float*)d_in[24];
    const float* W2   = (const float*)d_in[25];
    const float* b2   = (const float*)d_in[26];
    const float* ln2g = (const float*)d_in[27];
    const float* ln2b = (const float*)d_in[28];

    float* ws     = (float*)d_ws;
    float* pe     = ws;                       // NF
    float* hconv  = pe + NF;                  // 2NF
    float* xf     = hconv + (size_t)2*NF;     // 2NF
    float* o2     = xf + (size_t)2*NF;        // 2NF
    float* feat1  = o2 + (size_t)2*NF;        // 2NF
    float* ff2    = feat1 + (size_t)2*NF;     // 2NF
    float* stats  = ff2 + (size_t)2*NF;       // 2048
    float* mlbuf  = stats + 2048;             // 2*4*NSPLIT*4096
    float* Pbuf   = mlbuf + (size_t)2*4*NSPLIT*4096;      // 2048*chunk

    const size_t fixedFloats = (size_t)11*NF + 2048 + (size_t)2*4*NSPLIT*4096;
    const size_t fixedUsh = (size_t)2097152 + 196608 + 6*1048576 + 4194304
                          + (size_t)2*4*NSPLIT*4096*32;   // + Opartb (bf16)
    int chunk = 128;
    const int cand[6] = {4096, 2048, 1024, 512, 256, 128};
    for (int ci = 0; ci < 6; ++ci){
        size_t need = (fixedFloats + (size_t)2048*cand[ci])*4
                    + (fixedUsh + (size_t)2*cand[ci]*8192)*2;
        if (need <= ws_size){ chunk = cand[ci]; break; }
    }
    ushort_t* Wt     = (ushort_t*)(Pbuf + (size_t)2048*chunk);
    ushort_t* wbuf   = Wt + 2097152;
    ushort_t* hb     = wbuf + 196608;
    ushort_t* Qb     = hb + 1048576;
    ushort_t* Kb     = Qb + 1048576;
    ushort_t* Vtb    = Kb + 1048576;
    ushort_t* Ob     = Vtb + 1048576;
    ushort_t* feat1b = Ob + 1048576;
    ushort_t* ff1b   = feat1b + 1048576;
    ushort_t* Opartb = ff1b + 4194304;
    ushort_t* Abuf   = Opartb + (size_t)2*4*NSPLIT*4096*32;

    pos_stats_kernel<<<1, 256, 0, stream>>>(pos, stats);
    pe_kernel<<<NPTS*64/256, 256, 0, stream>>>(pos, stats, pe);
    wt_kernel<<<dim3(256, 4, 2), 256, 0, stream>>>(Wx, Wy, Wt);
    wcast_kernel<<<768, 256, 0, stream>>>(Wq, Wk, Wv, Wo, W1, W2, wbuf);

    for (int base = 0; base < NPTS; base += chunk){
        cf_kernel<<<chunk, 256, 0, stream>>>(x, y, pos, nbr, Abuf, base, chunk);
        mfma_gemm_kernel<<<dim3(chunk/128, 1, 2*KSPLIT), 256, 0, stream>>>(Abuf, Wt, Pbuf, chunk);
        reduceP_kernel<<<dim3(chunk*128/2048, 2), 256, 0, stream>>>(Pbuf, hconv, stats, chunk, base);
    }

    bn_apply_kernel<<<dim3(NF/256, 2), 256, 0, stream>>>(hconv, stats, bnxg, bnxb, bnyg, bnyb,
                                                         pe, xf, hb);

    dgemm_kernel<2><<<dim3(32, 1, 6), 256, 0, stream>>>(hb, wbuf, bq, bk, bv,
        nullptr, Qb, Kb, Vtb, 128, (long)NF, 0);

    attn_mfma_kernel<<<dim3(32, 4, 2*NSPLIT), 256, 0, stream>>>(Qb, Kb, Vtb, Opartb, mlbuf);
    attn_combine_kernel<<<2048, 256, 0, stream>>>(Opartb, mlbuf, Ob);

    dgemm_kernel<0><<<dim3(32, 1, 2), 256, 0, stream>>>(Ob, wbuf + 49152, bo, nullptr, nullptr,
        o2, nullptr, nullptr, nullptr, 128, (long)NF, (long)NF);
    ln_res_kernel<<<dim3(NPTS, 2), 128, 0, stream>>>(xf, o2, ln1g, ln1b, feat1, feat1b);

    dgemm_kernel<1><<<dim3(32, 4, 2), 256, 0, stream>>>(feat1b, wbuf + 65536, b1, nullptr, nullptr,
        nullptr, ff1b, nullptr, nullptr, 128, (long)NF, 0);
    dgemm_kernel<0><<<dim3(32, 1, 2), 256, 0, stream>>>(ff1b, wbuf + 131072, b2, nullptr, nullptr,
        ff2, nullptr, nullptr, nullptr, 512, (long)2097152, (long)NF);

    ln2_combine_kernel<<<NPTS, 128, 0, stream>>>(feat1, ff2, ln2g, ln2b, x, y, (float*)d_out);
}